// Round 14
// baseline (1086.991 us; speedup 1.0000x reference)
//
#include <hip/hip_runtime.h>
#include <hip/hip_fp16.h>
#include <math.h>

// ---------------------------------------------------------------------------
// NatureCNN: conv×3 (implicit-im2col bf16 MFMA GEMMs, NHWC intermediates)
// | lin1+relu -> lin2 (bf16 MFMA) -> concat feat -> wih0 pre-act GEMMs (fp32)
// -> 2×(2-layer LSTM) -> fused head.
// Round 14: r13's counters showed 1 wave/SIMD (Occupancy 1.4%) -> zero
// latency hiding; step = 1700cyc vs ~220cyc issue. Fix with TLP: 4 segments
// co-resident per block (1024 thr, 16 waves, 4 waves/SIMD, 8 blocks) --
// independent segments' waves interleave and hide each other's stalls.
// Per-thread code unchanged. Xl1 stored f16 (LDS 4x36.5KB=143KB<160KB).
// launch_bounds(1024,1): 16-wave block forces <=128 VGPR budget; demand 96.
// ---------------------------------------------------------------------------

typedef __attribute__((ext_vector_type(4))) float f32x4;
typedef __attribute__((ext_vector_type(8))) short s16x8;
typedef __attribute__((ext_vector_type(8))) unsigned short u16x8;
typedef __attribute__((ext_vector_type(4))) unsigned int u32x4;

__device__ __forceinline__ unsigned short f2bf(float f){
  union { float f; unsigned int u; } v; v.f = f;
  unsigned int r = (v.u + 0x7fffu + ((v.u >> 16) & 1u)) >> 16;
  return (unsigned short)r;
}
__device__ __forceinline__ unsigned short f2h(float f){
  return __half_as_ushort(__float2half(f));
}
__device__ __forceinline__ float h2f(unsigned short u){
  return __half2float(__ushort_as_half(u));
}
__device__ __forceinline__ float sigmoidf_(float x){ return 1.0f/(1.0f+__expf(-x)); }
__device__ __forceinline__ float tanhf_(float x){
  float e = __expf(-2.0f*fabsf(x));
  float t = (1.0f - e)/(1.0f + e);
  return copysignf(t, x);
}

#if __has_builtin(__builtin_amdgcn_fdot2)
typedef _Float16 f16x2 __attribute__((ext_vector_type(2)));
__device__ __forceinline__ float dot2h(unsigned int a, unsigned int b, float c){
  union { unsigned int u; f16x2 h; } ua, ub;
  ua.u = a; ub.u = b;
  return __builtin_amdgcn_fdot2(ua.h, ub.h, c, false);
}
#else
__device__ __forceinline__ float dot2h(unsigned int a, unsigned int b, float c){
  __half2 ha = *(__half2*)&a, hb = *(__half2*)&b;
  float2 fa = __half22float2(ha), fb = __half22float2(hb);
  return c + fa.x*fb.x + fa.y*fb.y;
}
#endif

// ---------------------------------------------------------------------------
// ONE merged prep kernel (unchanged).
// ---------------------------------------------------------------------------
__global__ void prep_k(
    const float* __restrict__ data, unsigned short* __restrict__ data_bf,
    const float* __restrict__ l1w,  unsigned short* __restrict__ l1w_bf,
    const float* __restrict__ l2w,  unsigned short* __restrict__ l2w_bf,
    const float* __restrict__ c1w,  unsigned short* __restrict__ c1w_bf,
    const float* __restrict__ c2w,  unsigned short* __restrict__ c2w_bf,
    const float* __restrict__ c3w,  unsigned short* __restrict__ c3w_bf,
    const float* __restrict__ wihS, unsigned short* __restrict__ wihS_bf,
    const float* __restrict__ wihR, unsigned short* __restrict__ wihR_bf,
    const float* __restrict__ m0, const float* __restrict__ m1,
    const float* __restrict__ m2, const float* __restrict__ m3,
    const float* __restrict__ m4, const float* __restrict__ m5,
    unsigned int* __restrict__ wpk)
{
  const int job = blockIdx.y;
  const int stride = gridDim.x * blockDim.x;
  int e0 = blockIdx.x * blockDim.x + threadIdx.x;
  if (job == 0){
    for (int e = e0; e < 2048*1536; e += stride){
      int r = e / 1536, k = e - r*1536;
      data_bf[e] = (k < 1500) ? f2bf(data[(size_t)r*1500 + k]) : (unsigned short)0;
    }
  } else if (job == 1){
    for (int e = e0; e < 1024*1536; e += stride){
      int r = e / 1536, k = e - r*1536;
      l1w_bf[e] = (k < 1500) ? f2bf(l1w[(size_t)r*1500 + k]) : (unsigned short)0;
    }
  } else if (job == 2){
    for (int e = e0; e < 512*1024; e += stride) l2w_bf[e] = f2bf(l2w[e]);
  } else if (job == 3){
    for (int e = e0; e < 32*192; e += stride) c1w_bf[e] = f2bf(c1w[e]);
  } else if (job == 4){
    for (int e = e0; e < 64*512; e += stride){
      int oc = e >> 9, r = e & 511;
      int tap = r >> 5, ic = r & 31;
      c2w_bf[e] = f2bf(c2w[(size_t)oc*512 + ic*16 + tap]);
    }
  } else if (job == 5){
    for (int e = e0; e < 64*576; e += stride){
      int oc = e / 576, r = e - oc*576;
      int tap = r >> 6, ic = r & 63;
      c3w_bf[e] = f2bf(c3w[(size_t)oc*576 + ic*9 + tap]);
    }
  } else if (job == 6 || job == 7){
    const float* src = (job == 6) ? wihS : wihR;
    unsigned short* dst = (job == 6) ? wihS_bf : wihR_bf;
    for (int e = e0; e < 400*1536; e += stride){
      int g = e / 1536, k = e - g*1536;
      int ksrc = (k < 1024) ? ((k & 63)*16 + (k >> 6)) : k;
      dst[e] = f2bf(src[(size_t)g*1536 + ksrc]);
    }
  } else {
    const float* srcs[6] = {m0,m1,m2,m3,m4,m5};
    for (int e = e0; e < 6*20000; e += stride){
      int mat = e / 20000, r = e - mat*20000;
      int kk = r / 400, g = r - kk*400;
      const float* src = srcs[mat];
      unsigned int lo = f2h(src[g*100 + 2*kk]);
      unsigned int hi = f2h(src[g*100 + 2*kk + 1]);
      wpk[e] = lo | (hi << 16);
    }
  }
}

// ---------------------------------------------------------------------------
// bf16 MFMA GEMM (unchanged, passing since round 2)
// ---------------------------------------------------------------------------
template<int BM,int BN,int WAVES_M,int WAVES_N,int AMODE,int CMODE,int RELU,int NGUARD,
         int CIN,int HI,int WI,int KH,int KW,int ST,int HO,int WO>
__global__ __launch_bounds__(256) void mgemm(
    const void* __restrict__ Av, const unsigned short* __restrict__ B,
    void* __restrict__ Cv, const float* __restrict__ bias,
    int M, int N, int K, int lda, int ldc, int cstride)
{
  constexpr int BK = 64;
  constexpr int WROWS = BM / WAVES_M;
  constexpr int WCOLS = BN / WAVES_N;
  constexpr int MF = WROWS / 16;
  constexpr int NF = WCOLS / 16;
  constexpr int HOWO = HO*WO;
  __shared__ unsigned short As[BM*BK];
  __shared__ unsigned short Bs[BN*BK];
  const int tid = threadIdx.x;
  const int bm = blockIdx.x * BM;
  const int bn = blockIdx.y * BN;
  const int lane = tid & 63, w = tid >> 6;
  const int wm = w / WAVES_N, wn = w % WAVES_N;
  const int m0 = wm * WROWS, n0 = wn * WCOLS;

  f32x4 acc[MF][NF] = {};

  const int ar = tid >> 1;
  const int as0 = 4 * (tid & 1);
  const int row_g = bm + ar;
  int a_n = 0, a_oy = 0, a_ox = 0;
  if (AMODE != 0){ a_n = row_g / HOWO; int p = row_g - a_n*HOWO; a_oy = p / WO; a_ox = p - a_oy*WO; }

  for (int kt = 0; kt < K; kt += BK){
    #pragma unroll
    for (int si = 0; si < 4; ++si){
      int s = as0 + si;
      int k0 = kt + s*8;
      u16x8 val;
      if constexpr (AMODE == 0){
        val = *(const u16x8*)((const unsigned short*)Av + (size_t)row_g*lda + k0);
      } else if constexpr (AMODE == 1){
        int ic = k0 >> 6, r = k0 & 63, ky = r >> 3;
        const float* src = (const float*)Av +
            (((size_t)(a_n*CIN + ic)*HI + a_oy*ST + ky)*WI + a_ox*ST);
        f32x4 f0 = *(const f32x4*)src;
        f32x4 f1 = *(const f32x4*)(src + 4);
        val[0]=f2bf(f0[0]); val[1]=f2bf(f0[1]); val[2]=f2bf(f0[2]); val[3]=f2bf(f0[3]);
        val[4]=f2bf(f1[0]); val[5]=f2bf(f1[1]); val[6]=f2bf(f1[2]); val[7]=f2bf(f1[3]);
      } else {
        int tap = k0 / CIN, ic0 = k0 - tap*CIN;
        int ky = tap / KW, kx = tap - ky*KW;
        const unsigned short* src = (const unsigned short*)Av +
            (((size_t)(a_n*HI + a_oy*ST + ky)*WI + a_ox*ST + kx)*CIN + ic0);
        val = *(const u16x8*)src;
      }
      int phys = s ^ ((ar >> 1) & 7);
      *(u16x8*)&As[ar*BK + phys*8] = val;
    }
    if constexpr (BN == 64){
      int br = tid >> 2, bs0 = 2*(tid & 3);
      #pragma unroll
      for (int si = 0; si < 2; ++si){
        int s = bs0 + si, k0 = kt + s*8;
        int n_g = bn + br;
        u16x8 val = {};
        if (!NGUARD || n_g < N) val = *(const u16x8*)(B + (size_t)n_g*K + k0);
        int phys = s ^ ((br >> 1) & 7);
        *(u16x8*)&Bs[br*BK + phys*8] = val;
      }
    } else {
      int br = tid >> 3, s = tid & 7, k0 = kt + s*8;
      int n_g = bn + br;
      u16x8 val = {};
      if (!NGUARD || n_g < N) val = *(const u16x8*)(B + (size_t)n_g*K + k0);
      int phys = s ^ ((br >> 1) & 7);
      *(u16x8*)&Bs[br*BK + phys*8] = val;
    }
    __syncthreads();
    #pragma unroll
    for (int ks = 0; ks < 2; ++ks){
      s16x8 a[MF], b[NF];
      #pragma unroll
      for (int i = 0; i < MF; ++i){
        int row = m0 + i*16 + (lane & 15);
        int phys = (ks*4 + (lane >> 4)) ^ ((row >> 1) & 7);
        a[i] = *(const s16x8*)&As[row*BK + phys*8];
      }
      #pragma unroll
      for (int j = 0; j < NF; ++j){
        int row = n0 + j*16 + (lane & 15);
        int phys = (ks*4 + (lane >> 4)) ^ ((row >> 1) & 7);
        b[j] = *(const s16x8*)&Bs[row*BK + phys*8];
      }
      #pragma unroll
      for (int i = 0; i < MF; ++i)
        #pragma unroll
        for (int j = 0; j < NF; ++j)
          acc[i][j] = __builtin_amdgcn_mfma_f32_16x16x32_bf16(a[i], b[j], acc[i][j], 0, 0, 0);
    }
    __syncthreads();
  }

  if constexpr (CMODE == 3){
    float* Cf = (float*)Cv;
    #pragma unroll
    for (int i = 0; i < MF; ++i)
      #pragma unroll
      for (int j = 0; j < NF; ++j){
        int col = bn + n0 + j*16 + (lane & 15);
        float bv = (bias && (!NGUARD || col < N)) ? bias[col] : 0.f;
        #pragma unroll
        for (int q = 0; q < 4; ++q){
          int row = bm + m0 + i*16 + (lane >> 4)*4 + q;
          float v = acc[i][j][q] + bv;
          if (RELU) v = fmaxf(v, 0.f);
          if (!NGUARD || col < N) Cf[(size_t)row*ldc + col] = v;
        }
      }
  } else {
    unsigned short* tile = As;
    #pragma unroll
    for (int i = 0; i < MF; ++i)
      #pragma unroll
      for (int j = 0; j < NF; ++j){
        int col = n0 + j*16 + (lane & 15);
        float bv = bias ? bias[bn + col] : 0.f;
        #pragma unroll
        for (int q = 0; q < 4; ++q){
          int row = m0 + i*16 + (lane >> 4)*4 + q;
          float v = acc[i][j][q] + bv;
          if (RELU) v = fmaxf(v, 0.f);
          tile[row*BN + col] = f2bf(v);
        }
      }
    __syncthreads();
    unsigned short* Cu = (unsigned short*)Cv;
    constexpr int CHUNKS = (BM*BN)/(256*8);
    #pragma unroll
    for (int c = 0; c < CHUNKS; ++c){
      int flat = tid*8 + c*2048;
      int row = flat / BN, col = flat - (flat/BN)*BN;
      u16x8 v = *(const u16x8*)&tile[flat];
      int rg = bm + row;
      size_t addr;
      if constexpr (CMODE == 0) addr = (size_t)rg*ldc + bn + col;
      else { int n = rg >> 4, p = rg & 15; addr = (size_t)n*cstride + p*64 + col; }
      *(u16x8*)&Cu[addr] = v;
    }
  }
}

// ---------------------------------------------------------------------------
// LSTM: 4 segments per block (1024 threads, 16 waves, 4 waves/SIMD; 8 blocks).
// Within a segment (256 threads): e = tl>>1, sub = tl&1; sub0 owns gate rows
// i(e),g(e); sub1 owns f(e),o(e) -- 100 packed f16-pair weight u32/thread.
// h: 50 packed u32 in segment-local LDS, broadcast ds_read_b128.
// sub0 sends i*g via shfl_xor(1); sub1 holds c in register, writes h to the
// double-buffered h (read t&1, write (t+1)&1): 1 block barrier per step
// (uniform trip counts across segments -> legal). Xl1 stored f16.
// Head fused per segment.
// ---------------------------------------------------------------------------
#define NSEG 4
__global__ __launch_bounds__(1024,1) void lstm_k(
    const float* __restrict__ X0s, const float* __restrict__ X0r,
    const unsigned int* __restrict__ wpk,  // 6 x [50][400] u32 packed f16 pairs
    const float* __restrict__ s_bih0, const float* __restrict__ s_bhh0,
    const float* __restrict__ s_bih1, const float* __restrict__ s_bhh1,
    const float* __restrict__ r_bih0, const float* __restrict__ r_bhh0,
    const float* __restrict__ r_bih1, const float* __restrict__ r_bhh1,
    const float* __restrict__ f1w, const float* __restrict__ f1b,
    const float* __restrict__ f2w, const float* __restrict__ f2b,
    float* __restrict__ out)
{
  __shared__ alignas(16) unsigned int h0p[NSEG][2][56];
  __shared__ alignas(16) unsigned int h1p[NSEG][2][56];
  __shared__ alignas(16) unsigned int hbufp[NSEG][1792];   // 32 x 56 pairs
  __shared__ alignas(16) unsigned short Xl1h[NSEG][12800]; // f16, 32 x 400
  __shared__ float xin[NSEG][200];
  __shared__ float mid[NSEG][512];

  const int tid = threadIdx.x;
  const int sl = tid >> 8;                 // segment slot 0..3
  const int tl = tid & 255;
  const int b = blockIdx.x*NSEG + sl;
  const int e = tl >> 1, sub = tl & 1;
  const bool act = (e < 100);
  const int eS = act ? e : 0;
  const int gA = sub*100 + eS;             // sub0: i-gate, sub1: f-gate
  const int gB = gA + 200;                 // sub0: g-gate, sub1: o-gate

  if (tl < 56){ h0p[sl][0][tl]=0u; h0p[sl][1][tl]=0u; h1p[sl][0][tl]=0u; h1p[sl][1][tl]=0u; }
  for (int q = tl; q < 1792; q += 256) hbufp[sl][q] = 0u;
  float c0r = 0.f, c1r = 0.f;
  __syncthreads();

  #pragma unroll 1
  for (int s = 0; s < 2; ++s){
    const float* Xp = (s ? X0r : X0s) + (size_t)b*32*400;
    const unsigned int* w0P  = wpk + (size_t)(s ? 3 : 0)*20000;
    const unsigned int* w1xP = wpk + (size_t)(s ? 4 : 1)*20000;
    const unsigned int* w1hP = wpk + (size_t)(s ? 5 : 2)*20000;
    const float* bi0 = s ? r_bih0 : s_bih0;
    const float* bh0 = s ? r_bhh0 : s_bhh0;
    const float* bi1 = s ? r_bih1 : s_bih1;
    const float* bh1 = s ? r_bhh1 : s_bhh1;

    // ------------- layer 0 (recurrent; 1 barrier/step) -------------
    {
      unsigned int wA[50], wB[50];
      #pragma unroll
      for (int p = 0; p < 50; ++p){
        wA[p] = w0P[p*400 + gA];
        wB[p] = w0P[p*400 + gB];
      }
      float bsA = bi0[gA] + bh0[gA];
      float bsB = bi0[gB] + bh0[gB];
      float xcA = Xp[gA], xcB = Xp[gB], xnA, xnB;
      #pragma unroll 1
      for (int t = 0; t < 32; ++t){
        if (t < 31){ xnA = Xp[(t+1)*400 + gA]; xnB = Xp[(t+1)*400 + gB]; }
        const u32x4* h4 = (const u32x4*)h0p[sl][t & 1];
        float a0=0.f, a1=0.f, b0=0.f, b1=0.f;
        #pragma unroll
        for (int i = 0; i < 12; ++i){
          u32x4 hv = h4[i];
          a0 = dot2h(wA[4*i+0], hv[0], a0);
          a1 = dot2h(wA[4*i+1], hv[1], a1);
          a0 = dot2h(wA[4*i+2], hv[2], a0);
          a1 = dot2h(wA[4*i+3], hv[3], a1);
          b0 = dot2h(wB[4*i+0], hv[0], b0);
          b1 = dot2h(wB[4*i+1], hv[1], b1);
          b0 = dot2h(wB[4*i+2], hv[2], b0);
          b1 = dot2h(wB[4*i+3], hv[3], b1);
        }
        { u32x4 hv = h4[12];
          a0 = dot2h(wA[48], hv[0], a0);
          a1 = dot2h(wA[49], hv[1], a1);
          b0 = dot2h(wB[48], hv[0], b0);
          b1 = dot2h(wB[49], hv[1], b1);
        }
        float preA = (a0 + a1) + xcA + bsA;
        float preB = (b0 + b1) + xcB + bsB;
        float vA = sigmoidf_(preA);                       // i (sub0) / f (sub1)
        float vB = sub ? sigmoidf_(preB) : tanhf_(preB);  // o (sub1) / g (sub0)
        float send = vA * vB;                             // sub0: i*g
        float recv = __shfl_xor(send, 1);
        if (act && sub){
          c0r = vA*c0r + recv;
          float hn = vB * tanhf_(c0r);
          unsigned short hv16 = f2h(hn);
          ((unsigned short*)h0p[sl][(t+1) & 1])[e] = hv16;
          ((unsigned short*)hbufp[sl])[t*112 + e] = hv16;
        }
        xcA = xnA; xcB = xnB;
        __syncthreads();
      }
    }
    // ------- layer 1a: x-part pre-acts (batch; same-thread LDS, no barrier) -------
    {
      unsigned int wA[50], wB[50];
      #pragma unroll
      for (int p = 0; p < 50; ++p){
        wA[p] = w1xP[p*400 + gA];
        wB[p] = w1xP[p*400 + gB];
      }
      float bsA = bi1[gA] + bh1[gA];
      float bsB = bi1[gB] + bh1[gB];
      #pragma unroll 1
      for (int t = 0; t < 32; ++t){
        const u32x4* x4 = (const u32x4*)&hbufp[sl][t*56];
        float a0=0.f, a1=0.f, b0=0.f, b1=0.f;
        #pragma unroll
        for (int i = 0; i < 12; ++i){
          u32x4 hv = x4[i];
          a0 = dot2h(wA[4*i+0], hv[0], a0);
          a1 = dot2h(wA[4*i+1], hv[1], a1);
          a0 = dot2h(wA[4*i+2], hv[2], a0);
          a1 = dot2h(wA[4*i+3], hv[3], a1);
          b0 = dot2h(wB[4*i+0], hv[0], b0);
          b1 = dot2h(wB[4*i+1], hv[1], b1);
          b0 = dot2h(wB[4*i+2], hv[2], b0);
          b1 = dot2h(wB[4*i+3], hv[3], b1);
        }
        { u32x4 hv = x4[12];
          a0 = dot2h(wA[48], hv[0], a0);
          a1 = dot2h(wA[49], hv[1], a1);
          b0 = dot2h(wB[48], hv[0], b0);
          b1 = dot2h(wB[49], hv[1], b1);
        }
        if (act){
          Xl1h[sl][t*400 + gA] = f2h((a0 + a1) + bsA);
          Xl1h[sl][t*400 + gB] = f2h((b0 + b1) + bsB);
        }
      }
    }
    // ------------- layer 1b: recurrent (1 barrier/step) -------------
    {
      unsigned int wA[50], wB[50];
      #pragma unroll
      for (int p = 0; p < 50; ++p){
        wA[p] = w1hP[p*400 + gA];
        wB[p] = w1hP[p*400 + gB];
      }
      #pragma unroll 1
      for (int t = 0; t < 32; ++t){
        const u32x4* h4 = (const u32x4*)h1p[sl][t & 1];
        float a0=0.f, a1=0.f, b0=0.f, b1=0.f;
        #pragma unroll
        for (int i = 0; i < 12; ++i){
          u32x4 hv = h4[i];
          a0 = dot2h(wA[4*i+0], hv[0], a0);
          a1 = dot2h(wA[4*i+1], hv[1], a1);
          a0 = dot2h(wA[4*i+2], hv[2], a0);
          a1 = dot2h(wA[4*i+3], hv[3], a1);
          b0 = dot2h(wB[4*i+0], hv[0], b0);
          b1 = dot2h(wB[4*i+1], hv[1], b1);
          b0 = dot2h(wB[4*i+2], hv[2], b0);
          b1 = dot2h(wB[4*i+3], hv[3], b1);
        }
        { u32x4 hv = h4[12];
          a0 = dot2h(wA[48], hv[0], a0);
          a1 = dot2h(wA[49], hv[1], a1);
          b0 = dot2h(wB[48], hv[0], b0);
          b1 = dot2h(wB[49], hv[1], b1);
        }
        float preA = (a0 + a1) + h2f(Xl1h[sl][t*400 + gA]);
        float preB = (b0 + b1) + h2f(Xl1h[sl][t*400 + gB]);
        float vA = sigmoidf_(preA);
        float vB = sub ? sigmoidf_(preB) : tanhf_(preB);
        float send = vA * vB;
        float recv = __shfl_xor(send, 1);
        if (act && sub){
          c1r = vA*c1r + recv;
          float hn = vB * tanhf_(c1r);
          ((unsigned short*)h1p[sl][(t+1) & 1])[e] = f2h(hn);
          if (t == 31){
            if (s) xin[sl][e] = hn;          // outR -> head cols [0,100)
            else   xin[sl][100 + e] = hn;    // outS -> head cols [100,200)
          }
        }
        __syncthreads();
      }
    }
  }

  // ------------- fused head (per segment) -------------
  for (int r = tl; r < 512; r += 256){
    float acc = f1b[r];
    const float* wrow = f1w + (size_t)r*200;
    #pragma unroll 4
    for (int k = 0; k < 200; ++k) acc += xin[sl][k]*wrow[k];
    mid[sl][r] = fmaxf(acc, 0.f);
  }
  __syncthreads();
  if (tl < 130){
    float acc = f2b[tl];
    const float* wrow = f2w + (size_t)tl*512;
    #pragma unroll 4
    for (int k = 0; k < 512; ++k) acc += mid[sl][k]*wrow[k];
    out[b*130 + tl] = acc;
  }
}

extern "C" void kernel_launch(void* const* d_in, const int* in_sizes, int n_in,
                              void* d_out, int out_size, void* d_ws, size_t ws_size,
                              hipStream_t stream)
{
  const float* obs  = (const float*)d_in[0];
  const float* data = (const float*)d_in[1];
  const float* c1w = (const float*)d_in[2];  const float* c1b = (const float*)d_in[3];
  const float* c2w = (const float*)d_in[4];  const float* c2b = (const float*)d_in[5];
  const float* c3w = (const float*)d_in[6];  const float* c3b = (const float*)d_in[7];
  const float* l1w = (const float*)d_in[8];  const float* l1b = (const float*)d_in[9];
  const float* l2w = (const float*)d_in[10]; const float* l2b = (const float*)d_in[11];
  const float* s_wih0=(const float*)d_in[12]; const float* s_whh0=(const float*)d_in[13];
  const float* s_bih0=(const float*)d_in[14]; const float* s_bhh0=(const float*)d_in[15];
  const float* s_wih1=(const float*)d_in[16]; const float* s_whh1=(const float*)d_in[17];
  const float* s_bih1=(const float*)d_in[18]; const float* s_bhh1=(const float*)d_in[19];
  const float* r_wih0=(const float*)d_in[20]; const float* r_whh0=(const float*)d_in[21];
  const float* r_bih0=(const float*)d_in[22]; const float* r_bhh0=(const float*)d_in[23];
  const float* r_wih1=(const float*)d_in[24]; const float* r_whh1=(const float*)d_in[25];
  const float* r_bih1=(const float*)d_in[26]; const float* r_bhh1=(const float*)d_in[27];
  const float* f1w=(const float*)d_in[28]; const float* f1b=(const float*)d_in[29];
  const float* f2w=(const float*)d_in[30]; const float* f2b=(const float*)d_in[31];
  float* out = (float*)d_out;
  (void)in_sizes; (void)n_in; (void)out_size;

  // ---- workspace layout (bytes, 256-aligned); total ~ 67 MB ----
  char* p = (char*)d_ws;
  auto alloc = [&](size_t bytes){ void* r = (void*)p; p += (bytes + 255) & ~(size_t)255; return r; };
  unsigned short* data_bf = (unsigned short*)alloc((size_t)2048*1536*2);
  unsigned short* c1w_bf  = (unsigned short*)alloc((size_t)32*192*2);
  unsigned short* c2w_bf  = (unsigned short*)alloc((size_t)64*512*2);
  unsigned short* c3w_bf  = (unsigned short*)alloc((size_t)64*576*2);
  unsigned short* l1w_bf  = (unsigned short*)alloc((size_t)1024*1536*2);
  unsigned short* l2w_bf  = (unsigned short*)alloc((size_t)512*1024*2);
  unsigned short* wihS_bf = (unsigned short*)alloc((size_t)400*1536*2);
  unsigned short* wihR_bf = (unsigned short*)alloc((size_t)400*1536*2);
  unsigned short* conv1o  = (unsigned short*)alloc((size_t)2048*225*32*2);  // NHWC
  unsigned short* conv2o  = (unsigned short*)alloc((size_t)2048*36*64*2);   // NHWC
  unsigned short* feat    = (unsigned short*)alloc((size_t)2048*1536*2);
  unsigned short* lin1o   = (unsigned short*)alloc((size_t)2048*1024*2);
  float* X0s  = (float*)alloc((size_t)1024*400*4);
  float* X0r  = (float*)alloc((size_t)1024*400*4);
  unsigned int* wpk = (unsigned int*)alloc((size_t)6*20000*4);
  (void)ws_size;

  // ---- merged prep (1 launch) ----
  prep_k<<<dim3(512,9),256,0,stream>>>(
      data, data_bf, l1w, l1w_bf, l2w, l2w_bf, c1w, c1w_bf,
      c2w, c2w_bf, c3w, c3w_bf, s_wih0, wihS_bf, r_wih0, wihR_bf,
      s_whh0, s_wih1, s_whh1, r_whh0, r_wih1, r_whh1, wpk);

  // ---- GEMM chain (bf16 MFMA, fp32 accumulate) ----
  mgemm<128,32,4,1, 1,0,1,0, 3,64,64,8,8,4,15,15><<<dim3(3600,1),256,0,stream>>>(
      obs, c1w_bf, conv1o, c1b, 460800, 32, 192, 0, 32, 0);
  mgemm<128,64,2,2, 2,0,1,0, 32,15,15,4,4,2,6,6><<<dim3(576,1),256,0,stream>>>(
      conv1o, c2w_bf, conv2o, c2b, 73728, 64, 512, 0, 64, 0);
  mgemm<128,64,2,2, 0,0,1,0, 1,1,1,1,1,1,1,1><<<dim3(16,16),256,0,stream>>>(
      data_bf, l1w_bf, lin1o, l1b, 2048, 1024, 1536, 1536, 1024, 0);
  mgemm<128,64,2,2, 2,2,1,0, 64,6,6,3,3,1,4,4><<<dim3(256,1),256,0,stream>>>(
      conv2o, c3w_bf, feat, c3b, 32768, 64, 576, 0, 0, 1536);
  mgemm<128,64,2,2, 0,0,0,0, 1,1,1,1,1,1,1,1><<<dim3(16,8),256,0,stream>>>(
      lin1o, l2w_bf, feat + 1024, l2b, 2048, 512, 1024, 1024, 1536, 0);
  mgemm<128,64,2,2, 0,3,0,1, 1,1,1,1,1,1,1,1><<<dim3(8,7),256,0,stream>>>(
      feat, wihS_bf, X0s, (const float*)nullptr, 1024, 400, 1536, 1536, 400, 0);
  mgemm<128,64,2,2, 0,3,0,1, 1,1,1,1,1,1,1,1><<<dim3(8,7),256,0,stream>>>(
      feat + (size_t)1024*1536, wihR_bf, X0r, (const float*)nullptr, 1024, 400, 1536, 1536, 400, 0);

  // ---- sequential LSTM (4 segments/block) + fused head ----
  lstm_k<<<8,1024,0,stream>>>(X0s, X0r, wpk,
                              s_bih0,s_bhh0,s_bih1,s_bhh1,
                              r_bih0,r_bhh0,r_bih1,r_bhh1,
                              f1w, f1b, f2w, f2b, out);
}

// Round 15
// 391.560 us; speedup vs baseline: 2.7761x; 2.7761x over previous
//
#include <hip/hip_runtime.h>
#include <hip/hip_fp16.h>
#include <math.h>

// ---------------------------------------------------------------------------
// NatureCNN: conv×3 (implicit-im2col bf16 MFMA GEMMs, NHWC intermediates)
// | lin1+relu -> lin2 (bf16 MFMA) -> concat feat -> wih0 pre-act GEMMs (fp32)
// -> 2×(2-layer LSTM) -> fused head.
// Round 15: TLP with the allocator's OBSERVED budgets: 2 segments per
// 512-thread block (16 blocks, 2 waves/SIMD). Empirical VGPR budgets:
// 256thr->256, 512thr->128, 832thr/1024thr->64. Demand ~96 fits 128.
// Per-thread code identical to r13 (spill-free at VGPR 96); only the
// segment-slot dimension added. Xl1 stays fp32 (LDS 2x62KB=124KB<160KB).
// ---------------------------------------------------------------------------

typedef __attribute__((ext_vector_type(4))) float f32x4;
typedef __attribute__((ext_vector_type(8))) short s16x8;
typedef __attribute__((ext_vector_type(8))) unsigned short u16x8;
typedef __attribute__((ext_vector_type(4))) unsigned int u32x4;

__device__ __forceinline__ unsigned short f2bf(float f){
  union { float f; unsigned int u; } v; v.f = f;
  unsigned int r = (v.u + 0x7fffu + ((v.u >> 16) & 1u)) >> 16;
  return (unsigned short)r;
}
__device__ __forceinline__ unsigned short f2h(float f){
  return __half_as_ushort(__float2half(f));
}
__device__ __forceinline__ float sigmoidf_(float x){ return 1.0f/(1.0f+__expf(-x)); }
__device__ __forceinline__ float tanhf_(float x){
  float e = __expf(-2.0f*fabsf(x));
  float t = (1.0f - e)/(1.0f + e);
  return copysignf(t, x);
}

#if __has_builtin(__builtin_amdgcn_fdot2)
typedef _Float16 f16x2 __attribute__((ext_vector_type(2)));
__device__ __forceinline__ float dot2h(unsigned int a, unsigned int b, float c){
  union { unsigned int u; f16x2 h; } ua, ub;
  ua.u = a; ub.u = b;
  return __builtin_amdgcn_fdot2(ua.h, ub.h, c, false);
}
#else
__device__ __forceinline__ float dot2h(unsigned int a, unsigned int b, float c){
  __half2 ha = *(__half2*)&a, hb = *(__half2*)&b;
  float2 fa = __half22float2(ha), fb = __half22float2(hb);
  return c + fa.x*fb.x + fa.y*fb.y;
}
#endif

// ---------------------------------------------------------------------------
// ONE merged prep kernel (unchanged).
// ---------------------------------------------------------------------------
__global__ void prep_k(
    const float* __restrict__ data, unsigned short* __restrict__ data_bf,
    const float* __restrict__ l1w,  unsigned short* __restrict__ l1w_bf,
    const float* __restrict__ l2w,  unsigned short* __restrict__ l2w_bf,
    const float* __restrict__ c1w,  unsigned short* __restrict__ c1w_bf,
    const float* __restrict__ c2w,  unsigned short* __restrict__ c2w_bf,
    const float* __restrict__ c3w,  unsigned short* __restrict__ c3w_bf,
    const float* __restrict__ wihS, unsigned short* __restrict__ wihS_bf,
    const float* __restrict__ wihR, unsigned short* __restrict__ wihR_bf,
    const float* __restrict__ m0, const float* __restrict__ m1,
    const float* __restrict__ m2, const float* __restrict__ m3,
    const float* __restrict__ m4, const float* __restrict__ m5,
    unsigned int* __restrict__ wpk)
{
  const int job = blockIdx.y;
  const int stride = gridDim.x * blockDim.x;
  int e0 = blockIdx.x * blockDim.x + threadIdx.x;
  if (job == 0){
    for (int e = e0; e < 2048*1536; e += stride){
      int r = e / 1536, k = e - r*1536;
      data_bf[e] = (k < 1500) ? f2bf(data[(size_t)r*1500 + k]) : (unsigned short)0;
    }
  } else if (job == 1){
    for (int e = e0; e < 1024*1536; e += stride){
      int r = e / 1536, k = e - r*1536;
      l1w_bf[e] = (k < 1500) ? f2bf(l1w[(size_t)r*1500 + k]) : (unsigned short)0;
    }
  } else if (job == 2){
    for (int e = e0; e < 512*1024; e += stride) l2w_bf[e] = f2bf(l2w[e]);
  } else if (job == 3){
    for (int e = e0; e < 32*192; e += stride) c1w_bf[e] = f2bf(c1w[e]);
  } else if (job == 4){
    for (int e = e0; e < 64*512; e += stride){
      int oc = e >> 9, r = e & 511;
      int tap = r >> 5, ic = r & 31;
      c2w_bf[e] = f2bf(c2w[(size_t)oc*512 + ic*16 + tap]);
    }
  } else if (job == 5){
    for (int e = e0; e < 64*576; e += stride){
      int oc = e / 576, r = e - oc*576;
      int tap = r >> 6, ic = r & 63;
      c3w_bf[e] = f2bf(c3w[(size_t)oc*576 + ic*9 + tap]);
    }
  } else if (job == 6 || job == 7){
    const float* src = (job == 6) ? wihS : wihR;
    unsigned short* dst = (job == 6) ? wihS_bf : wihR_bf;
    for (int e = e0; e < 400*1536; e += stride){
      int g = e / 1536, k = e - g*1536;
      int ksrc = (k < 1024) ? ((k & 63)*16 + (k >> 6)) : k;
      dst[e] = f2bf(src[(size_t)g*1536 + ksrc]);
    }
  } else {
    const float* srcs[6] = {m0,m1,m2,m3,m4,m5};
    for (int e = e0; e < 6*20000; e += stride){
      int mat = e / 20000, r = e - mat*20000;
      int kk = r / 400, g = r - kk*400;
      const float* src = srcs[mat];
      unsigned int lo = f2h(src[g*100 + 2*kk]);
      unsigned int hi = f2h(src[g*100 + 2*kk + 1]);
      wpk[e] = lo | (hi << 16);
    }
  }
}

// ---------------------------------------------------------------------------
// bf16 MFMA GEMM (unchanged, passing since round 2)
// ---------------------------------------------------------------------------
template<int BM,int BN,int WAVES_M,int WAVES_N,int AMODE,int CMODE,int RELU,int NGUARD,
         int CIN,int HI,int WI,int KH,int KW,int ST,int HO,int WO>
__global__ __launch_bounds__(256) void mgemm(
    const void* __restrict__ Av, const unsigned short* __restrict__ B,
    void* __restrict__ Cv, const float* __restrict__ bias,
    int M, int N, int K, int lda, int ldc, int cstride)
{
  constexpr int BK = 64;
  constexpr int WROWS = BM / WAVES_M;
  constexpr int WCOLS = BN / WAVES_N;
  constexpr int MF = WROWS / 16;
  constexpr int NF = WCOLS / 16;
  constexpr int HOWO = HO*WO;
  __shared__ unsigned short As[BM*BK];
  __shared__ unsigned short Bs[BN*BK];
  const int tid = threadIdx.x;
  const int bm = blockIdx.x * BM;
  const int bn = blockIdx.y * BN;
  const int lane = tid & 63, w = tid >> 6;
  const int wm = w / WAVES_N, wn = w % WAVES_N;
  const int m0 = wm * WROWS, n0 = wn * WCOLS;

  f32x4 acc[MF][NF] = {};

  const int ar = tid >> 1;
  const int as0 = 4 * (tid & 1);
  const int row_g = bm + ar;
  int a_n = 0, a_oy = 0, a_ox = 0;
  if (AMODE != 0){ a_n = row_g / HOWO; int p = row_g - a_n*HOWO; a_oy = p / WO; a_ox = p - a_oy*WO; }

  for (int kt = 0; kt < K; kt += BK){
    #pragma unroll
    for (int si = 0; si < 4; ++si){
      int s = as0 + si;
      int k0 = kt + s*8;
      u16x8 val;
      if constexpr (AMODE == 0){
        val = *(const u16x8*)((const unsigned short*)Av + (size_t)row_g*lda + k0);
      } else if constexpr (AMODE == 1){
        int ic = k0 >> 6, r = k0 & 63, ky = r >> 3;
        const float* src = (const float*)Av +
            (((size_t)(a_n*CIN + ic)*HI + a_oy*ST + ky)*WI + a_ox*ST);
        f32x4 f0 = *(const f32x4*)src;
        f32x4 f1 = *(const f32x4*)(src + 4);
        val[0]=f2bf(f0[0]); val[1]=f2bf(f0[1]); val[2]=f2bf(f0[2]); val[3]=f2bf(f0[3]);
        val[4]=f2bf(f1[0]); val[5]=f2bf(f1[1]); val[6]=f2bf(f1[2]); val[7]=f2bf(f1[3]);
      } else {
        int tap = k0 / CIN, ic0 = k0 - tap*CIN;
        int ky = tap / KW, kx = tap - ky*KW;
        const unsigned short* src = (const unsigned short*)Av +
            (((size_t)(a_n*HI + a_oy*ST + ky)*WI + a_ox*ST + kx)*CIN + ic0);
        val = *(const u16x8*)src;
      }
      int phys = s ^ ((ar >> 1) & 7);
      *(u16x8*)&As[ar*BK + phys*8] = val;
    }
    if constexpr (BN == 64){
      int br = tid >> 2, bs0 = 2*(tid & 3);
      #pragma unroll
      for (int si = 0; si < 2; ++si){
        int s = bs0 + si, k0 = kt + s*8;
        int n_g = bn + br;
        u16x8 val = {};
        if (!NGUARD || n_g < N) val = *(const u16x8*)(B + (size_t)n_g*K + k0);
        int phys = s ^ ((br >> 1) & 7);
        *(u16x8*)&Bs[br*BK + phys*8] = val;
      }
    } else {
      int br = tid >> 3, s = tid & 7, k0 = kt + s*8;
      int n_g = bn + br;
      u16x8 val = {};
      if (!NGUARD || n_g < N) val = *(const u16x8*)(B + (size_t)n_g*K + k0);
      int phys = s ^ ((br >> 1) & 7);
      *(u16x8*)&Bs[br*BK + phys*8] = val;
    }
    __syncthreads();
    #pragma unroll
    for (int ks = 0; ks < 2; ++ks){
      s16x8 a[MF], b[NF];
      #pragma unroll
      for (int i = 0; i < MF; ++i){
        int row = m0 + i*16 + (lane & 15);
        int phys = (ks*4 + (lane >> 4)) ^ ((row >> 1) & 7);
        a[i] = *(const s16x8*)&As[row*BK + phys*8];
      }
      #pragma unroll
      for (int j = 0; j < NF; ++j){
        int row = n0 + j*16 + (lane & 15);
        int phys = (ks*4 + (lane >> 4)) ^ ((row >> 1) & 7);
        b[j] = *(const s16x8*)&Bs[row*BK + phys*8];
      }
      #pragma unroll
      for (int i = 0; i < MF; ++i)
        #pragma unroll
        for (int j = 0; j < NF; ++j)
          acc[i][j] = __builtin_amdgcn_mfma_f32_16x16x32_bf16(a[i], b[j], acc[i][j], 0, 0, 0);
    }
    __syncthreads();
  }

  if constexpr (CMODE == 3){
    float* Cf = (float*)Cv;
    #pragma unroll
    for (int i = 0; i < MF; ++i)
      #pragma unroll
      for (int j = 0; j < NF; ++j){
        int col = bn + n0 + j*16 + (lane & 15);
        float bv = (bias && (!NGUARD || col < N)) ? bias[col] : 0.f;
        #pragma unroll
        for (int q = 0; q < 4; ++q){
          int row = bm + m0 + i*16 + (lane >> 4)*4 + q;
          float v = acc[i][j][q] + bv;
          if (RELU) v = fmaxf(v, 0.f);
          if (!NGUARD || col < N) Cf[(size_t)row*ldc + col] = v;
        }
      }
  } else {
    unsigned short* tile = As;
    #pragma unroll
    for (int i = 0; i < MF; ++i)
      #pragma unroll
      for (int j = 0; j < NF; ++j){
        int col = n0 + j*16 + (lane & 15);
        float bv = bias ? bias[bn + col] : 0.f;
        #pragma unroll
        for (int q = 0; q < 4; ++q){
          int row = m0 + i*16 + (lane >> 4)*4 + q;
          float v = acc[i][j][q] + bv;
          if (RELU) v = fmaxf(v, 0.f);
          tile[row*BN + col] = f2bf(v);
        }
      }
    __syncthreads();
    unsigned short* Cu = (unsigned short*)Cv;
    constexpr int CHUNKS = (BM*BN)/(256*8);
    #pragma unroll
    for (int c = 0; c < CHUNKS; ++c){
      int flat = tid*8 + c*2048;
      int row = flat / BN, col = flat - (flat/BN)*BN;
      u16x8 v = *(const u16x8*)&tile[flat];
      int rg = bm + row;
      size_t addr;
      if constexpr (CMODE == 0) addr = (size_t)rg*ldc + bn + col;
      else { int n = rg >> 4, p = rg & 15; addr = (size_t)n*cstride + p*64 + col; }
      *(u16x8*)&Cu[addr] = v;
    }
  }
}

// ---------------------------------------------------------------------------
// LSTM: 2 segments per block (512 threads, 8 waves, 2 waves/SIMD; 16 blocks).
// Per segment (256 threads): e = tl>>1, sub = tl&1; sub0 owns gate rows
// i(e),g(e); sub1 owns f(e),o(e) -- 100 packed f16-pair weight u32/thread
// (fits the OBSERVED 128-VGPR budget of 512-thread blocks; r13 ran this
// exact per-thread code at VGPR 96). h broadcast ds_read_b128; shfl_xor(1)
// hands i*g to sub1 which keeps c in a register; double-buffered h ->
// 1 block barrier per step (uniform trip counts). Head fused per segment.
// ---------------------------------------------------------------------------
#define NSEG 2
__global__ __launch_bounds__(512,1) void lstm_k(
    const float* __restrict__ X0s, const float* __restrict__ X0r,
    const unsigned int* __restrict__ wpk,  // 6 x [50][400] u32 packed f16 pairs
    const float* __restrict__ s_bih0, const float* __restrict__ s_bhh0,
    const float* __restrict__ s_bih1, const float* __restrict__ s_bhh1,
    const float* __restrict__ r_bih0, const float* __restrict__ r_bhh0,
    const float* __restrict__ r_bih1, const float* __restrict__ r_bhh1,
    const float* __restrict__ f1w, const float* __restrict__ f1b,
    const float* __restrict__ f2w, const float* __restrict__ f2b,
    float* __restrict__ out)
{
  __shared__ alignas(16) unsigned int h0p[NSEG][2][56];
  __shared__ alignas(16) unsigned int h1p[NSEG][2][56];
  __shared__ alignas(16) unsigned int hbufp[NSEG][1792];  // 32 x 56 pairs
  __shared__ alignas(16) float Xl1[NSEG][12800];          // fp32, 32 x 400
  __shared__ float xin[NSEG][200];
  __shared__ float mid[NSEG][512];

  const int tid = threadIdx.x;
  const int sl = tid >> 8;                 // segment slot 0..1
  const int tl = tid & 255;
  const int b = blockIdx.x*NSEG + sl;
  const int e = tl >> 1, sub = tl & 1;
  const bool act = (e < 100);
  const int eS = act ? e : 0;
  const int gA = sub*100 + eS;             // sub0: i-gate, sub1: f-gate
  const int gB = gA + 200;                 // sub0: g-gate, sub1: o-gate

  if (tl < 56){ h0p[sl][0][tl]=0u; h0p[sl][1][tl]=0u; h1p[sl][0][tl]=0u; h1p[sl][1][tl]=0u; }
  for (int q = tl; q < 1792; q += 256) hbufp[sl][q] = 0u;
  float c0r = 0.f, c1r = 0.f;
  __syncthreads();

  #pragma unroll 1
  for (int s = 0; s < 2; ++s){
    const float* Xp = (s ? X0r : X0s) + (size_t)b*32*400;
    const unsigned int* w0P  = wpk + (size_t)(s ? 3 : 0)*20000;
    const unsigned int* w1xP = wpk + (size_t)(s ? 4 : 1)*20000;
    const unsigned int* w1hP = wpk + (size_t)(s ? 5 : 2)*20000;
    const float* bi0 = s ? r_bih0 : s_bih0;
    const float* bh0 = s ? r_bhh0 : s_bhh0;
    const float* bi1 = s ? r_bih1 : s_bih1;
    const float* bh1 = s ? r_bhh1 : s_bhh1;

    // ------------- layer 0 (recurrent; 1 barrier/step) -------------
    {
      unsigned int wA[50], wB[50];
      #pragma unroll
      for (int p = 0; p < 50; ++p){
        wA[p] = w0P[p*400 + gA];
        wB[p] = w0P[p*400 + gB];
      }
      float bsA = bi0[gA] + bh0[gA];
      float bsB = bi0[gB] + bh0[gB];
      float xcA = Xp[gA], xcB = Xp[gB], xnA, xnB;
      #pragma unroll 1
      for (int t = 0; t < 32; ++t){
        if (t < 31){ xnA = Xp[(t+1)*400 + gA]; xnB = Xp[(t+1)*400 + gB]; }
        const u32x4* h4 = (const u32x4*)h0p[sl][t & 1];
        float a0=0.f, a1=0.f, b0=0.f, b1=0.f;
        #pragma unroll
        for (int i = 0; i < 12; ++i){
          u32x4 hv = h4[i];
          a0 = dot2h(wA[4*i+0], hv[0], a0);
          a1 = dot2h(wA[4*i+1], hv[1], a1);
          a0 = dot2h(wA[4*i+2], hv[2], a0);
          a1 = dot2h(wA[4*i+3], hv[3], a1);
          b0 = dot2h(wB[4*i+0], hv[0], b0);
          b1 = dot2h(wB[4*i+1], hv[1], b1);
          b0 = dot2h(wB[4*i+2], hv[2], b0);
          b1 = dot2h(wB[4*i+3], hv[3], b1);
        }
        { u32x4 hv = h4[12];
          a0 = dot2h(wA[48], hv[0], a0);
          a1 = dot2h(wA[49], hv[1], a1);
          b0 = dot2h(wB[48], hv[0], b0);
          b1 = dot2h(wB[49], hv[1], b1);
        }
        float preA = (a0 + a1) + xcA + bsA;
        float preB = (b0 + b1) + xcB + bsB;
        float vA = sigmoidf_(preA);                       // i (sub0) / f (sub1)
        float vB = sub ? sigmoidf_(preB) : tanhf_(preB);  // o (sub1) / g (sub0)
        float send = vA * vB;                             // sub0: i*g
        float recv = __shfl_xor(send, 1);
        if (act && sub){
          c0r = vA*c0r + recv;
          float hn = vB * tanhf_(c0r);
          unsigned short hv16 = f2h(hn);
          ((unsigned short*)h0p[sl][(t+1) & 1])[e] = hv16;
          ((unsigned short*)hbufp[sl])[t*112 + e] = hv16;
        }
        xcA = xnA; xcB = xnB;
        __syncthreads();
      }
    }
    // ------- layer 1a: x-part pre-acts (batch; same-thread LDS, no barrier) -------
    {
      unsigned int wA[50], wB[50];
      #pragma unroll
      for (int p = 0; p < 50; ++p){
        wA[p] = w1xP[p*400 + gA];
        wB[p] = w1xP[p*400 + gB];
      }
      float bsA = bi1[gA] + bh1[gA];
      float bsB = bi1[gB] + bh1[gB];
      #pragma unroll 1
      for (int t = 0; t < 32; ++t){
        const u32x4* x4 = (const u32x4*)&hbufp[sl][t*56];
        float a0=0.f, a1=0.f, b0=0.f, b1=0.f;
        #pragma unroll
        for (int i = 0; i < 12; ++i){
          u32x4 hv = x4[i];
          a0 = dot2h(wA[4*i+0], hv[0], a0);
          a1 = dot2h(wA[4*i+1], hv[1], a1);
          a0 = dot2h(wA[4*i+2], hv[2], a0);
          a1 = dot2h(wA[4*i+3], hv[3], a1);
          b0 = dot2h(wB[4*i+0], hv[0], b0);
          b1 = dot2h(wB[4*i+1], hv[1], b1);
          b0 = dot2h(wB[4*i+2], hv[2], b0);
          b1 = dot2h(wB[4*i+3], hv[3], b1);
        }
        { u32x4 hv = x4[12];
          a0 = dot2h(wA[48], hv[0], a0);
          a1 = dot2h(wA[49], hv[1], a1);
          b0 = dot2h(wB[48], hv[0], b0);
          b1 = dot2h(wB[49], hv[1], b1);
        }
        if (act){
          Xl1[sl][t*400 + gA] = (a0 + a1) + bsA;
          Xl1[sl][t*400 + gB] = (b0 + b1) + bsB;
        }
      }
    }
    // ------------- layer 1b: recurrent (1 barrier/step) -------------
    {
      unsigned int wA[50], wB[50];
      #pragma unroll
      for (int p = 0; p < 50; ++p){
        wA[p] = w1hP[p*400 + gA];
        wB[p] = w1hP[p*400 + gB];
      }
      #pragma unroll 1
      for (int t = 0; t < 32; ++t){
        const u32x4* h4 = (const u32x4*)h1p[sl][t & 1];
        float a0=0.f, a1=0.f, b0=0.f, b1=0.f;
        #pragma unroll
        for (int i = 0; i < 12; ++i){
          u32x4 hv = h4[i];
          a0 = dot2h(wA[4*i+0], hv[0], a0);
          a1 = dot2h(wA[4*i+1], hv[1], a1);
          a0 = dot2h(wA[4*i+2], hv[2], a0);
          a1 = dot2h(wA[4*i+3], hv[3], a1);
          b0 = dot2h(wB[4*i+0], hv[0], b0);
          b1 = dot2h(wB[4*i+1], hv[1], b1);
          b0 = dot2h(wB[4*i+2], hv[2], b0);
          b1 = dot2h(wB[4*i+3], hv[3], b1);
        }
        { u32x4 hv = h4[12];
          a0 = dot2h(wA[48], hv[0], a0);
          a1 = dot2h(wA[49], hv[1], a1);
          b0 = dot2h(wB[48], hv[0], b0);
          b1 = dot2h(wB[49], hv[1], b1);
        }
        float preA = (a0 + a1) + Xl1[sl][t*400 + gA];
        float preB = (b0 + b1) + Xl1[sl][t*400 + gB];
        float vA = sigmoidf_(preA);
        float vB = sub ? sigmoidf_(preB) : tanhf_(preB);
        float send = vA * vB;
        float recv = __shfl_xor(send, 1);
        if (act && sub){
          c1r = vA*c1r + recv;
          float hn = vB * tanhf_(c1r);
          ((unsigned short*)h1p[sl][(t+1) & 1])[e] = f2h(hn);
          if (t == 31){
            if (s) xin[sl][e] = hn;          // outR -> head cols [0,100)
            else   xin[sl][100 + e] = hn;    // outS -> head cols [100,200)
          }
        }
        __syncthreads();
      }
    }
  }

  // ------------- fused head (per segment) -------------
  for (int r = tl; r < 512; r += 256){
    float acc = f1b[r];
    const float* wrow = f1w + (size_t)r*200;
    #pragma unroll 4
    for (int k = 0; k < 200; ++k) acc += xin[sl][k]*wrow[k];
    mid[sl][r] = fmaxf(acc, 0.f);
  }
  __syncthreads();
  if (tl < 130){
    float acc = f2b[tl];
    const float* wrow = f2w + (size_t)tl*512;
    #pragma unroll 4
    for (int k = 0; k < 512; ++k) acc += mid[sl][k]*wrow[k];
    out[b*130 + tl] = acc;
  }
}

extern "C" void kernel_launch(void* const* d_in, const int* in_sizes, int n_in,
                              void* d_out, int out_size, void* d_ws, size_t ws_size,
                              hipStream_t stream)
{
  const float* obs  = (const float*)d_in[0];
  const float* data = (const float*)d_in[1];
  const float* c1w = (const float*)d_in[2];  const float* c1b = (const float*)d_in[3];
  const float* c2w = (const float*)d_in[4];  const float* c2b = (const float*)d_in[5];
  const float* c3w = (const float*)d_in[6];  const float* c3b = (const float*)d_in[7];
  const float* l1w = (const float*)d_in[8];  const float* l1b = (const float*)d_in[9];
  const float* l2w = (const float*)d_in[10]; const float* l2b = (const float*)d_in[11];
  const float* s_wih0=(const float*)d_in[12]; const float* s_whh0=(const float*)d_in[13];
  const float* s_bih0=(const float*)d_in[14]; const float* s_bhh0=(const float*)d_in[15];
  const float* s_wih1=(const float*)d_in[16]; const float* s_whh1=(const float*)d_in[17];
  const float* s_bih1=(const float*)d_in[18]; const float* s_bhh1=(const float*)d_in[19];
  const float* r_wih0=(const float*)d_in[20]; const float* r_whh0=(const float*)d_in[21];
  const float* r_bih0=(const float*)d_in[22]; const float* r_bhh0=(const float*)d_in[23];
  const float* r_wih1=(const float*)d_in[24]; const float* r_whh1=(const float*)d_in[25];
  const float* r_bih1=(const float*)d_in[26]; const float* r_bhh1=(const float*)d_in[27];
  const float* f1w=(const float*)d_in[28]; const float* f1b=(const float*)d_in[29];
  const float* f2w=(const float*)d_in[30]; const float* f2b=(const float*)d_in[31];
  float* out = (float*)d_out;
  (void)in_sizes; (void)n_in; (void)out_size;

  // ---- workspace layout (bytes, 256-aligned); total ~ 67 MB ----
  char* p = (char*)d_ws;
  auto alloc = [&](size_t bytes){ void* r = (void*)p; p += (bytes + 255) & ~(size_t)255; return r; };
  unsigned short* data_bf = (unsigned short*)alloc((size_t)2048*1536*2);
  unsigned short* c1w_bf  = (unsigned short*)alloc((size_t)32*192*2);
  unsigned short* c2w_bf  = (unsigned short*)alloc((size_t)64*512*2);
  unsigned short* c3w_bf  = (unsigned short*)alloc((size_t)64*576*2);
  unsigned short* l1w_bf  = (unsigned short*)alloc((size_t)1024*1536*2);
  unsigned short* l2w_bf  = (unsigned short*)alloc((size_t)512*1024*2);
  unsigned short* wihS_bf = (unsigned short*)alloc((size_t)400*1536*2);
  unsigned short* wihR_bf = (unsigned short*)alloc((size_t)400*1536*2);
  unsigned short* conv1o  = (unsigned short*)alloc((size_t)2048*225*32*2);  // NHWC
  unsigned short* conv2o  = (unsigned short*)alloc((size_t)2048*36*64*2);   // NHWC
  unsigned short* feat    = (unsigned short*)alloc((size_t)2048*1536*2);
  unsigned short* lin1o   = (unsigned short*)alloc((size_t)2048*1024*2);
  float* X0s  = (float*)alloc((size_t)1024*400*4);
  float* X0r  = (float*)alloc((size_t)1024*400*4);
  unsigned int* wpk = (unsigned int*)alloc((size_t)6*20000*4);
  (void)ws_size;

  // ---- merged prep (1 launch) ----
  prep_k<<<dim3(512,9),256,0,stream>>>(
      data, data_bf, l1w, l1w_bf, l2w, l2w_bf, c1w, c1w_bf,
      c2w, c2w_bf, c3w, c3w_bf, s_wih0, wihS_bf, r_wih0, wihR_bf,
      s_whh0, s_wih1, s_whh1, r_whh0, r_wih1, r_whh1, wpk);

  // ---- GEMM chain (bf16 MFMA, fp32 accumulate) ----
  mgemm<128,32,4,1, 1,0,1,0, 3,64,64,8,8,4,15,15><<<dim3(3600,1),256,0,stream>>>(
      obs, c1w_bf, conv1o, c1b, 460800, 32, 192, 0, 32, 0);
  mgemm<128,64,2,2, 2,0,1,0, 32,15,15,4,4,2,6,6><<<dim3(576,1),256,0,stream>>>(
      conv1o, c2w_bf, conv2o, c2b, 73728, 64, 512, 0, 64, 0);
  mgemm<128,64,2,2, 0,0,1,0, 1,1,1,1,1,1,1,1><<<dim3(16,16),256,0,stream>>>(
      data_bf, l1w_bf, lin1o, l1b, 2048, 1024, 1536, 1536, 1024, 0);
  mgemm<128,64,2,2, 2,2,1,0, 64,6,6,3,3,1,4,4><<<dim3(256,1),256,0,stream>>>(
      conv2o, c3w_bf, feat, c3b, 32768, 64, 576, 0, 0, 1536);
  mgemm<128,64,2,2, 0,0,0,0, 1,1,1,1,1,1,1,1><<<dim3(16,8),256,0,stream>>>(
      lin1o, l2w_bf, feat + 1024, l2b, 2048, 512, 1024, 1024, 1536, 0);
  mgemm<128,64,2,2, 0,3,0,1, 1,1,1,1,1,1,1,1><<<dim3(8,7),256,0,stream>>>(
      feat, wihS_bf, X0s, (const float*)nullptr, 1024, 400, 1536, 1536, 400, 0);
  mgemm<128,64,2,2, 0,3,0,1, 1,1,1,1,1,1,1,1><<<dim3(8,7),256,0,stream>>>(
      feat + (size_t)1024*1536, wihR_bf, X0r, (const float*)nullptr, 1024, 400, 1536, 1536, 400, 0);

  // ---- sequential LSTM (2 segments/block) + fused head ----
  lstm_k<<<16,512,0,stream>>>(X0s, X0r, wpk,
                              s_bih0,s_bhh0,s_bih1,s_bhh1,
                              r_bih0,r_bhh0,r_bih1,r_bhh1,
                              f1w, f1b, f2w, f2b, out);
}

// Round 16
// 331.351 us; speedup vs baseline: 3.2805x; 1.1817x over previous
//
#include <hip/hip_runtime.h>
#include <hip/hip_fp16.h>
#include <math.h>

// ---------------------------------------------------------------------------
// NatureCNN: conv×3 (implicit-im2col bf16 MFMA GEMMs, NHWC intermediates)
// | lin1+relu -> lin2 (bf16 MFMA) -> concat feat -> wih0 pre-act GEMMs (fp32)
// -> 2×(2-layer LSTM) -> fused head.
// Round 16: restore the verified optimum (r13, 331.2us). r15's 2-seg/block
// TLP regressed (221us lstm): the per-step __syncthreads is a SHARED barrier
// across segments -> no relative slip -> latencies add; and CU count halved.
// LSTM config: 32 blocks x 256 thr (1 seg each, independent barrier domain),
// thread pair (e,sub) owns 2 full gate rows (100 packed f16-pair u32 regs,
// spill-free at the observed 256-budget of 256-thread blocks).
// ---------------------------------------------------------------------------

typedef __attribute__((ext_vector_type(4))) float f32x4;
typedef __attribute__((ext_vector_type(8))) short s16x8;
typedef __attribute__((ext_vector_type(8))) unsigned short u16x8;
typedef __attribute__((ext_vector_type(4))) unsigned int u32x4;

__device__ __forceinline__ unsigned short f2bf(float f){
  union { float f; unsigned int u; } v; v.f = f;
  unsigned int r = (v.u + 0x7fffu + ((v.u >> 16) & 1u)) >> 16;
  return (unsigned short)r;
}
__device__ __forceinline__ unsigned short f2h(float f){
  return __half_as_ushort(__float2half(f));
}
__device__ __forceinline__ float sigmoidf_(float x){ return 1.0f/(1.0f+__expf(-x)); }
__device__ __forceinline__ float tanhf_(float x){
  float e = __expf(-2.0f*fabsf(x));
  float t = (1.0f - e)/(1.0f + e);
  return copysignf(t, x);
}

#if __has_builtin(__builtin_amdgcn_fdot2)
typedef _Float16 f16x2 __attribute__((ext_vector_type(2)));
__device__ __forceinline__ float dot2h(unsigned int a, unsigned int b, float c){
  union { unsigned int u; f16x2 h; } ua, ub;
  ua.u = a; ub.u = b;
  return __builtin_amdgcn_fdot2(ua.h, ub.h, c, false);
}
#else
__device__ __forceinline__ float dot2h(unsigned int a, unsigned int b, float c){
  __half2 ha = *(__half2*)&a, hb = *(__half2*)&b;
  float2 fa = __half22float2(ha), fb = __half22float2(hb);
  return c + fa.x*fb.x + fa.y*fb.y;
}
#endif

// ---------------------------------------------------------------------------
// ONE merged prep kernel.
// ---------------------------------------------------------------------------
__global__ void prep_k(
    const float* __restrict__ data, unsigned short* __restrict__ data_bf,
    const float* __restrict__ l1w,  unsigned short* __restrict__ l1w_bf,
    const float* __restrict__ l2w,  unsigned short* __restrict__ l2w_bf,
    const float* __restrict__ c1w,  unsigned short* __restrict__ c1w_bf,
    const float* __restrict__ c2w,  unsigned short* __restrict__ c2w_bf,
    const float* __restrict__ c3w,  unsigned short* __restrict__ c3w_bf,
    const float* __restrict__ wihS, unsigned short* __restrict__ wihS_bf,
    const float* __restrict__ wihR, unsigned short* __restrict__ wihR_bf,
    const float* __restrict__ m0, const float* __restrict__ m1,
    const float* __restrict__ m2, const float* __restrict__ m3,
    const float* __restrict__ m4, const float* __restrict__ m5,
    unsigned int* __restrict__ wpk)
{
  const int job = blockIdx.y;
  const int stride = gridDim.x * blockDim.x;
  int e0 = blockIdx.x * blockDim.x + threadIdx.x;
  if (job == 0){
    for (int e = e0; e < 2048*1536; e += stride){
      int r = e / 1536, k = e - r*1536;
      data_bf[e] = (k < 1500) ? f2bf(data[(size_t)r*1500 + k]) : (unsigned short)0;
    }
  } else if (job == 1){
    for (int e = e0; e < 1024*1536; e += stride){
      int r = e / 1536, k = e - r*1536;
      l1w_bf[e] = (k < 1500) ? f2bf(l1w[(size_t)r*1500 + k]) : (unsigned short)0;
    }
  } else if (job == 2){
    for (int e = e0; e < 512*1024; e += stride) l2w_bf[e] = f2bf(l2w[e]);
  } else if (job == 3){
    for (int e = e0; e < 32*192; e += stride) c1w_bf[e] = f2bf(c1w[e]);
  } else if (job == 4){
    for (int e = e0; e < 64*512; e += stride){
      int oc = e >> 9, r = e & 511;
      int tap = r >> 5, ic = r & 31;
      c2w_bf[e] = f2bf(c2w[(size_t)oc*512 + ic*16 + tap]);
    }
  } else if (job == 5){
    for (int e = e0; e < 64*576; e += stride){
      int oc = e / 576, r = e - oc*576;
      int tap = r >> 6, ic = r & 63;
      c3w_bf[e] = f2bf(c3w[(size_t)oc*576 + ic*9 + tap]);
    }
  } else if (job == 6 || job == 7){
    const float* src = (job == 6) ? wihS : wihR;
    unsigned short* dst = (job == 6) ? wihS_bf : wihR_bf;
    for (int e = e0; e < 400*1536; e += stride){
      int g = e / 1536, k = e - g*1536;
      int ksrc = (k < 1024) ? ((k & 63)*16 + (k >> 6)) : k;
      dst[e] = f2bf(src[(size_t)g*1536 + ksrc]);
    }
  } else {
    const float* srcs[6] = {m0,m1,m2,m3,m4,m5};
    for (int e = e0; e < 6*20000; e += stride){
      int mat = e / 20000, r = e - mat*20000;
      int kk = r / 400, g = r - kk*400;
      const float* src = srcs[mat];
      unsigned int lo = f2h(src[g*100 + 2*kk]);
      unsigned int hi = f2h(src[g*100 + 2*kk + 1]);
      wpk[e] = lo | (hi << 16);
    }
  }
}

// ---------------------------------------------------------------------------
// bf16 MFMA GEMM (unchanged, passing since round 2)
// ---------------------------------------------------------------------------
template<int BM,int BN,int WAVES_M,int WAVES_N,int AMODE,int CMODE,int RELU,int NGUARD,
         int CIN,int HI,int WI,int KH,int KW,int ST,int HO,int WO>
__global__ __launch_bounds__(256) void mgemm(
    const void* __restrict__ Av, const unsigned short* __restrict__ B,
    void* __restrict__ Cv, const float* __restrict__ bias,
    int M, int N, int K, int lda, int ldc, int cstride)
{
  constexpr int BK = 64;
  constexpr int WROWS = BM / WAVES_M;
  constexpr int WCOLS = BN / WAVES_N;
  constexpr int MF = WROWS / 16;
  constexpr int NF = WCOLS / 16;
  constexpr int HOWO = HO*WO;
  __shared__ unsigned short As[BM*BK];
  __shared__ unsigned short Bs[BN*BK];
  const int tid = threadIdx.x;
  const int bm = blockIdx.x * BM;
  const int bn = blockIdx.y * BN;
  const int lane = tid & 63, w = tid >> 6;
  const int wm = w / WAVES_N, wn = w % WAVES_N;
  const int m0 = wm * WROWS, n0 = wn * WCOLS;

  f32x4 acc[MF][NF] = {};

  const int ar = tid >> 1;
  const int as0 = 4 * (tid & 1);
  const int row_g = bm + ar;
  int a_n = 0, a_oy = 0, a_ox = 0;
  if (AMODE != 0){ a_n = row_g / HOWO; int p = row_g - a_n*HOWO; a_oy = p / WO; a_ox = p - a_oy*WO; }

  for (int kt = 0; kt < K; kt += BK){
    #pragma unroll
    for (int si = 0; si < 4; ++si){
      int s = as0 + si;
      int k0 = kt + s*8;
      u16x8 val;
      if constexpr (AMODE == 0){
        val = *(const u16x8*)((const unsigned short*)Av + (size_t)row_g*lda + k0);
      } else if constexpr (AMODE == 1){
        int ic = k0 >> 6, r = k0 & 63, ky = r >> 3;
        const float* src = (const float*)Av +
            (((size_t)(a_n*CIN + ic)*HI + a_oy*ST + ky)*WI + a_ox*ST);
        f32x4 f0 = *(const f32x4*)src;
        f32x4 f1 = *(const f32x4*)(src + 4);
        val[0]=f2bf(f0[0]); val[1]=f2bf(f0[1]); val[2]=f2bf(f0[2]); val[3]=f2bf(f0[3]);
        val[4]=f2bf(f1[0]); val[5]=f2bf(f1[1]); val[6]=f2bf(f1[2]); val[7]=f2bf(f1[3]);
      } else {
        int tap = k0 / CIN, ic0 = k0 - tap*CIN;
        int ky = tap / KW, kx = tap - ky*KW;
        const unsigned short* src = (const unsigned short*)Av +
            (((size_t)(a_n*HI + a_oy*ST + ky)*WI + a_ox*ST + kx)*CIN + ic0);
        val = *(const u16x8*)src;
      }
      int phys = s ^ ((ar >> 1) & 7);
      *(u16x8*)&As[ar*BK + phys*8] = val;
    }
    if constexpr (BN == 64){
      int br = tid >> 2, bs0 = 2*(tid & 3);
      #pragma unroll
      for (int si = 0; si < 2; ++si){
        int s = bs0 + si, k0 = kt + s*8;
        int n_g = bn + br;
        u16x8 val = {};
        if (!NGUARD || n_g < N) val = *(const u16x8*)(B + (size_t)n_g*K + k0);
        int phys = s ^ ((br >> 1) & 7);
        *(u16x8*)&Bs[br*BK + phys*8] = val;
      }
    } else {
      int br = tid >> 3, s = tid & 7, k0 = kt + s*8;
      int n_g = bn + br;
      u16x8 val = {};
      if (!NGUARD || n_g < N) val = *(const u16x8*)(B + (size_t)n_g*K + k0);
      int phys = s ^ ((br >> 1) & 7);
      *(u16x8*)&Bs[br*BK + phys*8] = val;
    }
    __syncthreads();
    #pragma unroll
    for (int ks = 0; ks < 2; ++ks){
      s16x8 a[MF], b[NF];
      #pragma unroll
      for (int i = 0; i < MF; ++i){
        int row = m0 + i*16 + (lane & 15);
        int phys = (ks*4 + (lane >> 4)) ^ ((row >> 1) & 7);
        a[i] = *(const s16x8*)&As[row*BK + phys*8];
      }
      #pragma unroll
      for (int j = 0; j < NF; ++j){
        int row = n0 + j*16 + (lane & 15);
        int phys = (ks*4 + (lane >> 4)) ^ ((row >> 1) & 7);
        b[j] = *(const s16x8*)&Bs[row*BK + phys*8];
      }
      #pragma unroll
      for (int i = 0; i < MF; ++i)
        #pragma unroll
        for (int j = 0; j < NF; ++j)
          acc[i][j] = __builtin_amdgcn_mfma_f32_16x16x32_bf16(a[i], b[j], acc[i][j], 0, 0, 0);
    }
    __syncthreads();
  }

  if constexpr (CMODE == 3){
    float* Cf = (float*)Cv;
    #pragma unroll
    for (int i = 0; i < MF; ++i)
      #pragma unroll
      for (int j = 0; j < NF; ++j){
        int col = bn + n0 + j*16 + (lane & 15);
        float bv = (bias && (!NGUARD || col < N)) ? bias[col] : 0.f;
        #pragma unroll
        for (int q = 0; q < 4; ++q){
          int row = bm + m0 + i*16 + (lane >> 4)*4 + q;
          float v = acc[i][j][q] + bv;
          if (RELU) v = fmaxf(v, 0.f);
          if (!NGUARD || col < N) Cf[(size_t)row*ldc + col] = v;
        }
      }
  } else {
    unsigned short* tile = As;
    #pragma unroll
    for (int i = 0; i < MF; ++i)
      #pragma unroll
      for (int j = 0; j < NF; ++j){
        int col = n0 + j*16 + (lane & 15);
        float bv = bias ? bias[bn + col] : 0.f;
        #pragma unroll
        for (int q = 0; q < 4; ++q){
          int row = m0 + i*16 + (lane >> 4)*4 + q;
          float v = acc[i][j][q] + bv;
          if (RELU) v = fmaxf(v, 0.f);
          tile[row*BN + col] = f2bf(v);
        }
      }
    __syncthreads();
    unsigned short* Cu = (unsigned short*)Cv;
    constexpr int CHUNKS = (BM*BN)/(256*8);
    #pragma unroll
    for (int c = 0; c < CHUNKS; ++c){
      int flat = tid*8 + c*2048;
      int row = flat / BN, col = flat - (flat/BN)*BN;
      u16x8 v = *(const u16x8*)&tile[flat];
      int rg = bm + row;
      size_t addr;
      if constexpr (CMODE == 0) addr = (size_t)rg*ldc + bn + col;
      else { int n = rg >> 4, p = rg & 15; addr = (size_t)n*cstride + p*64 + col; }
      *(u16x8*)&Cu[addr] = v;
    }
  }
}

// ---------------------------------------------------------------------------
// LSTM (r13 exact): one block per segment; both stacks. 256 threads (4 waves).
// e = tid>>1 (element, <100 active), sub = tid&1. sub0 owns full gate rows
// i(e),g(e); sub1 owns f(e),o(e) -- 100 packed f16-pair weight u32/thread,
// full 50-pair dots in-register. h: 50 packed u32 in LDS, 13 broadcast
// ds_read_b128 per wave. sub0 sends i*g via shfl_xor(1); sub1 holds c in a
// register, writes h to the double-buffered h (read t&1, write (t+1)&1):
// 1 barrier/step. L1a batches x-part into LDS (same-thread, no barriers).
// Head fused.
// ---------------------------------------------------------------------------
__global__ __launch_bounds__(256,1) void lstm_k(
    const float* __restrict__ X0s, const float* __restrict__ X0r,
    const unsigned int* __restrict__ wpk,  // 6 x [50][400] u32 packed f16 pairs
    const float* __restrict__ s_bih0, const float* __restrict__ s_bhh0,
    const float* __restrict__ s_bih1, const float* __restrict__ s_bhh1,
    const float* __restrict__ r_bih0, const float* __restrict__ r_bhh0,
    const float* __restrict__ r_bih1, const float* __restrict__ r_bhh1,
    const float* __restrict__ f1w, const float* __restrict__ f1b,
    const float* __restrict__ f2w, const float* __restrict__ f2b,
    float* __restrict__ out)
{
  __shared__ alignas(16) unsigned int h0p[2][56];   // dbuf, 50 pairs (+pad)
  __shared__ alignas(16) unsigned int h1p[2][56];
  __shared__ alignas(16) unsigned int hbufp[1792];  // 32 steps x 56 pairs
  __shared__ alignas(16) float Xl1[12800];          // layer-1 x-part, 32 x 400
  __shared__ float xin[200];                        // head input [outR|outS]
  __shared__ float mid[512];                        // head hidden

  const int b = blockIdx.x, tid = threadIdx.x;
  const int e = tid >> 1, sub = tid & 1;
  const bool act = (e < 100);
  const int eS = act ? e : 0;            // clamped for safe addressing
  const int gA = sub*100 + eS;           // sub0: i-gate, sub1: f-gate
  const int gB = gA + 200;               // sub0: g-gate, sub1: o-gate

  if (tid < 56){ h0p[0][tid]=0u; h0p[1][tid]=0u; h1p[0][tid]=0u; h1p[1][tid]=0u; }
  for (int q = tid; q < 1792; q += 256) hbufp[q] = 0u;
  float c0r = 0.f, c1r = 0.f;
  __syncthreads();

  #pragma unroll 1
  for (int s = 0; s < 2; ++s){
    const float* Xp = (s ? X0r : X0s) + (size_t)b*32*400;
    const unsigned int* w0P  = wpk + (size_t)(s ? 3 : 0)*20000;
    const unsigned int* w1xP = wpk + (size_t)(s ? 4 : 1)*20000;
    const unsigned int* w1hP = wpk + (size_t)(s ? 5 : 2)*20000;
    const float* bi0 = s ? r_bih0 : s_bih0;
    const float* bh0 = s ? r_bhh0 : s_bhh0;
    const float* bi1 = s ? r_bih1 : s_bih1;
    const float* bh1 = s ? r_bhh1 : s_bhh1;

    // ------------- layer 0 (recurrent; 1 barrier/step) -------------
    {
      unsigned int wA[50], wB[50];
      #pragma unroll
      for (int p = 0; p < 50; ++p){
        wA[p] = w0P[p*400 + gA];
        wB[p] = w0P[p*400 + gB];
      }
      float bsA = bi0[gA] + bh0[gA];
      float bsB = bi0[gB] + bh0[gB];
      float xcA = Xp[gA], xcB = Xp[gB], xnA, xnB;
      #pragma unroll 1
      for (int t = 0; t < 32; ++t){
        if (t < 31){ xnA = Xp[(t+1)*400 + gA]; xnB = Xp[(t+1)*400 + gB]; }
        const u32x4* h4 = (const u32x4*)h0p[t & 1];
        float a0=0.f, a1=0.f, b0=0.f, b1=0.f;
        #pragma unroll
        for (int i = 0; i < 12; ++i){
          u32x4 hv = h4[i];
          a0 = dot2h(wA[4*i+0], hv[0], a0);
          a1 = dot2h(wA[4*i+1], hv[1], a1);
          a0 = dot2h(wA[4*i+2], hv[2], a0);
          a1 = dot2h(wA[4*i+3], hv[3], a1);
          b0 = dot2h(wB[4*i+0], hv[0], b0);
          b1 = dot2h(wB[4*i+1], hv[1], b1);
          b0 = dot2h(wB[4*i+2], hv[2], b0);
          b1 = dot2h(wB[4*i+3], hv[3], b1);
        }
        { u32x4 hv = h4[12];
          a0 = dot2h(wA[48], hv[0], a0);
          a1 = dot2h(wA[49], hv[1], a1);
          b0 = dot2h(wB[48], hv[0], b0);
          b1 = dot2h(wB[49], hv[1], b1);
        }
        float preA = (a0 + a1) + xcA + bsA;
        float preB = (b0 + b1) + xcB + bsB;
        float vA = sigmoidf_(preA);                       // i (sub0) / f (sub1)
        float vB = sub ? sigmoidf_(preB) : tanhf_(preB);  // o (sub1) / g (sub0)
        float send = vA * vB;                             // sub0: i*g
        float recv = __shfl_xor(send, 1);
        if (act && sub){
          c0r = vA*c0r + recv;
          float hn = vB * tanhf_(c0r);
          unsigned short hv16 = f2h(hn);
          ((unsigned short*)h0p[(t+1) & 1])[e] = hv16;
          ((unsigned short*)hbufp)[t*112 + e] = hv16;
        }
        xcA = xnA; xcB = xnB;
        __syncthreads();
      }
    }
    // ------- layer 1a: x-part pre-acts (batch; same-thread LDS, no barrier) -------
    {
      unsigned int wA[50], wB[50];
      #pragma unroll
      for (int p = 0; p < 50; ++p){
        wA[p] = w1xP[p*400 + gA];
        wB[p] = w1xP[p*400 + gB];
      }
      float bsA = bi1[gA] + bh1[gA];
      float bsB = bi1[gB] + bh1[gB];
      #pragma unroll 1
      for (int t = 0; t < 32; ++t){
        const u32x4* x4 = (const u32x4*)&hbufp[t*56];
        float a0=0.f, a1=0.f, b0=0.f, b1=0.f;
        #pragma unroll
        for (int i = 0; i < 12; ++i){
          u32x4 hv = x4[i];
          a0 = dot2h(wA[4*i+0], hv[0], a0);
          a1 = dot2h(wA[4*i+1], hv[1], a1);
          a0 = dot2h(wA[4*i+2], hv[2], a0);
          a1 = dot2h(wA[4*i+3], hv[3], a1);
          b0 = dot2h(wB[4*i+0], hv[0], b0);
          b1 = dot2h(wB[4*i+1], hv[1], b1);
          b0 = dot2h(wB[4*i+2], hv[2], b0);
          b1 = dot2h(wB[4*i+3], hv[3], b1);
        }
        { u32x4 hv = x4[12];
          a0 = dot2h(wA[48], hv[0], a0);
          a1 = dot2h(wA[49], hv[1], a1);
          b0 = dot2h(wB[48], hv[0], b0);
          b1 = dot2h(wB[49], hv[1], b1);
        }
        if (act){
          Xl1[t*400 + gA] = (a0 + a1) + bsA;
          Xl1[t*400 + gB] = (b0 + b1) + bsB;
        }
      }
    }
    // ------------- layer 1b: recurrent (1 barrier/step) -------------
    {
      unsigned int wA[50], wB[50];
      #pragma unroll
      for (int p = 0; p < 50; ++p){
        wA[p] = w1hP[p*400 + gA];
        wB[p] = w1hP[p*400 + gB];
      }
      #pragma unroll 1
      for (int t = 0; t < 32; ++t){
        const u32x4* h4 = (const u32x4*)h1p[t & 1];
        float a0=0.f, a1=0.f, b0=0.f, b1=0.f;
        #pragma unroll
        for (int i = 0; i < 12; ++i){
          u32x4 hv = h4[i];
          a0 = dot2h(wA[4*i+0], hv[0], a0);
          a1 = dot2h(wA[4*i+1], hv[1], a1);
          a0 = dot2h(wA[4*i+2], hv[2], a0);
          a1 = dot2h(wA[4*i+3], hv[3], a1);
          b0 = dot2h(wB[4*i+0], hv[0], b0);
          b1 = dot2h(wB[4*i+1], hv[1], b1);
          b0 = dot2h(wB[4*i+2], hv[2], b0);
          b1 = dot2h(wB[4*i+3], hv[3], b1);
        }
        { u32x4 hv = h4[12];
          a0 = dot2h(wA[48], hv[0], a0);
          a1 = dot2h(wA[49], hv[1], a1);
          b0 = dot2h(wB[48], hv[0], b0);
          b1 = dot2h(wB[49], hv[1], b1);
        }
        float preA = (a0 + a1) + Xl1[t*400 + gA];
        float preB = (b0 + b1) + Xl1[t*400 + gB];
        float vA = sigmoidf_(preA);
        float vB = sub ? sigmoidf_(preB) : tanhf_(preB);
        float send = vA * vB;
        float recv = __shfl_xor(send, 1);
        if (act && sub){
          c1r = vA*c1r + recv;
          float hn = vB * tanhf_(c1r);
          ((unsigned short*)h1p[(t+1) & 1])[e] = f2h(hn);
          if (t == 31){
            if (s) xin[e] = hn;          // outR -> head cols [0,100)
            else   xin[100 + e] = hn;    // outS -> head cols [100,200)
          }
        }
        __syncthreads();
      }
    }
  }

  // ------------- fused head: out[b] = relu(xin@f1w^T+b1)@f2w^T+b2 -------------
  for (int r = tid; r < 512; r += 256){
    float acc = f1b[r];
    const float* wrow = f1w + (size_t)r*200;
    #pragma unroll 4
    for (int k = 0; k < 200; ++k) acc += xin[k]*wrow[k];
    mid[r] = fmaxf(acc, 0.f);
  }
  __syncthreads();
  if (tid < 130){
    float acc = f2b[tid];
    const float* wrow = f2w + (size_t)tid*512;
    #pragma unroll 4
    for (int k = 0; k < 512; ++k) acc += mid[k]*wrow[k];
    out[b*130 + tid] = acc;
  }
}

extern "C" void kernel_launch(void* const* d_in, const int* in_sizes, int n_in,
                              void* d_out, int out_size, void* d_ws, size_t ws_size,
                              hipStream_t stream)
{
  const float* obs  = (const float*)d_in[0];
  const float* data = (const float*)d_in[1];
  const float* c1w = (const float*)d_in[2];  const float* c1b = (const float*)d_in[3];
  const float* c2w = (const float*)d_in[4];  const float* c2b = (const float*)d_in[5];
  const float* c3w = (const float*)d_in[6];  const float* c3b = (const float*)d_in[7];
  const float* l1w = (const float*)d_in[8];  const float* l1b = (const float*)d_in[9];
  const float* l2w = (const float*)d_in[10]; const float* l2b = (const float*)d_in[11];
  const float* s_wih0=(const float*)d_in[12]; const float* s_whh0=(const float*)d_in[13];
  const float* s_bih0=(const float*)d_in[14]; const float* s_bhh0=(const float*)d_in[15];
  const float* s_wih1=(const float*)d_in[16]; const float* s_whh1=(const float*)d_in[17];
  const float* s_bih1=(const float*)d_in[18]; const float* s_bhh1=(const float*)d_in[19];
  const float* r_wih0=(const float*)d_in[20]; const float* r_whh0=(const float*)d_in[21];
  const float* r_bih0=(const float*)d_in[22]; const float* r_bhh0=(const float*)d_in[23];
  const float* r_wih1=(const float*)d_in[24]; const float* r_whh1=(const float*)d_in[25];
  const float* r_bih1=(const float*)d_in[26]; const float* r_bhh1=(const float*)d_in[27];
  const float* f1w=(const float*)d_in[28]; const float* f1b=(const float*)d_in[29];
  const float* f2w=(const float*)d_in[30]; const float* f2b=(const float*)d_in[31];
  float* out = (float*)d_out;
  (void)in_sizes; (void)n_in; (void)out_size;

  // ---- workspace layout (bytes, 256-aligned); total ~ 67 MB ----
  char* p = (char*)d_ws;
  auto alloc = [&](size_t bytes){ void* r = (void*)p; p += (bytes + 255) & ~(size_t)255; return r; };
  unsigned short* data_bf = (unsigned short*)alloc((size_t)2048*1536*2);
  unsigned short* c1w_bf  = (unsigned short*)alloc((size_t)32*192*2);
  unsigned short* c2w_bf  = (unsigned short*)alloc((size_t)64*512*2);
  unsigned short* c3w_bf  = (unsigned short*)alloc((size_t)64*576*2);
  unsigned short* l1w_bf  = (unsigned short*)alloc((size_t)1024*1536*2);
  unsigned short* l2w_bf  = (unsigned short*)alloc((size_t)512*1024*2);
  unsigned short* wihS_bf = (unsigned short*)alloc((size_t)400*1536*2);
  unsigned short* wihR_bf = (unsigned short*)alloc((size_t)400*1536*2);
  unsigned short* conv1o  = (unsigned short*)alloc((size_t)2048*225*32*2);  // NHWC
  unsigned short* conv2o  = (unsigned short*)alloc((size_t)2048*36*64*2);   // NHWC
  unsigned short* feat    = (unsigned short*)alloc((size_t)2048*1536*2);
  unsigned short* lin1o   = (unsigned short*)alloc((size_t)2048*1024*2);
  float* X0s  = (float*)alloc((size_t)1024*400*4);
  float* X0r  = (float*)alloc((size_t)1024*400*4);
  unsigned int* wpk = (unsigned int*)alloc((size_t)6*20000*4);
  (void)ws_size;

  // ---- merged prep (1 launch) ----
  prep_k<<<dim3(512,9),256,0,stream>>>(
      data, data_bf, l1w, l1w_bf, l2w, l2w_bf, c1w, c1w_bf,
      c2w, c2w_bf, c3w, c3w_bf, s_wih0, wihS_bf, r_wih0, wihR_bf,
      s_whh0, s_wih1, s_whh1, r_whh0, r_wih1, r_whh1, wpk);

  // ---- GEMM chain (bf16 MFMA, fp32 accumulate) ----
  mgemm<128,32,4,1, 1,0,1,0, 3,64,64,8,8,4,15,15><<<dim3(3600,1),256,0,stream>>>(
      obs, c1w_bf, conv1o, c1b, 460800, 32, 192, 0, 32, 0);
  mgemm<128,64,2,2, 2,0,1,0, 32,15,15,4,4,2,6,6><<<dim3(576,1),256,0,stream>>>(
      conv1o, c2w_bf, conv2o, c2b, 73728, 64, 512, 0, 64, 0);
  mgemm<128,64,2,2, 0,0,1,0, 1,1,1,1,1,1,1,1><<<dim3(16,16),256,0,stream>>>(
      data_bf, l1w_bf, lin1o, l1b, 2048, 1024, 1536, 1536, 1024, 0);
  mgemm<128,64,2,2, 2,2,1,0, 64,6,6,3,3,1,4,4><<<dim3(256,1),256,0,stream>>>(
      conv2o, c3w_bf, feat, c3b, 32768, 64, 576, 0, 0, 1536);
  mgemm<128,64,2,2, 0,0,0,0, 1,1,1,1,1,1,1,1><<<dim3(16,8),256,0,stream>>>(
      lin1o, l2w_bf, feat + 1024, l2b, 2048, 512, 1024, 1024, 1536, 0);
  mgemm<128,64,2,2, 0,3,0,1, 1,1,1,1,1,1,1,1><<<dim3(8,7),256,0,stream>>>(
      feat, wihS_bf, X0s, (const float*)nullptr, 1024, 400, 1536, 1536, 400, 0);
  mgemm<128,64,2,2, 0,3,0,1, 1,1,1,1,1,1,1,1><<<dim3(8,7),256,0,stream>>>(
      feat + (size_t)1024*1536, wihR_bf, X0r, (const float*)nullptr, 1024, 400, 1536, 1536, 400, 0);

  // ---- sequential LSTM + fused head ----
  lstm_k<<<32,256,0,stream>>>(X0s, X0r, wpk,
                              s_bih0,s_bhh0,s_bih1,s_bhh1,
                              r_bih0,r_bhh0,r_bih1,r_bhh1,
                              f1w, f1b, f2w, f2b, out);
}

// Round 17
// 301.582 us; speedup vs baseline: 3.6043x; 1.0987x over previous
//
#include <hip/hip_runtime.h>
#include <hip/hip_fp16.h>
#include <math.h>

// ---------------------------------------------------------------------------
// NatureCNN. Round 17: split the LSTM's serial phase chain.
//  - L1's x-part (batch GEMM h0out @ w1x^T) moves to the MFMA path (~8us vs
//    ~28us of in-kernel VALU iterations).
//  - L0 of stack-R runs CONCURRENTLY with L1 of stack-S (independent by the
//    layer-wise carry), as block-ranges of one launch.
// Pipeline: recA(L0_S) -> GEMM X1_S -> recB(L1_S || L0_R) -> GEMM X1_R ->
// recC(L1_R + head). rec inner loop = r13's proven code (256 thr, spill-free).
// ---------------------------------------------------------------------------

typedef __attribute__((ext_vector_type(4))) float f32x4;
typedef __attribute__((ext_vector_type(8))) short s16x8;
typedef __attribute__((ext_vector_type(8))) unsigned short u16x8;
typedef __attribute__((ext_vector_type(4))) unsigned int u32x4;

__device__ __forceinline__ unsigned short f2bf(float f){
  union { float f; unsigned int u; } v; v.f = f;
  unsigned int r = (v.u + 0x7fffu + ((v.u >> 16) & 1u)) >> 16;
  return (unsigned short)r;
}
__device__ __forceinline__ unsigned short f2h(float f){
  return __half_as_ushort(__float2half(f));
}
__device__ __forceinline__ float sigmoidf_(float x){ return 1.0f/(1.0f+__expf(-x)); }
__device__ __forceinline__ float tanhf_(float x){
  float e = __expf(-2.0f*fabsf(x));
  float t = (1.0f - e)/(1.0f + e);
  return copysignf(t, x);
}

#if __has_builtin(__builtin_amdgcn_fdot2)
typedef _Float16 f16x2 __attribute__((ext_vector_type(2)));
__device__ __forceinline__ float dot2h(unsigned int a, unsigned int b, float c){
  union { unsigned int u; f16x2 h; } ua, ub;
  ua.u = a; ub.u = b;
  return __builtin_amdgcn_fdot2(ua.h, ub.h, c, false);
}
#else
__device__ __forceinline__ float dot2h(unsigned int a, unsigned int b, float c){
  __half2 ha = *(__half2*)&a, hb = *(__half2*)&b;
  float2 fa = __half22float2(ha), fb = __half22float2(hb);
  return c + fa.x*fb.x + fa.y*fb.y;
}
#endif

// ---------------------------------------------------------------------------
// ONE merged prep kernel. Jobs:
//  0 data cast-pad  1 l1w cast-pad  2 l2w  3 c1w  4 c2w reorder  5 c3w reorder
//  6 wihS permute   7 wihR permute
//  8 wpk: 4 recurrent mats {s_whh0, s_whh1, r_whh0, r_whh1} -> f16-pair [50][400]
//  9 w1x bf16 zero-padded [400][128] for both stacks
// 10 combined biases (bias0S/0R/1S/1R) + zero h0out matrices
// ---------------------------------------------------------------------------
__global__ void prep_k(
    const float* __restrict__ data, unsigned short* __restrict__ data_bf,
    const float* __restrict__ l1w,  unsigned short* __restrict__ l1w_bf,
    const float* __restrict__ l2w,  unsigned short* __restrict__ l2w_bf,
    const float* __restrict__ c1w,  unsigned short* __restrict__ c1w_bf,
    const float* __restrict__ c2w,  unsigned short* __restrict__ c2w_bf,
    const float* __restrict__ c3w,  unsigned short* __restrict__ c3w_bf,
    const float* __restrict__ wihS, unsigned short* __restrict__ wihS_bf,
    const float* __restrict__ wihR, unsigned short* __restrict__ wihR_bf,
    const float* __restrict__ m0, const float* __restrict__ m1,
    const float* __restrict__ m2, const float* __restrict__ m3,
    unsigned int* __restrict__ wpk,
    const float* __restrict__ wih1S, const float* __restrict__ wih1R,
    unsigned short* __restrict__ w1xS_bf, unsigned short* __restrict__ w1xR_bf,
    const float* __restrict__ s_bih0, const float* __restrict__ s_bhh0,
    const float* __restrict__ s_bih1, const float* __restrict__ s_bhh1,
    const float* __restrict__ r_bih0, const float* __restrict__ r_bhh0,
    const float* __restrict__ r_bih1, const float* __restrict__ r_bhh1,
    float* __restrict__ bias0S, float* __restrict__ bias0R,
    float* __restrict__ bias1S, float* __restrict__ bias1R,
    unsigned short* __restrict__ h0outS, unsigned short* __restrict__ h0outR)
{
  const int job = blockIdx.y;
  const int stride = gridDim.x * blockDim.x;
  int e0 = blockIdx.x * blockDim.x + threadIdx.x;
  if (job == 0){
    for (int e = e0; e < 2048*1536; e += stride){
      int r = e / 1536, k = e - r*1536;
      data_bf[e] = (k < 1500) ? f2bf(data[(size_t)r*1500 + k]) : (unsigned short)0;
    }
  } else if (job == 1){
    for (int e = e0; e < 1024*1536; e += stride){
      int r = e / 1536, k = e - r*1536;
      l1w_bf[e] = (k < 1500) ? f2bf(l1w[(size_t)r*1500 + k]) : (unsigned short)0;
    }
  } else if (job == 2){
    for (int e = e0; e < 512*1024; e += stride) l2w_bf[e] = f2bf(l2w[e]);
  } else if (job == 3){
    for (int e = e0; e < 32*192; e += stride) c1w_bf[e] = f2bf(c1w[e]);
  } else if (job == 4){
    for (int e = e0; e < 64*512; e += stride){
      int oc = e >> 9, r = e & 511;
      int tap = r >> 5, ic = r & 31;
      c2w_bf[e] = f2bf(c2w[(size_t)oc*512 + ic*16 + tap]);
    }
  } else if (job == 5){
    for (int e = e0; e < 64*576; e += stride){
      int oc = e / 576, r = e - oc*576;
      int tap = r >> 6, ic = r & 63;
      c3w_bf[e] = f2bf(c3w[(size_t)oc*576 + ic*9 + tap]);
    }
  } else if (job == 6 || job == 7){
    const float* src = (job == 6) ? wihS : wihR;
    unsigned short* dst = (job == 6) ? wihS_bf : wihR_bf;
    for (int e = e0; e < 400*1536; e += stride){
      int g = e / 1536, k = e - g*1536;
      int ksrc = (k < 1024) ? ((k & 63)*16 + (k >> 6)) : k;
      dst[e] = f2bf(src[(size_t)g*1536 + ksrc]);
    }
  } else if (job == 8){
    const float* srcs[4] = {m0,m1,m2,m3};
    for (int e = e0; e < 4*20000; e += stride){
      int mat = e / 20000, r = e - mat*20000;
      int kk = r / 400, g = r - kk*400;
      const float* src = srcs[mat];
      unsigned int lo = f2h(src[g*100 + 2*kk]);
      unsigned int hi = f2h(src[g*100 + 2*kk + 1]);
      wpk[e] = lo | (hi << 16);
    }
  } else if (job == 9){
    for (int e = e0; e < 2*400*128; e += stride){
      int half = e / 51200, r = e - half*51200;
      int g = r >> 7, k = r & 127;
      const float* src = half ? wih1R : wih1S;
      unsigned short* dst = half ? w1xR_bf : w1xS_bf;
      dst[r] = (k < 100) ? f2bf(src[g*100 + k]) : (unsigned short)0;
    }
  } else {
    for (int e = e0; e < 1600 + 131072; e += stride){
      if (e < 400)        bias0S[e]       = s_bih0[e]       + s_bhh0[e];
      else if (e < 800)   bias0R[e-400]   = r_bih0[e-400]   + r_bhh0[e-400];
      else if (e < 1200)  bias1S[e-800]   = s_bih1[e-800]   + s_bhh1[e-800];
      else if (e < 1600)  bias1R[e-1200]  = r_bih1[e-1200]  + r_bhh1[e-1200];
      else {
        int idx = e - 1600;
        if (idx < 65536) ((unsigned int*)h0outS)[idx] = 0u;
        else             ((unsigned int*)h0outR)[idx - 65536] = 0u;
      }
    }
  }
}

// ---------------------------------------------------------------------------
// bf16 MFMA GEMM (unchanged, passing since round 2)
// ---------------------------------------------------------------------------
template<int BM,int BN,int WAVES_M,int WAVES_N,int AMODE,int CMODE,int RELU,int NGUARD,
         int CIN,int HI,int WI,int KH,int KW,int ST,int HO,int WO>
__global__ __launch_bounds__(256) void mgemm(
    const void* __restrict__ Av, const unsigned short* __restrict__ B,
    void* __restrict__ Cv, const float* __restrict__ bias,
    int M, int N, int K, int lda, int ldc, int cstride)
{
  constexpr int BK = 64;
  constexpr int WROWS = BM / WAVES_M;
  constexpr int WCOLS = BN / WAVES_N;
  constexpr int MF = WROWS / 16;
  constexpr int NF = WCOLS / 16;
  constexpr int HOWO = HO*WO;
  __shared__ unsigned short As[BM*BK];
  __shared__ unsigned short Bs[BN*BK];
  const int tid = threadIdx.x;
  const int bm = blockIdx.x * BM;
  const int bn = blockIdx.y * BN;
  const int lane = tid & 63, w = tid >> 6;
  const int wm = w / WAVES_N, wn = w % WAVES_N;
  const int m0 = wm * WROWS, n0 = wn * WCOLS;

  f32x4 acc[MF][NF] = {};

  const int ar = tid >> 1;
  const int as0 = 4 * (tid & 1);
  const int row_g = bm + ar;
  int a_n = 0, a_oy = 0, a_ox = 0;
  if (AMODE != 0){ a_n = row_g / HOWO; int p = row_g - a_n*HOWO; a_oy = p / WO; a_ox = p - a_oy*WO; }

  for (int kt = 0; kt < K; kt += BK){
    #pragma unroll
    for (int si = 0; si < 4; ++si){
      int s = as0 + si;
      int k0 = kt + s*8;
      u16x8 val;
      if constexpr (AMODE == 0){
        val = *(const u16x8*)((const unsigned short*)Av + (size_t)row_g*lda + k0);
      } else if constexpr (AMODE == 1){
        int ic = k0 >> 6, r = k0 & 63, ky = r >> 3;
        const float* src = (const float*)Av +
            (((size_t)(a_n*CIN + ic)*HI + a_oy*ST + ky)*WI + a_ox*ST);
        f32x4 f0 = *(const f32x4*)src;
        f32x4 f1 = *(const f32x4*)(src + 4);
        val[0]=f2bf(f0[0]); val[1]=f2bf(f0[1]); val[2]=f2bf(f0[2]); val[3]=f2bf(f0[3]);
        val[4]=f2bf(f1[0]); val[5]=f2bf(f1[1]); val[6]=f2bf(f1[2]); val[7]=f2bf(f1[3]);
      } else {
        int tap = k0 / CIN, ic0 = k0 - tap*CIN;
        int ky = tap / KW, kx = tap - ky*KW;
        const unsigned short* src = (const unsigned short*)Av +
            (((size_t)(a_n*HI + a_oy*ST + ky)*WI + a_ox*ST + kx)*CIN + ic0);
        val = *(const u16x8*)src;
      }
      int phys = s ^ ((ar >> 1) & 7);
      *(u16x8*)&As[ar*BK + phys*8] = val;
    }
    if constexpr (BN == 64){
      int br = tid >> 2, bs0 = 2*(tid & 3);
      #pragma unroll
      for (int si = 0; si < 2; ++si){
        int s = bs0 + si, k0 = kt + s*8;
        int n_g = bn + br;
        u16x8 val = {};
        if (!NGUARD || n_g < N) val = *(const u16x8*)(B + (size_t)n_g*K + k0);
        int phys = s ^ ((br >> 1) & 7);
        *(u16x8*)&Bs[br*BK + phys*8] = val;
      }
    } else {
      int br = tid >> 3, s = tid & 7, k0 = kt + s*8;
      int n_g = bn + br;
      u16x8 val = {};
      if (!NGUARD || n_g < N) val = *(const u16x8*)(B + (size_t)n_g*K + k0);
      int phys = s ^ ((br >> 1) & 7);
      *(u16x8*)&Bs[br*BK + phys*8] = val;
    }
    __syncthreads();
    #pragma unroll
    for (int ks = 0; ks < 2; ++ks){
      s16x8 a[MF], b[NF];
      #pragma unroll
      for (int i = 0; i < MF; ++i){
        int row = m0 + i*16 + (lane & 15);
        int phys = (ks*4 + (lane >> 4)) ^ ((row >> 1) & 7);
        a[i] = *(const s16x8*)&As[row*BK + phys*8];
      }
      #pragma unroll
      for (int j = 0; j < NF; ++j){
        int row = n0 + j*16 + (lane & 15);
        int phys = (ks*4 + (lane >> 4)) ^ ((row >> 1) & 7);
        b[j] = *(const s16x8*)&Bs[row*BK + phys*8];
      }
      #pragma unroll
      for (int i = 0; i < MF; ++i)
        #pragma unroll
        for (int j = 0; j < NF; ++j)
          acc[i][j] = __builtin_amdgcn_mfma_f32_16x16x32_bf16(a[i], b[j], acc[i][j], 0, 0, 0);
    }
    __syncthreads();
  }

  if constexpr (CMODE == 3){
    float* Cf = (float*)Cv;
    #pragma unroll
    for (int i = 0; i < MF; ++i)
      #pragma unroll
      for (int j = 0; j < NF; ++j){
        int col = bn + n0 + j*16 + (lane & 15);
        float bv = (bias && (!NGUARD || col < N)) ? bias[col] : 0.f;
        #pragma unroll
        for (int q = 0; q < 4; ++q){
          int row = bm + m0 + i*16 + (lane >> 4)*4 + q;
          float v = acc[i][j][q] + bv;
          if (RELU) v = fmaxf(v, 0.f);
          if (!NGUARD || col < N) Cf[(size_t)row*ldc + col] = v;
        }
      }
  } else {
    unsigned short* tile = As;
    #pragma unroll
    for (int i = 0; i < MF; ++i)
      #pragma unroll
      for (int j = 0; j < NF; ++j){
        int col = n0 + j*16 + (lane & 15);
        float bv = bias ? bias[bn + col] : 0.f;
        #pragma unroll
        for (int q = 0; q < 4; ++q){
          int row = m0 + i*16 + (lane >> 4)*4 + q;
          float v = acc[i][j][q] + bv;
          if (RELU) v = fmaxf(v, 0.f);
          tile[row*BN + col] = f2bf(v);
        }
      }
    __syncthreads();
    unsigned short* Cu = (unsigned short*)Cv;
    constexpr int CHUNKS = (BM*BN)/(256*8);
    #pragma unroll
    for (int c = 0; c < CHUNKS; ++c){
      int flat = tid*8 + c*2048;
      int row = flat / BN, col = flat - (flat/BN)*BN;
      u16x8 v = *(const u16x8*)&tile[flat];
      int rg = bm + row;
      size_t addr;
      if constexpr (CMODE == 0) addr = (size_t)rg*ldc + bn + col;
      else { int n = rg >> 4, p = rg & 15; addr = (size_t)n*cstride + p*64 + col; }
      *(u16x8*)&Cu[addr] = v;
    }
  }
}

// ---------------------------------------------------------------------------
// Unified single-layer recurrent body (r13's proven inner loop).
// 256 threads; e=tid>>1, sub=tid&1; sub0 owns gate rows i(e),g(e); sub1 owns
// f(e),o(e). 100 packed f16-pair weight u32 in regs, h dbuf in LDS,
// 1 barrier/step. x pre-acts read from global X (prefetched). Optional:
// bias add (bsum), h/c init from global (hinit/cinit fp32), h-out matrix
// (bf16, K=128-padded) for the next layer's x-GEMM, final h/c carry out.
// ---------------------------------------------------------------------------
__device__ __forceinline__ void rec_body(
    int seg, int tid,
    const float* __restrict__ X,            // [(seg*32+t)*400 + g]
    const unsigned int* __restrict__ wP,    // [50][400] f16 pairs
    const float* __restrict__ bsum,         // [400] or null
    const float* __restrict__ hinit,        // [seg*100+*] fp32 or null
    const float* __restrict__ cinit,        // or null
    unsigned short* __restrict__ houtm,     // [(seg*32+t)*128 + e] bf16 or null
    float* __restrict__ hfin,               // [seg*100+e] or null
    float* __restrict__ cfin,               // or null
    unsigned int (*hp)[56],                 // LDS dbuf
    float* __restrict__ xout)               // xin[0..99] or null
{
  const int e = tid >> 1, sub = tid & 1;
  const bool act = (e < 100);
  const int eS = act ? e : 0;
  const int gA = sub*100 + eS;
  const int gB = gA + 200;

  if (tid < 56){
    unsigned int v = 0u;
    if (hinit && tid < 50){
      unsigned int lo = f2h(hinit[seg*100 + 2*tid]);
      unsigned int hi = f2h(hinit[seg*100 + 2*tid + 1]);
      v = lo | (hi << 16);
    }
    hp[0][tid] = v;
    hp[1][tid] = 0u;
  }
  float cr = 0.f;
  if (cinit && act && sub) cr = cinit[seg*100 + e];
  __syncthreads();

  unsigned int wA[50], wB[50];
  #pragma unroll
  for (int p = 0; p < 50; ++p){
    wA[p] = wP[p*400 + gA];
    wB[p] = wP[p*400 + gB];
  }
  float bsA = bsum ? bsum[gA] : 0.f;
  float bsB = bsum ? bsum[gB] : 0.f;
  const float* Xs = X + (size_t)seg*32*400;
  float xcA = Xs[gA], xcB = Xs[gB], xnA = 0.f, xnB = 0.f;
  float hnK = 0.f;

  #pragma unroll 1
  for (int t = 0; t < 32; ++t){
    if (t < 31){ xnA = Xs[(t+1)*400 + gA]; xnB = Xs[(t+1)*400 + gB]; }
    const u32x4* h4 = (const u32x4*)hp[t & 1];
    float a0=0.f, a1=0.f, b0=0.f, b1=0.f;
    #pragma unroll
    for (int i = 0; i < 12; ++i){
      u32x4 hv = h4[i];
      a0 = dot2h(wA[4*i+0], hv[0], a0);
      a1 = dot2h(wA[4*i+1], hv[1], a1);
      a0 = dot2h(wA[4*i+2], hv[2], a0);
      a1 = dot2h(wA[4*i+3], hv[3], a1);
      b0 = dot2h(wB[4*i+0], hv[0], b0);
      b1 = dot2h(wB[4*i+1], hv[1], b1);
      b0 = dot2h(wB[4*i+2], hv[2], b0);
      b1 = dot2h(wB[4*i+3], hv[3], b1);
    }
    { u32x4 hv = h4[12];
      a0 = dot2h(wA[48], hv[0], a0);
      a1 = dot2h(wA[49], hv[1], a1);
      b0 = dot2h(wB[48], hv[0], b0);
      b1 = dot2h(wB[49], hv[1], b1);
    }
    float preA = (a0 + a1) + xcA + bsA;
    float preB = (b0 + b1) + xcB + bsB;
    float vA = sigmoidf_(preA);                       // i (sub0) / f (sub1)
    float vB = sub ? sigmoidf_(preB) : tanhf_(preB);  // o (sub1) / g (sub0)
    float send = vA * vB;                             // sub0: i*g
    float recv = __shfl_xor(send, 1);
    if (act && sub){
      cr = vA*cr + recv;
      float hn = vB * tanhf_(cr);
      hnK = hn;
      ((unsigned short*)hp[(t+1) & 1])[e] = f2h(hn);
      if (houtm) houtm[((size_t)seg*32 + t)*128 + e] = f2bf(hn);
    }
    xcA = xnA; xcB = xnB;
    __syncthreads();
  }

  if (act && sub){
    if (hfin) hfin[seg*100 + e] = hnK;
    if (cfin) cfin[seg*100 + e] = cr;
    if (xout) xout[e] = hnK;
  }
}

// recA: stack-S layer 0 (zero init) -> h0out matrix + layer-0 carry
__global__ __launch_bounds__(256,1) void recA_k(
    const float* __restrict__ X0s, const unsigned int* __restrict__ wpk,
    const float* __restrict__ bias0S,
    unsigned short* __restrict__ h0outS,
    float* __restrict__ h0finS, float* __restrict__ c0finS)
{
  __shared__ unsigned int hp[2][56];
  rec_body(blockIdx.x, threadIdx.x, X0s, wpk, bias0S, nullptr, nullptr,
           h0outS, h0finS, c0finS, hp, nullptr);
}

// recB: blocks 0-31 = stack-S layer 1 (zero init, x=X1s) -> layer-1 carry;
//       blocks 32-63 = stack-R layer 0 (init = layer-0 carry) -> h0outR.
__global__ __launch_bounds__(256,1) void recB_k(
    const float* __restrict__ X1s, const float* __restrict__ X0r,
    const unsigned int* __restrict__ wpk, const float* __restrict__ bias0R,
    const float* __restrict__ h0finS, const float* __restrict__ c0finS,
    unsigned short* __restrict__ h0outR,
    float* __restrict__ h1finS, float* __restrict__ c1finS)
{
  __shared__ unsigned int hp[2][56];
  int bx = blockIdx.x;
  if (bx < 32){
    rec_body(bx, threadIdx.x, X1s, wpk + 20000, nullptr, nullptr, nullptr,
             nullptr, h1finS, c1finS, hp, nullptr);
  } else {
    rec_body(bx - 32, threadIdx.x, X0r, wpk + 40000, bias0R, h0finS, c0finS,
             h0outR, nullptr, nullptr, hp, nullptr);
  }
}

// recC: stack-R layer 1 (init = stack-S layer-1 carry, x=X1r) + fused head.
__global__ __launch_bounds__(256,1) void recC_k(
    const float* __restrict__ X1r, const unsigned int* __restrict__ wpk,
    const float* __restrict__ h1finS, const float* __restrict__ c1finS,
    const float* __restrict__ f1w, const float* __restrict__ f1b,
    const float* __restrict__ f2w, const float* __restrict__ f2b,
    float* __restrict__ out)
{
  __shared__ unsigned int hp[2][56];
  __shared__ float xin[208];
  __shared__ float mid[512];
  const int tid = threadIdx.x, b = blockIdx.x;
  rec_body(b, tid, X1r, wpk + 60000, nullptr, h1finS, c1finS,
           nullptr, nullptr, nullptr, hp, xin);          // xin[0..99] = outR
  if (tid < 100) xin[100 + tid] = h1finS[b*100 + tid];   // outS
  __syncthreads();
  for (int r = tid; r < 512; r += 256){
    float acc = f1b[r];
    const float* wrow = f1w + (size_t)r*200;
    #pragma unroll 4
    for (int k = 0; k < 200; ++k) acc += xin[k]*wrow[k];
    mid[r] = fmaxf(acc, 0.f);
  }
  __syncthreads();
  if (tid < 130){
    float acc = f2b[tid];
    const float* wrow = f2w + (size_t)tid*512;
    #pragma unroll 4
    for (int k = 0; k < 512; ++k) acc += mid[k]*wrow[k];
    out[b*130 + tid] = acc;
  }
}

extern "C" void kernel_launch(void* const* d_in, const int* in_sizes, int n_in,
                              void* d_out, int out_size, void* d_ws, size_t ws_size,
                              hipStream_t stream)
{
  const float* obs  = (const float*)d_in[0];
  const float* data = (const float*)d_in[1];
  const float* c1w = (const float*)d_in[2];  const float* c1b = (const float*)d_in[3];
  const float* c2w = (const float*)d_in[4];  const float* c2b = (const float*)d_in[5];
  const float* c3w = (const float*)d_in[6];  const float* c3b = (const float*)d_in[7];
  const float* l1w = (const float*)d_in[8];  const float* l1b = (const float*)d_in[9];
  const float* l2w = (const float*)d_in[10]; const float* l2b = (const float*)d_in[11];
  const float* s_wih0=(const float*)d_in[12]; const float* s_whh0=(const float*)d_in[13];
  const float* s_bih0=(const float*)d_in[14]; const float* s_bhh0=(const float*)d_in[15];
  const float* s_wih1=(const float*)d_in[16]; const float* s_whh1=(const float*)d_in[17];
  const float* s_bih1=(const float*)d_in[18]; const float* s_bhh1=(const float*)d_in[19];
  const float* r_wih0=(const float*)d_in[20]; const float* r_whh0=(const float*)d_in[21];
  const float* r_bih0=(const float*)d_in[22]; const float* r_bhh0=(const float*)d_in[23];
  const float* r_wih1=(const float*)d_in[24]; const float* r_whh1=(const float*)d_in[25];
  const float* r_bih1=(const float*)d_in[26]; const float* r_bhh1=(const float*)d_in[27];
  const float* f1w=(const float*)d_in[28]; const float* f1b=(const float*)d_in[29];
  const float* f2w=(const float*)d_in[30]; const float* f2b=(const float*)d_in[31];
  float* out = (float*)d_out;
  (void)in_sizes; (void)n_in; (void)out_size;

  // ---- workspace layout (bytes, 256-aligned) ----
  char* p = (char*)d_ws;
  auto alloc = [&](size_t bytes){ void* r = (void*)p; p += (bytes + 255) & ~(size_t)255; return r; };
  unsigned short* data_bf = (unsigned short*)alloc((size_t)2048*1536*2);
  unsigned short* c1w_bf  = (unsigned short*)alloc((size_t)32*192*2);
  unsigned short* c2w_bf  = (unsigned short*)alloc((size_t)64*512*2);
  unsigned short* c3w_bf  = (unsigned short*)alloc((size_t)64*576*2);
  unsigned short* l1w_bf  = (unsigned short*)alloc((size_t)1024*1536*2);
  unsigned short* l2w_bf  = (unsigned short*)alloc((size_t)512*1024*2);
  unsigned short* wihS_bf = (unsigned short*)alloc((size_t)400*1536*2);
  unsigned short* wihR_bf = (unsigned short*)alloc((size_t)400*1536*2);
  unsigned short* conv1o  = (unsigned short*)alloc((size_t)2048*225*32*2);  // NHWC
  unsigned short* conv2o  = (unsigned short*)alloc((size_t)2048*36*64*2);   // NHWC
  unsigned short* feat    = (unsigned short*)alloc((size_t)2048*1536*2);
  unsigned short* lin1o   = (unsigned short*)alloc((size_t)2048*1024*2);
  float* X0s  = (float*)alloc((size_t)1024*400*4);
  float* X0r  = (float*)alloc((size_t)1024*400*4);
  unsigned int* wpk = (unsigned int*)alloc((size_t)4*20000*4);
  unsigned short* w1xS_bf = (unsigned short*)alloc((size_t)400*128*2);
  unsigned short* w1xR_bf = (unsigned short*)alloc((size_t)400*128*2);
  unsigned short* h0outS  = (unsigned short*)alloc((size_t)1024*128*2);
  unsigned short* h0outR  = (unsigned short*)alloc((size_t)1024*128*2);
  float* X1s = (float*)alloc((size_t)1024*400*4);
  float* X1r = (float*)alloc((size_t)1024*400*4);
  float* bias0S = (float*)alloc(400*4);
  float* bias0R = (float*)alloc(400*4);
  float* bias1S = (float*)alloc(400*4);
  float* bias1R = (float*)alloc(400*4);
  float* h0finS = (float*)alloc(3200*4);
  float* c0finS = (float*)alloc(3200*4);
  float* h1finS = (float*)alloc(3200*4);
  float* c1finS = (float*)alloc(3200*4);
  (void)ws_size;

  // ---- merged prep (1 launch) ----
  prep_k<<<dim3(512,11),256,0,stream>>>(
      data, data_bf, l1w, l1w_bf, l2w, l2w_bf, c1w, c1w_bf,
      c2w, c2w_bf, c3w, c3w_bf, s_wih0, wihS_bf, r_wih0, wihR_bf,
      s_whh0, s_whh1, r_whh0, r_whh1, wpk,
      s_wih1, r_wih1, w1xS_bf, w1xR_bf,
      s_bih0, s_bhh0, s_bih1, s_bhh1, r_bih0, r_bhh0, r_bih1, r_bhh1,
      bias0S, bias0R, bias1S, bias1R, h0outS, h0outR);

  // ---- GEMM chain (bf16 MFMA, fp32 accumulate) ----
  mgemm<128,32,4,1, 1,0,1,0, 3,64,64,8,8,4,15,15><<<dim3(3600,1),256,0,stream>>>(
      obs, c1w_bf, conv1o, c1b, 460800, 32, 192, 0, 32, 0);
  mgemm<128,64,2,2, 2,0,1,0, 32,15,15,4,4,2,6,6><<<dim3(576,1),256,0,stream>>>(
      conv1o, c2w_bf, conv2o, c2b, 73728, 64, 512, 0, 64, 0);
  mgemm<128,64,2,2, 0,0,1,0, 1,1,1,1,1,1,1,1><<<dim3(16,16),256,0,stream>>>(
      data_bf, l1w_bf, lin1o, l1b, 2048, 1024, 1536, 1536, 1024, 0);
  mgemm<128,64,2,2, 2,2,1,0, 64,6,6,3,3,1,4,4><<<dim3(256,1),256,0,stream>>>(
      conv2o, c3w_bf, feat, c3b, 32768, 64, 576, 0, 0, 1536);
  mgemm<128,64,2,2, 0,0,0,0, 1,1,1,1,1,1,1,1><<<dim3(16,8),256,0,stream>>>(
      lin1o, l2w_bf, feat + 1024, l2b, 2048, 512, 1024, 1024, 1536, 0);
  mgemm<128,64,2,2, 0,3,0,1, 1,1,1,1,1,1,1,1><<<dim3(8,7),256,0,stream>>>(
      feat, wihS_bf, X0s, (const float*)nullptr, 1024, 400, 1536, 1536, 400, 0);
  mgemm<128,64,2,2, 0,3,0,1, 1,1,1,1,1,1,1,1><<<dim3(8,7),256,0,stream>>>(
      feat + (size_t)1024*1536, wihR_bf, X0r, (const float*)nullptr, 1024, 400, 1536, 1536, 400, 0);

  // ---- pipelined LSTM: recA -> G1 -> recB (L1_S || L0_R) -> G2 -> recC+head ----
  recA_k<<<32,256,0,stream>>>(X0s, wpk, bias0S, h0outS, h0finS, c0finS);
  mgemm<128,64,2,2, 0,3,0,1, 1,1,1,1,1,1,1,1><<<dim3(8,7),256,0,stream>>>(
      h0outS, w1xS_bf, X1s, bias1S, 1024, 400, 128, 128, 400, 0);
  recB_k<<<64,256,0,stream>>>(X1s, X0r, wpk, bias0R, h0finS, c0finS,
                              h0outR, h1finS, c1finS);
  mgemm<128,64,2,2, 0,3,0,1, 1,1,1,1,1,1,1,1><<<dim3(8,7),256,0,stream>>>(
      h0outR, w1xR_bf, X1r, bias1R, 1024, 400, 128, 128, 400, 0);
  recC_k<<<32,256,0,stream>>>(X1r, wpk, h1finS, c1finS,
                              f1w, f1b, f2w, f2b, out);
}

// Round 18
// 298.522 us; speedup vs baseline: 3.6412x; 1.0102x over previous
//
#include <hip/hip_runtime.h>
#include <hip/hip_fp16.h>
#include <math.h>

// ---------------------------------------------------------------------------
// NatureCNN. Round 18: coalesce the fused head (was ~45us of recC's 74us:
// 800B-stride f1w row reads = 64-line gathers per instruction). Head weights
// prep-transposed to k-major f16-pair layout (f1wTp[k][512], f2wTp[k][130]);
// k-loop loads are lane-consecutive, bytes halved, inner op = dot2h.
// Pipeline (r17): recA(L0_S) -> GEMM X1_S -> recB(L1_S || L0_R) -> GEMM X1_R
// -> recC(L1_R + head).
// ---------------------------------------------------------------------------

typedef __attribute__((ext_vector_type(4))) float f32x4;
typedef __attribute__((ext_vector_type(8))) short s16x8;
typedef __attribute__((ext_vector_type(8))) unsigned short u16x8;
typedef __attribute__((ext_vector_type(4))) unsigned int u32x4;

__device__ __forceinline__ unsigned short f2bf(float f){
  union { float f; unsigned int u; } v; v.f = f;
  unsigned int r = (v.u + 0x7fffu + ((v.u >> 16) & 1u)) >> 16;
  return (unsigned short)r;
}
__device__ __forceinline__ unsigned short f2h(float f){
  return __half_as_ushort(__float2half(f));
}
__device__ __forceinline__ float sigmoidf_(float x){ return 1.0f/(1.0f+__expf(-x)); }
__device__ __forceinline__ float tanhf_(float x){
  float e = __expf(-2.0f*fabsf(x));
  float t = (1.0f - e)/(1.0f + e);
  return copysignf(t, x);
}

#if __has_builtin(__builtin_amdgcn_fdot2)
typedef _Float16 f16x2 __attribute__((ext_vector_type(2)));
__device__ __forceinline__ float dot2h(unsigned int a, unsigned int b, float c){
  union { unsigned int u; f16x2 h; } ua, ub;
  ua.u = a; ub.u = b;
  return __builtin_amdgcn_fdot2(ua.h, ub.h, c, false);
}
#else
__device__ __forceinline__ float dot2h(unsigned int a, unsigned int b, float c){
  __half2 ha = *(__half2*)&a, hb = *(__half2*)&b;
  float2 fa = __half22float2(ha), fb = __half22float2(hb);
  return c + fa.x*fb.x + fa.y*fb.y;
}
#endif

// ---------------------------------------------------------------------------
// ONE merged prep kernel. Jobs:
//  0 data cast-pad  1 l1w cast-pad  2 l2w  3 c1w  4 c2w reorder  5 c3w reorder
//  6 wihS permute   7 wihR permute
//  8 wpk: {s_whh0, s_whh1, r_whh0, r_whh1} -> f16-pair [50][400]
//  9 w1x bf16 zero-padded [400][128] both stacks
// 10 combined biases + zero h0out matrices
// 11 f1wTp: f16-pair k-major [100][512]
// 12 f2wTp: f16-pair k-major [256][130]
// ---------------------------------------------------------------------------
__global__ void prep_k(
    const float* __restrict__ data, unsigned short* __restrict__ data_bf,
    const float* __restrict__ l1w,  unsigned short* __restrict__ l1w_bf,
    const float* __restrict__ l2w,  unsigned short* __restrict__ l2w_bf,
    const float* __restrict__ c1w,  unsigned short* __restrict__ c1w_bf,
    const float* __restrict__ c2w,  unsigned short* __restrict__ c2w_bf,
    const float* __restrict__ c3w,  unsigned short* __restrict__ c3w_bf,
    const float* __restrict__ wihS, unsigned short* __restrict__ wihS_bf,
    const float* __restrict__ wihR, unsigned short* __restrict__ wihR_bf,
    const float* __restrict__ m0, const float* __restrict__ m1,
    const float* __restrict__ m2, const float* __restrict__ m3,
    unsigned int* __restrict__ wpk,
    const float* __restrict__ wih1S, const float* __restrict__ wih1R,
    unsigned short* __restrict__ w1xS_bf, unsigned short* __restrict__ w1xR_bf,
    const float* __restrict__ s_bih0, const float* __restrict__ s_bhh0,
    const float* __restrict__ s_bih1, const float* __restrict__ s_bhh1,
    const float* __restrict__ r_bih0, const float* __restrict__ r_bhh0,
    const float* __restrict__ r_bih1, const float* __restrict__ r_bhh1,
    float* __restrict__ bias0S, float* __restrict__ bias0R,
    float* __restrict__ bias1S, float* __restrict__ bias1R,
    unsigned short* __restrict__ h0outS, unsigned short* __restrict__ h0outR,
    const float* __restrict__ f1w, const float* __restrict__ f2w,
    unsigned int* __restrict__ f1wTp, unsigned int* __restrict__ f2wTp)
{
  const int job = blockIdx.y;
  const int stride = gridDim.x * blockDim.x;
  int e0 = blockIdx.x * blockDim.x + threadIdx.x;
  if (job == 0){
    for (int e = e0; e < 2048*1536; e += stride){
      int r = e / 1536, k = e - r*1536;
      data_bf[e] = (k < 1500) ? f2bf(data[(size_t)r*1500 + k]) : (unsigned short)0;
    }
  } else if (job == 1){
    for (int e = e0; e < 1024*1536; e += stride){
      int r = e / 1536, k = e - r*1536;
      l1w_bf[e] = (k < 1500) ? f2bf(l1w[(size_t)r*1500 + k]) : (unsigned short)0;
    }
  } else if (job == 2){
    for (int e = e0; e < 512*1024; e += stride) l2w_bf[e] = f2bf(l2w[e]);
  } else if (job == 3){
    for (int e = e0; e < 32*192; e += stride) c1w_bf[e] = f2bf(c1w[e]);
  } else if (job == 4){
    for (int e = e0; e < 64*512; e += stride){
      int oc = e >> 9, r = e & 511;
      int tap = r >> 5, ic = r & 31;
      c2w_bf[e] = f2bf(c2w[(size_t)oc*512 + ic*16 + tap]);
    }
  } else if (job == 5){
    for (int e = e0; e < 64*576; e += stride){
      int oc = e / 576, r = e - oc*576;
      int tap = r >> 6, ic = r & 63;
      c3w_bf[e] = f2bf(c3w[(size_t)oc*576 + ic*9 + tap]);
    }
  } else if (job == 6 || job == 7){
    const float* src = (job == 6) ? wihS : wihR;
    unsigned short* dst = (job == 6) ? wihS_bf : wihR_bf;
    for (int e = e0; e < 400*1536; e += stride){
      int g = e / 1536, k = e - g*1536;
      int ksrc = (k < 1024) ? ((k & 63)*16 + (k >> 6)) : k;
      dst[e] = f2bf(src[(size_t)g*1536 + ksrc]);
    }
  } else if (job == 8){
    const float* srcs[4] = {m0,m1,m2,m3};
    for (int e = e0; e < 4*20000; e += stride){
      int mat = e / 20000, r = e - mat*20000;
      int kk = r / 400, g = r - kk*400;
      const float* src = srcs[mat];
      unsigned int lo = f2h(src[g*100 + 2*kk]);
      unsigned int hi = f2h(src[g*100 + 2*kk + 1]);
      wpk[e] = lo | (hi << 16);
    }
  } else if (job == 9){
    for (int e = e0; e < 2*400*128; e += stride){
      int half = e / 51200, r = e - half*51200;
      int g = r >> 7, k = r & 127;
      const float* src = half ? wih1R : wih1S;
      unsigned short* dst = half ? w1xR_bf : w1xS_bf;
      dst[r] = (k < 100) ? f2bf(src[g*100 + k]) : (unsigned short)0;
    }
  } else if (job == 10){
    for (int e = e0; e < 1600 + 131072; e += stride){
      if (e < 400)        bias0S[e]       = s_bih0[e]       + s_bhh0[e];
      else if (e < 800)   bias0R[e-400]   = r_bih0[e-400]   + r_bhh0[e-400];
      else if (e < 1200)  bias1S[e-800]   = s_bih1[e-800]   + s_bhh1[e-800];
      else if (e < 1600)  bias1R[e-1200]  = r_bih1[e-1200]  + r_bhh1[e-1200];
      else {
        int idx = e - 1600;
        if (idx < 65536) ((unsigned int*)h0outS)[idx] = 0u;
        else             ((unsigned int*)h0outR)[idx - 65536] = 0u;
      }
    }
  } else if (job == 11){
    for (int e = e0; e < 100*512; e += stride){
      int k = e >> 9, r = e & 511;
      unsigned int lo = f2h(f1w[(size_t)r*200 + 2*k]);
      unsigned int hi = f2h(f1w[(size_t)r*200 + 2*k + 1]);
      f1wTp[e] = lo | (hi << 16);
    }
  } else {
    for (int e = e0; e < 256*130; e += stride){
      int k = e / 130, j = e - k*130;
      unsigned int lo = f2h(f2w[(size_t)j*512 + 2*k]);
      unsigned int hi = f2h(f2w[(size_t)j*512 + 2*k + 1]);
      f2wTp[e] = lo | (hi << 16);
    }
  }
}

// ---------------------------------------------------------------------------
// bf16 MFMA GEMM (unchanged, passing since round 2)
// ---------------------------------------------------------------------------
template<int BM,int BN,int WAVES_M,int WAVES_N,int AMODE,int CMODE,int RELU,int NGUARD,
         int CIN,int HI,int WI,int KH,int KW,int ST,int HO,int WO>
__global__ __launch_bounds__(256) void mgemm(
    const void* __restrict__ Av, const unsigned short* __restrict__ B,
    void* __restrict__ Cv, const float* __restrict__ bias,
    int M, int N, int K, int lda, int ldc, int cstride)
{
  constexpr int BK = 64;
  constexpr int WROWS = BM / WAVES_M;
  constexpr int WCOLS = BN / WAVES_N;
  constexpr int MF = WROWS / 16;
  constexpr int NF = WCOLS / 16;
  constexpr int HOWO = HO*WO;
  __shared__ unsigned short As[BM*BK];
  __shared__ unsigned short Bs[BN*BK];
  const int tid = threadIdx.x;
  const int bm = blockIdx.x * BM;
  const int bn = blockIdx.y * BN;
  const int lane = tid & 63, w = tid >> 6;
  const int wm = w / WAVES_N, wn = w % WAVES_N;
  const int m0 = wm * WROWS, n0 = wn * WCOLS;

  f32x4 acc[MF][NF] = {};

  const int ar = tid >> 1;
  const int as0 = 4 * (tid & 1);
  const int row_g = bm + ar;
  int a_n = 0, a_oy = 0, a_ox = 0;
  if (AMODE != 0){ a_n = row_g / HOWO; int p = row_g - a_n*HOWO; a_oy = p / WO; a_ox = p - a_oy*WO; }

  for (int kt = 0; kt < K; kt += BK){
    #pragma unroll
    for (int si = 0; si < 4; ++si){
      int s = as0 + si;
      int k0 = kt + s*8;
      u16x8 val;
      if constexpr (AMODE == 0){
        val = *(const u16x8*)((const unsigned short*)Av + (size_t)row_g*lda + k0);
      } else if constexpr (AMODE == 1){
        int ic = k0 >> 6, r = k0 & 63, ky = r >> 3;
        const float* src = (const float*)Av +
            (((size_t)(a_n*CIN + ic)*HI + a_oy*ST + ky)*WI + a_ox*ST);
        f32x4 f0 = *(const f32x4*)src;
        f32x4 f1 = *(const f32x4*)(src + 4);
        val[0]=f2bf(f0[0]); val[1]=f2bf(f0[1]); val[2]=f2bf(f0[2]); val[3]=f2bf(f0[3]);
        val[4]=f2bf(f1[0]); val[5]=f2bf(f1[1]); val[6]=f2bf(f1[2]); val[7]=f2bf(f1[3]);
      } else {
        int tap = k0 / CIN, ic0 = k0 - tap*CIN;
        int ky = tap / KW, kx = tap - ky*KW;
        const unsigned short* src = (const unsigned short*)Av +
            (((size_t)(a_n*HI + a_oy*ST + ky)*WI + a_ox*ST + kx)*CIN + ic0);
        val = *(const u16x8*)src;
      }
      int phys = s ^ ((ar >> 1) & 7);
      *(u16x8*)&As[ar*BK + phys*8] = val;
    }
    if constexpr (BN == 64){
      int br = tid >> 2, bs0 = 2*(tid & 3);
      #pragma unroll
      for (int si = 0; si < 2; ++si){
        int s = bs0 + si, k0 = kt + s*8;
        int n_g = bn + br;
        u16x8 val = {};
        if (!NGUARD || n_g < N) val = *(const u16x8*)(B + (size_t)n_g*K + k0);
        int phys = s ^ ((br >> 1) & 7);
        *(u16x8*)&Bs[br*BK + phys*8] = val;
      }
    } else {
      int br = tid >> 3, s = tid & 7, k0 = kt + s*8;
      int n_g = bn + br;
      u16x8 val = {};
      if (!NGUARD || n_g < N) val = *(const u16x8*)(B + (size_t)n_g*K + k0);
      int phys = s ^ ((br >> 1) & 7);
      *(u16x8*)&Bs[br*BK + phys*8] = val;
    }
    __syncthreads();
    #pragma unroll
    for (int ks = 0; ks < 2; ++ks){
      s16x8 a[MF], b[NF];
      #pragma unroll
      for (int i = 0; i < MF; ++i){
        int row = m0 + i*16 + (lane & 15);
        int phys = (ks*4 + (lane >> 4)) ^ ((row >> 1) & 7);
        a[i] = *(const s16x8*)&As[row*BK + phys*8];
      }
      #pragma unroll
      for (int j = 0; j < NF; ++j){
        int row = n0 + j*16 + (lane & 15);
        int phys = (ks*4 + (lane >> 4)) ^ ((row >> 1) & 7);
        b[j] = *(const s16x8*)&Bs[row*BK + phys*8];
      }
      #pragma unroll
      for (int i = 0; i < MF; ++i)
        #pragma unroll
        for (int j = 0; j < NF; ++j)
          acc[i][j] = __builtin_amdgcn_mfma_f32_16x16x32_bf16(a[i], b[j], acc[i][j], 0, 0, 0);
    }
    __syncthreads();
  }

  if constexpr (CMODE == 3){
    float* Cf = (float*)Cv;
    #pragma unroll
    for (int i = 0; i < MF; ++i)
      #pragma unroll
      for (int j = 0; j < NF; ++j){
        int col = bn + n0 + j*16 + (lane & 15);
        float bv = (bias && (!NGUARD || col < N)) ? bias[col] : 0.f;
        #pragma unroll
        for (int q = 0; q < 4; ++q){
          int row = bm + m0 + i*16 + (lane >> 4)*4 + q;
          float v = acc[i][j][q] + bv;
          if (RELU) v = fmaxf(v, 0.f);
          if (!NGUARD || col < N) Cf[(size_t)row*ldc + col] = v;
        }
      }
  } else {
    unsigned short* tile = As;
    #pragma unroll
    for (int i = 0; i < MF; ++i)
      #pragma unroll
      for (int j = 0; j < NF; ++j){
        int col = n0 + j*16 + (lane & 15);
        float bv = bias ? bias[bn + col] : 0.f;
        #pragma unroll
        for (int q = 0; q < 4; ++q){
          int row = m0 + i*16 + (lane >> 4)*4 + q;
          float v = acc[i][j][q] + bv;
          if (RELU) v = fmaxf(v, 0.f);
          tile[row*BN + col] = f2bf(v);
        }
      }
    __syncthreads();
    unsigned short* Cu = (unsigned short*)Cv;
    constexpr int CHUNKS = (BM*BN)/(256*8);
    #pragma unroll
    for (int c = 0; c < CHUNKS; ++c){
      int flat = tid*8 + c*2048;
      int row = flat / BN, col = flat - (flat/BN)*BN;
      u16x8 v = *(const u16x8*)&tile[flat];
      int rg = bm + row;
      size_t addr;
      if constexpr (CMODE == 0) addr = (size_t)rg*ldc + bn + col;
      else { int n = rg >> 4, p = rg & 15; addr = (size_t)n*cstride + p*64 + col; }
      *(u16x8*)&Cu[addr] = v;
    }
  }
}

// ---------------------------------------------------------------------------
// Unified single-layer recurrent body (r13's proven inner loop).
// ---------------------------------------------------------------------------
__device__ __forceinline__ void rec_body(
    int seg, int tid,
    const float* __restrict__ X,
    const unsigned int* __restrict__ wP,
    const float* __restrict__ bsum,
    const float* __restrict__ hinit,
    const float* __restrict__ cinit,
    unsigned short* __restrict__ houtm,
    float* __restrict__ hfin,
    float* __restrict__ cfin,
    unsigned int (*hp)[56],
    float* __restrict__ xout)
{
  const int e = tid >> 1, sub = tid & 1;
  const bool act = (e < 100);
  const int eS = act ? e : 0;
  const int gA = sub*100 + eS;
  const int gB = gA + 200;

  if (tid < 56){
    unsigned int v = 0u;
    if (hinit && tid < 50){
      unsigned int lo = f2h(hinit[seg*100 + 2*tid]);
      unsigned int hi = f2h(hinit[seg*100 + 2*tid + 1]);
      v = lo | (hi << 16);
    }
    hp[0][tid] = v;
    hp[1][tid] = 0u;
  }
  float cr = 0.f;
  if (cinit && act && sub) cr = cinit[seg*100 + e];
  __syncthreads();

  unsigned int wA[50], wB[50];
  #pragma unroll
  for (int p = 0; p < 50; ++p){
    wA[p] = wP[p*400 + gA];
    wB[p] = wP[p*400 + gB];
  }
  float bsA = bsum ? bsum[gA] : 0.f;
  float bsB = bsum ? bsum[gB] : 0.f;
  const float* Xs = X + (size_t)seg*32*400;
  float xcA = Xs[gA], xcB = Xs[gB], xnA = 0.f, xnB = 0.f;
  float hnK = 0.f;

  #pragma unroll 1
  for (int t = 0; t < 32; ++t){
    if (t < 31){ xnA = Xs[(t+1)*400 + gA]; xnB = Xs[(t+1)*400 + gB]; }
    const u32x4* h4 = (const u32x4*)hp[t & 1];
    float a0=0.f, a1=0.f, b0=0.f, b1=0.f;
    #pragma unroll
    for (int i = 0; i < 12; ++i){
      u32x4 hv = h4[i];
      a0 = dot2h(wA[4*i+0], hv[0], a0);
      a1 = dot2h(wA[4*i+1], hv[1], a1);
      a0 = dot2h(wA[4*i+2], hv[2], a0);
      a1 = dot2h(wA[4*i+3], hv[3], a1);
      b0 = dot2h(wB[4*i+0], hv[0], b0);
      b1 = dot2h(wB[4*i+1], hv[1], b1);
      b0 = dot2h(wB[4*i+2], hv[2], b0);
      b1 = dot2h(wB[4*i+3], hv[3], b1);
    }
    { u32x4 hv = h4[12];
      a0 = dot2h(wA[48], hv[0], a0);
      a1 = dot2h(wA[49], hv[1], a1);
      b0 = dot2h(wB[48], hv[0], b0);
      b1 = dot2h(wB[49], hv[1], b1);
    }
    float preA = (a0 + a1) + xcA + bsA;
    float preB = (b0 + b1) + xcB + bsB;
    float vA = sigmoidf_(preA);                       // i (sub0) / f (sub1)
    float vB = sub ? sigmoidf_(preB) : tanhf_(preB);  // o (sub1) / g (sub0)
    float send = vA * vB;                             // sub0: i*g
    float recv = __shfl_xor(send, 1);
    if (act && sub){
      cr = vA*cr + recv;
      float hn = vB * tanhf_(cr);
      hnK = hn;
      ((unsigned short*)hp[(t+1) & 1])[e] = f2h(hn);
      if (houtm) houtm[((size_t)seg*32 + t)*128 + e] = f2bf(hn);
    }
    xcA = xnA; xcB = xnB;
    __syncthreads();
  }

  if (act && sub){
    if (hfin) hfin[seg*100 + e] = hnK;
    if (cfin) cfin[seg*100 + e] = cr;
    if (xout) xout[e] = hnK;
  }
}

// recA: stack-S layer 0 (zero init) -> h0out matrix + layer-0 carry
__global__ __launch_bounds__(256,1) void recA_k(
    const float* __restrict__ X0s, const unsigned int* __restrict__ wpk,
    const float* __restrict__ bias0S,
    unsigned short* __restrict__ h0outS,
    float* __restrict__ h0finS, float* __restrict__ c0finS)
{
  __shared__ unsigned int hp[2][56];
  rec_body(blockIdx.x, threadIdx.x, X0s, wpk, bias0S, nullptr, nullptr,
           h0outS, h0finS, c0finS, hp, nullptr);
}

// recB: blocks 0-31 = stack-S layer 1; blocks 32-63 = stack-R layer 0.
__global__ __launch_bounds__(256,1) void recB_k(
    const float* __restrict__ X1s, const float* __restrict__ X0r,
    const unsigned int* __restrict__ wpk, const float* __restrict__ bias0R,
    const float* __restrict__ h0finS, const float* __restrict__ c0finS,
    unsigned short* __restrict__ h0outR,
    float* __restrict__ h1finS, float* __restrict__ c1finS)
{
  __shared__ unsigned int hp[2][56];
  int bx = blockIdx.x;
  if (bx < 32){
    rec_body(bx, threadIdx.x, X1s, wpk + 20000, nullptr, nullptr, nullptr,
             nullptr, h1finS, c1finS, hp, nullptr);
  } else {
    rec_body(bx - 32, threadIdx.x, X0r, wpk + 40000, bias0R, h0finS, c0finS,
             h0outR, nullptr, nullptr, hp, nullptr);
  }
}

// recC: stack-R layer 1 + fused COALESCED head (k-major f16-pair weights).
__global__ __launch_bounds__(256,1) void recC_k(
    const float* __restrict__ X1r, const unsigned int* __restrict__ wpk,
    const float* __restrict__ h1finS, const float* __restrict__ c1finS,
    const unsigned int* __restrict__ f1wTp, const float* __restrict__ f1b,
    const unsigned int* __restrict__ f2wTp, const float* __restrict__ f2b,
    float* __restrict__ out)
{
  __shared__ unsigned int hp[2][56];
  __shared__ float xin[208];
  __shared__ unsigned int xinp[104];
  __shared__ float mid[512];
  __shared__ unsigned int midp[256];
  const int tid = threadIdx.x, b = blockIdx.x;
  rec_body(b, tid, X1r, wpk + 60000, nullptr, h1finS, c1finS,
           nullptr, nullptr, nullptr, hp, xin);          // xin[0..99] = outR
  if (tid < 100) xin[100 + tid] = h1finS[b*100 + tid];   // outS
  __syncthreads();
  if (tid < 100) xinp[tid] = (unsigned int)f2h(xin[2*tid]) |
                             ((unsigned int)f2h(xin[2*tid + 1]) << 16);
  __syncthreads();
  for (int r = tid; r < 512; r += 256){
    float acc = f1b[r];
    #pragma unroll 4
    for (int k = 0; k < 100; ++k) acc = dot2h(xinp[k], f1wTp[(size_t)k*512 + r], acc);
    mid[r] = fmaxf(acc, 0.f);
  }
  __syncthreads();
  midp[tid] = (unsigned int)f2h(mid[2*tid]) |
              ((unsigned int)f2h(mid[2*tid + 1]) << 16);
  __syncthreads();
  if (tid < 130){
    float acc = f2b[tid];
    #pragma unroll 4
    for (int k = 0; k < 256; ++k) acc = dot2h(midp[k], f2wTp[(size_t)k*130 + tid], acc);
    out[b*130 + tid] = acc;
  }
}

extern "C" void kernel_launch(void* const* d_in, const int* in_sizes, int n_in,
                              void* d_out, int out_size, void* d_ws, size_t ws_size,
                              hipStream_t stream)
{
  const float* obs  = (const float*)d_in[0];
  const float* data = (const float*)d_in[1];
  const float* c1w = (const float*)d_in[2];  const float* c1b = (const float*)d_in[3];
  const float* c2w = (const float*)d_in[4];  const float* c2b = (const float*)d_in[5];
  const float* c3w = (const float*)d_in[6];  const float* c3b = (const float*)d_in[7];
  const float* l1w = (const float*)d_in[8];  const float* l1b = (const float*)d_in[9];
  const float* l2w = (const float*)d_in[10]; const float* l2b = (const float*)d_in[11];
  const float* s_wih0=(const float*)d_in[12]; const float* s_whh0=(const float*)d_in[13];
  const float* s_bih0=(const float*)d_in[14]; const float* s_bhh0=(const float*)d_in[15];
  const float* s_wih1=(const float*)d_in[16]; const float* s_whh1=(const float*)d_in[17];
  const float* s_bih1=(const float*)d_in[18]; const float* s_bhh1=(const float*)d_in[19];
  const float* r_wih0=(const float*)d_in[20]; const float* r_whh0=(const float*)d_in[21];
  const float* r_bih0=(const float*)d_in[22]; const float* r_bhh0=(const float*)d_in[23];
  const float* r_wih1=(const float*)d_in[24]; const float* r_whh1=(const float*)d_in[25];
  const float* r_bih1=(const float*)d_in[26]; const float* r_bhh1=(const float*)d_in[27];
  const float* f1w=(const float*)d_in[28]; const float* f1b=(const float*)d_in[29];
  const float* f2w=(const float*)d_in[30]; const float* f2b=(const float*)d_in[31];
  float* out = (float*)d_out;
  (void)in_sizes; (void)n_in; (void)out_size;

  // ---- workspace layout (bytes, 256-aligned) ----
  char* p = (char*)d_ws;
  auto alloc = [&](size_t bytes){ void* r = (void*)p; p += (bytes + 255) & ~(size_t)255; return r; };
  unsigned short* data_bf = (unsigned short*)alloc((size_t)2048*1536*2);
  unsigned short* c1w_bf  = (unsigned short*)alloc((size_t)32*192*2);
  unsigned short* c2w_bf  = (unsigned short*)alloc((size_t)64*512*2);
  unsigned short* c3w_bf  = (unsigned short*)alloc((size_t)64*576*2);
  unsigned short* l1w_bf  = (unsigned short*)alloc((size_t)1024*1536*2);
  unsigned short* l2w_bf  = (unsigned short*)alloc((size_t)512*1024*2);
  unsigned short* wihS_bf = (unsigned short*)alloc((size_t)400*1536*2);
  unsigned short* wihR_bf = (unsigned short*)alloc((size_t)400*1536*2);
  unsigned short* conv1o  = (unsigned short*)alloc((size_t)2048*225*32*2);  // NHWC
  unsigned short* conv2o  = (unsigned short*)alloc((size_t)2048*36*64*2);   // NHWC
  unsigned short* feat    = (unsigned short*)alloc((size_t)2048*1536*2);
  unsigned short* lin1o   = (unsigned short*)alloc((size_t)2048*1024*2);
  float* X0s  = (float*)alloc((size_t)1024*400*4);
  float* X0r  = (float*)alloc((size_t)1024*400*4);
  unsigned int* wpk = (unsigned int*)alloc((size_t)4*20000*4);
  unsigned short* w1xS_bf = (unsigned short*)alloc((size_t)400*128*2);
  unsigned short* w1xR_bf = (unsigned short*)alloc((size_t)400*128*2);
  unsigned short* h0outS  = (unsigned short*)alloc((size_t)1024*128*2);
  unsigned short* h0outR  = (unsigned short*)alloc((size_t)1024*128*2);
  float* X1s = (float*)alloc((size_t)1024*400*4);
  float* X1r = (float*)alloc((size_t)1024*400*4);
  float* bias0S = (float*)alloc(400*4);
  float* bias0R = (float*)alloc(400*4);
  float* bias1S = (float*)alloc(400*4);
  float* bias1R = (float*)alloc(400*4);
  float* h0finS = (float*)alloc(3200*4);
  float* c0finS = (float*)alloc(3200*4);
  float* h1finS = (float*)alloc(3200*4);
  float* c1finS = (float*)alloc(3200*4);
  unsigned int* f1wTp = (unsigned int*)alloc((size_t)100*512*4);
  unsigned int* f2wTp = (unsigned int*)alloc((size_t)256*130*4);
  (void)ws_size;

  // ---- merged prep (1 launch) ----
  prep_k<<<dim3(512,13),256,0,stream>>>(
      data, data_bf, l1w, l1w_bf, l2w, l2w_bf, c1w, c1w_bf,
      c2w, c2w_bf, c3w, c3w_bf, s_wih0, wihS_bf, r_wih0, wihR_bf,
      s_whh0, s_whh1, r_whh0, r_whh1, wpk,
      s_wih1, r_wih1, w1xS_bf, w1xR_bf,
      s_bih0, s_bhh0, s_bih1, s_bhh1, r_bih0, r_bhh0, r_bih1, r_bhh1,
      bias0S, bias0R, bias1S, bias1R, h0outS, h0outR,
      f1w, f2w, f1wTp, f2wTp);

  // ---- GEMM chain (bf16 MFMA, fp32 accumulate) ----
  mgemm<128,32,4,1, 1,0,1,0, 3,64,64,8,8,4,15,15><<<dim3(3600,1),256,0,stream>>>(
      obs, c1w_bf, conv1o, c1b, 460800, 32, 192, 0, 32, 0);
  mgemm<128,64,2,2, 2,0,1,0, 32,15,15,4,4,2,6,6><<<dim3(576,1),256,0,stream>>>(
      conv1o, c2w_bf, conv2o, c2b, 73728, 64, 512, 0, 64, 0);
  mgemm<128,64,2,2, 0,0,1,0, 1,1,1,1,1,1,1,1><<<dim3(16,16),256,0,stream>>>(
      data_bf, l1w_bf, lin1o, l1b, 2048, 1024, 1536, 1536, 1024, 0);
  mgemm<128,64,2,2, 2,2,1,0, 64,6,6,3,3,1,4,4><<<dim3(256,1),256,0,stream>>>(
      conv2o, c3w_bf, feat, c3b, 32768, 64, 576, 0, 0, 1536);
  mgemm<128,64,2,2, 0,0,0,0, 1,1,1,1,1,1,1,1><<<dim3(16,8),256,0,stream>>>(
      lin1o, l2w_bf, feat + 1024, l2b, 2048, 512, 1024, 1024, 1536, 0);
  mgemm<128,64,2,2, 0,3,0,1, 1,1,1,1,1,1,1,1><<<dim3(8,7),256,0,stream>>>(
      feat, wihS_bf, X0s, (const float*)nullptr, 1024, 400, 1536, 1536, 400, 0);
  mgemm<128,64,2,2, 0,3,0,1, 1,1,1,1,1,1,1,1><<<dim3(8,7),256,0,stream>>>(
      feat + (size_t)1024*1536, wihR_bf, X0r, (const float*)nullptr, 1024, 400, 1536, 1536, 400, 0);

  // ---- pipelined LSTM: recA -> G1 -> recB (L1_S || L0_R) -> G2 -> recC+head ----
  recA_k<<<32,256,0,stream>>>(X0s, wpk, bias0S, h0outS, h0finS, c0finS);
  mgemm<128,64,2,2, 0,3,0,1, 1,1,1,1,1,1,1,1><<<dim3(8,7),256,0,stream>>>(
      h0outS, w1xS_bf, X1s, bias1S, 1024, 400, 128, 128, 400, 0);
  recB_k<<<64,256,0,stream>>>(X1s, X0r, wpk, bias0R, h0finS, c0finS,
                              h0outR, h1finS, c1finS);
  mgemm<128,64,2,2, 0,3,0,1, 1,1,1,1,1,1,1,1><<<dim3(8,7),256,0,stream>>>(
      h0outR, w1xR_bf, X1r, bias1R, 1024, 400, 128, 128, 400, 0);
  recC_k<<<32,256,0,stream>>>(X1r, wpk, h1finS, c1finS,
                              f1wTp, f1b, f2wTp, f2b, out);
}

// Round 19
// 295.738 us; speedup vs baseline: 3.6755x; 1.0094x over previous
//
#include <hip/hip_runtime.h>
#include <hip/hip_fp16.h>
#include <math.h>

// ---------------------------------------------------------------------------
// NatureCNN. Round 19: stage each rec phase's X slab (32x400 fp32 = 51.2KB)
// into LDS with one coalesced copy; the 32-step loop reads x from LDS
// (2-way bank aliasing = free) instead of per-step global reads whose
// L2/cross-XCD latency was exposed at 1 wave/SIMD (recC rec ~50us vs 28).
// Pipeline (r17/18): recA(L0_S) -> GEMM X1_S -> recB(L1_S || L0_R) ->
// GEMM X1_R -> recC(L1_R + coalesced f16 head).
// ---------------------------------------------------------------------------

typedef __attribute__((ext_vector_type(4))) float f32x4;
typedef __attribute__((ext_vector_type(8))) short s16x8;
typedef __attribute__((ext_vector_type(8))) unsigned short u16x8;
typedef __attribute__((ext_vector_type(4))) unsigned int u32x4;

__device__ __forceinline__ unsigned short f2bf(float f){
  union { float f; unsigned int u; } v; v.f = f;
  unsigned int r = (v.u + 0x7fffu + ((v.u >> 16) & 1u)) >> 16;
  return (unsigned short)r;
}
__device__ __forceinline__ unsigned short f2h(float f){
  return __half_as_ushort(__float2half(f));
}
__device__ __forceinline__ float sigmoidf_(float x){ return 1.0f/(1.0f+__expf(-x)); }
__device__ __forceinline__ float tanhf_(float x){
  float e = __expf(-2.0f*fabsf(x));
  float t = (1.0f - e)/(1.0f + e);
  return copysignf(t, x);
}

#if __has_builtin(__builtin_amdgcn_fdot2)
typedef _Float16 f16x2 __attribute__((ext_vector_type(2)));
__device__ __forceinline__ float dot2h(unsigned int a, unsigned int b, float c){
  union { unsigned int u; f16x2 h; } ua, ub;
  ua.u = a; ub.u = b;
  return __builtin_amdgcn_fdot2(ua.h, ub.h, c, false);
}
#else
__device__ __forceinline__ float dot2h(unsigned int a, unsigned int b, float c){
  __half2 ha = *(__half2*)&a, hb = *(__half2*)&b;
  float2 fa = __half22float2(ha), fb = __half22float2(hb);
  return c + fa.x*fb.x + fa.y*fb.y;
}
#endif

// ---------------------------------------------------------------------------
// ONE merged prep kernel (jobs as in r18).
// ---------------------------------------------------------------------------
__global__ void prep_k(
    const float* __restrict__ data, unsigned short* __restrict__ data_bf,
    const float* __restrict__ l1w,  unsigned short* __restrict__ l1w_bf,
    const float* __restrict__ l2w,  unsigned short* __restrict__ l2w_bf,
    const float* __restrict__ c1w,  unsigned short* __restrict__ c1w_bf,
    const float* __restrict__ c2w,  unsigned short* __restrict__ c2w_bf,
    const float* __restrict__ c3w,  unsigned short* __restrict__ c3w_bf,
    const float* __restrict__ wihS, unsigned short* __restrict__ wihS_bf,
    const float* __restrict__ wihR, unsigned short* __restrict__ wihR_bf,
    const float* __restrict__ m0, const float* __restrict__ m1,
    const float* __restrict__ m2, const float* __restrict__ m3,
    unsigned int* __restrict__ wpk,
    const float* __restrict__ wih1S, const float* __restrict__ wih1R,
    unsigned short* __restrict__ w1xS_bf, unsigned short* __restrict__ w1xR_bf,
    const float* __restrict__ s_bih0, const float* __restrict__ s_bhh0,
    const float* __restrict__ s_bih1, const float* __restrict__ s_bhh1,
    const float* __restrict__ r_bih0, const float* __restrict__ r_bhh0,
    const float* __restrict__ r_bih1, const float* __restrict__ r_bhh1,
    float* __restrict__ bias0S, float* __restrict__ bias0R,
    float* __restrict__ bias1S, float* __restrict__ bias1R,
    unsigned short* __restrict__ h0outS, unsigned short* __restrict__ h0outR,
    const float* __restrict__ f1w, const float* __restrict__ f2w,
    unsigned int* __restrict__ f1wTp, unsigned int* __restrict__ f2wTp)
{
  const int job = blockIdx.y;
  const int stride = gridDim.x * blockDim.x;
  int e0 = blockIdx.x * blockDim.x + threadIdx.x;
  if (job == 0){
    for (int e = e0; e < 2048*1536; e += stride){
      int r = e / 1536, k = e - r*1536;
      data_bf[e] = (k < 1500) ? f2bf(data[(size_t)r*1500 + k]) : (unsigned short)0;
    }
  } else if (job == 1){
    for (int e = e0; e < 1024*1536; e += stride){
      int r = e / 1536, k = e - r*1536;
      l1w_bf[e] = (k < 1500) ? f2bf(l1w[(size_t)r*1500 + k]) : (unsigned short)0;
    }
  } else if (job == 2){
    for (int e = e0; e < 512*1024; e += stride) l2w_bf[e] = f2bf(l2w[e]);
  } else if (job == 3){
    for (int e = e0; e < 32*192; e += stride) c1w_bf[e] = f2bf(c1w[e]);
  } else if (job == 4){
    for (int e = e0; e < 64*512; e += stride){
      int oc = e >> 9, r = e & 511;
      int tap = r >> 5, ic = r & 31;
      c2w_bf[e] = f2bf(c2w[(size_t)oc*512 + ic*16 + tap]);
    }
  } else if (job == 5){
    for (int e = e0; e < 64*576; e += stride){
      int oc = e / 576, r = e - oc*576;
      int tap = r >> 6, ic = r & 63;
      c3w_bf[e] = f2bf(c3w[(size_t)oc*576 + ic*9 + tap]);
    }
  } else if (job == 6 || job == 7){
    const float* src = (job == 6) ? wihS : wihR;
    unsigned short* dst = (job == 6) ? wihS_bf : wihR_bf;
    for (int e = e0; e < 400*1536; e += stride){
      int g = e / 1536, k = e - g*1536;
      int ksrc = (k < 1024) ? ((k & 63)*16 + (k >> 6)) : k;
      dst[e] = f2bf(src[(size_t)g*1536 + ksrc]);
    }
  } else if (job == 8){
    const float* srcs[4] = {m0,m1,m2,m3};
    for (int e = e0; e < 4*20000; e += stride){
      int mat = e / 20000, r = e - mat*20000;
      int kk = r / 400, g = r - kk*400;
      const float* src = srcs[mat];
      unsigned int lo = f2h(src[g*100 + 2*kk]);
      unsigned int hi = f2h(src[g*100 + 2*kk + 1]);
      wpk[e] = lo | (hi << 16);
    }
  } else if (job == 9){
    for (int e = e0; e < 2*400*128; e += stride){
      int half = e / 51200, r = e - half*51200;
      int g = r >> 7, k = r & 127;
      const float* src = half ? wih1R : wih1S;
      unsigned short* dst = half ? w1xR_bf : w1xS_bf;
      dst[r] = (k < 100) ? f2bf(src[g*100 + k]) : (unsigned short)0;
    }
  } else if (job == 10){
    for (int e = e0; e < 1600 + 131072; e += stride){
      if (e < 400)        bias0S[e]       = s_bih0[e]       + s_bhh0[e];
      else if (e < 800)   bias0R[e-400]   = r_bih0[e-400]   + r_bhh0[e-400];
      else if (e < 1200)  bias1S[e-800]   = s_bih1[e-800]   + s_bhh1[e-800];
      else if (e < 1600)  bias1R[e-1200]  = r_bih1[e-1200]  + r_bhh1[e-1200];
      else {
        int idx = e - 1600;
        if (idx < 65536) ((unsigned int*)h0outS)[idx] = 0u;
        else             ((unsigned int*)h0outR)[idx - 65536] = 0u;
      }
    }
  } else if (job == 11){
    for (int e = e0; e < 100*512; e += stride){
      int k = e >> 9, r = e & 511;
      unsigned int lo = f2h(f1w[(size_t)r*200 + 2*k]);
      unsigned int hi = f2h(f1w[(size_t)r*200 + 2*k + 1]);
      f1wTp[e] = lo | (hi << 16);
    }
  } else {
    for (int e = e0; e < 256*130; e += stride){
      int k = e / 130, j = e - k*130;
      unsigned int lo = f2h(f2w[(size_t)j*512 + 2*k]);
      unsigned int hi = f2h(f2w[(size_t)j*512 + 2*k + 1]);
      f2wTp[e] = lo | (hi << 16);
    }
  }
}

// ---------------------------------------------------------------------------
// bf16 MFMA GEMM (unchanged, passing since round 2)
// ---------------------------------------------------------------------------
template<int BM,int BN,int WAVES_M,int WAVES_N,int AMODE,int CMODE,int RELU,int NGUARD,
         int CIN,int HI,int WI,int KH,int KW,int ST,int HO,int WO>
__global__ __launch_bounds__(256) void mgemm(
    const void* __restrict__ Av, const unsigned short* __restrict__ B,
    void* __restrict__ Cv, const float* __restrict__ bias,
    int M, int N, int K, int lda, int ldc, int cstride)
{
  constexpr int BK = 64;
  constexpr int WROWS = BM / WAVES_M;
  constexpr int WCOLS = BN / WAVES_N;
  constexpr int MF = WROWS / 16;
  constexpr int NF = WCOLS / 16;
  constexpr int HOWO = HO*WO;
  __shared__ unsigned short As[BM*BK];
  __shared__ unsigned short Bs[BN*BK];
  const int tid = threadIdx.x;
  const int bm = blockIdx.x * BM;
  const int bn = blockIdx.y * BN;
  const int lane = tid & 63, w = tid >> 6;
  const int wm = w / WAVES_N, wn = w % WAVES_N;
  const int m0 = wm * WROWS, n0 = wn * WCOLS;

  f32x4 acc[MF][NF] = {};

  const int ar = tid >> 1;
  const int as0 = 4 * (tid & 1);
  const int row_g = bm + ar;
  int a_n = 0, a_oy = 0, a_ox = 0;
  if (AMODE != 0){ a_n = row_g / HOWO; int p = row_g - a_n*HOWO; a_oy = p / WO; a_ox = p - a_oy*WO; }

  for (int kt = 0; kt < K; kt += BK){
    #pragma unroll
    for (int si = 0; si < 4; ++si){
      int s = as0 + si;
      int k0 = kt + s*8;
      u16x8 val;
      if constexpr (AMODE == 0){
        val = *(const u16x8*)((const unsigned short*)Av + (size_t)row_g*lda + k0);
      } else if constexpr (AMODE == 1){
        int ic = k0 >> 6, r = k0 & 63, ky = r >> 3;
        const float* src = (const float*)Av +
            (((size_t)(a_n*CIN + ic)*HI + a_oy*ST + ky)*WI + a_ox*ST);
        f32x4 f0 = *(const f32x4*)src;
        f32x4 f1 = *(const f32x4*)(src + 4);
        val[0]=f2bf(f0[0]); val[1]=f2bf(f0[1]); val[2]=f2bf(f0[2]); val[3]=f2bf(f0[3]);
        val[4]=f2bf(f1[0]); val[5]=f2bf(f1[1]); val[6]=f2bf(f1[2]); val[7]=f2bf(f1[3]);
      } else {
        int tap = k0 / CIN, ic0 = k0 - tap*CIN;
        int ky = tap / KW, kx = tap - ky*KW;
        const unsigned short* src = (const unsigned short*)Av +
            (((size_t)(a_n*HI + a_oy*ST + ky)*WI + a_ox*ST + kx)*CIN + ic0);
        val = *(const u16x8*)src;
      }
      int phys = s ^ ((ar >> 1) & 7);
      *(u16x8*)&As[ar*BK + phys*8] = val;
    }
    if constexpr (BN == 64){
      int br = tid >> 2, bs0 = 2*(tid & 3);
      #pragma unroll
      for (int si = 0; si < 2; ++si){
        int s = bs0 + si, k0 = kt + s*8;
        int n_g = bn + br;
        u16x8 val = {};
        if (!NGUARD || n_g < N) val = *(const u16x8*)(B + (size_t)n_g*K + k0);
        int phys = s ^ ((br >> 1) & 7);
        *(u16x8*)&Bs[br*BK + phys*8] = val;
      }
    } else {
      int br = tid >> 3, s = tid & 7, k0 = kt + s*8;
      int n_g = bn + br;
      u16x8 val = {};
      if (!NGUARD || n_g < N) val = *(const u16x8*)(B + (size_t)n_g*K + k0);
      int phys = s ^ ((br >> 1) & 7);
      *(u16x8*)&Bs[br*BK + phys*8] = val;
    }
    __syncthreads();
    #pragma unroll
    for (int ks = 0; ks < 2; ++ks){
      s16x8 a[MF], b[NF];
      #pragma unroll
      for (int i = 0; i < MF; ++i){
        int row = m0 + i*16 + (lane & 15);
        int phys = (ks*4 + (lane >> 4)) ^ ((row >> 1) & 7);
        a[i] = *(const s16x8*)&As[row*BK + phys*8];
      }
      #pragma unroll
      for (int j = 0; j < NF; ++j){
        int row = n0 + j*16 + (lane & 15);
        int phys = (ks*4 + (lane >> 4)) ^ ((row >> 1) & 7);
        b[j] = *(const s16x8*)&Bs[row*BK + phys*8];
      }
      #pragma unroll
      for (int i = 0; i < MF; ++i)
        #pragma unroll
        for (int j = 0; j < NF; ++j)
          acc[i][j] = __builtin_amdgcn_mfma_f32_16x16x32_bf16(a[i], b[j], acc[i][j], 0, 0, 0);
    }
    __syncthreads();
  }

  if constexpr (CMODE == 3){
    float* Cf = (float*)Cv;
    #pragma unroll
    for (int i = 0; i < MF; ++i)
      #pragma unroll
      for (int j = 0; j < NF; ++j){
        int col = bn + n0 + j*16 + (lane & 15);
        float bv = (bias && (!NGUARD || col < N)) ? bias[col] : 0.f;
        #pragma unroll
        for (int q = 0; q < 4; ++q){
          int row = bm + m0 + i*16 + (lane >> 4)*4 + q;
          float v = acc[i][j][q] + bv;
          if (RELU) v = fmaxf(v, 0.f);
          if (!NGUARD || col < N) Cf[(size_t)row*ldc + col] = v;
        }
      }
  } else {
    unsigned short* tile = As;
    #pragma unroll
    for (int i = 0; i < MF; ++i)
      #pragma unroll
      for (int j = 0; j < NF; ++j){
        int col = n0 + j*16 + (lane & 15);
        float bv = bias ? bias[bn + col] : 0.f;
        #pragma unroll
        for (int q = 0; q < 4; ++q){
          int row = m0 + i*16 + (lane >> 4)*4 + q;
          float v = acc[i][j][q] + bv;
          if (RELU) v = fmaxf(v, 0.f);
          tile[row*BN + col] = f2bf(v);
        }
      }
    __syncthreads();
    unsigned short* Cu = (unsigned short*)Cv;
    constexpr int CHUNKS = (BM*BN)/(256*8);
    #pragma unroll
    for (int c = 0; c < CHUNKS; ++c){
      int flat = tid*8 + c*2048;
      int row = flat / BN, col = flat - (flat/BN)*BN;
      u16x8 v = *(const u16x8*)&tile[flat];
      int rg = bm + row;
      size_t addr;
      if constexpr (CMODE == 0) addr = (size_t)rg*ldc + bn + col;
      else { int n = rg >> 4, p = rg & 15; addr = (size_t)n*cstride + p*64 + col; }
      *(u16x8*)&Cu[addr] = v;
    }
  }
}

// ---------------------------------------------------------------------------
// Unified single-layer recurrent body; X slab staged into LDS up front
// (coalesced float4 copy), step loop reads x from LDS (2-way alias = free).
// ---------------------------------------------------------------------------
__device__ __forceinline__ void rec_body(
    int seg, int tid,
    const float* __restrict__ X,            // global [(seg*32+t)*400 + g]
    float* __restrict__ Xl,                 // LDS [12800]
    const unsigned int* __restrict__ wP,
    const float* __restrict__ bsum,
    const float* __restrict__ hinit,
    const float* __restrict__ cinit,
    unsigned short* __restrict__ houtm,
    float* __restrict__ hfin,
    float* __restrict__ cfin,
    unsigned int (*hp)[56],
    float* __restrict__ xout)
{
  const int e = tid >> 1, sub = tid & 1;
  const bool act = (e < 100);
  const int eS = act ? e : 0;
  const int gA = sub*100 + eS;
  const int gB = gA + 200;

  // stage X (51.2 KB) into LDS, coalesced
  const f32x4* Xg4 = (const f32x4*)(X + (size_t)seg*32*400);
  f32x4* Xl4 = (f32x4*)Xl;
  #pragma unroll
  for (int q = 0; q < 12; ++q) Xl4[tid + q*256] = Xg4[tid + q*256];
  if (tid < 128) Xl4[tid + 3072] = Xg4[tid + 3072];

  if (tid < 56){
    unsigned int v = 0u;
    if (hinit && tid < 50){
      unsigned int lo = f2h(hinit[seg*100 + 2*tid]);
      unsigned int hi = f2h(hinit[seg*100 + 2*tid + 1]);
      v = lo | (hi << 16);
    }
    hp[0][tid] = v;
    hp[1][tid] = 0u;
  }
  float cr = 0.f;
  if (cinit && act && sub) cr = cinit[seg*100 + e];

  unsigned int wA[50], wB[50];
  #pragma unroll
  for (int p = 0; p < 50; ++p){
    wA[p] = wP[p*400 + gA];
    wB[p] = wP[p*400 + gB];
  }
  float bsA = bsum ? bsum[gA] : 0.f;
  float bsB = bsum ? bsum[gB] : 0.f;
  float hnK = 0.f;
  __syncthreads();

  #pragma unroll 1
  for (int t = 0; t < 32; ++t){
    float xcA = Xl[t*400 + gA];
    float xcB = Xl[t*400 + gB];
    const u32x4* h4 = (const u32x4*)hp[t & 1];
    float a0=0.f, a1=0.f, b0=0.f, b1=0.f;
    #pragma unroll
    for (int i = 0; i < 12; ++i){
      u32x4 hv = h4[i];
      a0 = dot2h(wA[4*i+0], hv[0], a0);
      a1 = dot2h(wA[4*i+1], hv[1], a1);
      a0 = dot2h(wA[4*i+2], hv[2], a0);
      a1 = dot2h(wA[4*i+3], hv[3], a1);
      b0 = dot2h(wB[4*i+0], hv[0], b0);
      b1 = dot2h(wB[4*i+1], hv[1], b1);
      b0 = dot2h(wB[4*i+2], hv[2], b0);
      b1 = dot2h(wB[4*i+3], hv[3], b1);
    }
    { u32x4 hv = h4[12];
      a0 = dot2h(wA[48], hv[0], a0);
      a1 = dot2h(wA[49], hv[1], a1);
      b0 = dot2h(wB[48], hv[0], b0);
      b1 = dot2h(wB[49], hv[1], b1);
    }
    float preA = (a0 + a1) + xcA + bsA;
    float preB = (b0 + b1) + xcB + bsB;
    float vA = sigmoidf_(preA);                       // i (sub0) / f (sub1)
    float vB = sub ? sigmoidf_(preB) : tanhf_(preB);  // o (sub1) / g (sub0)
    float send = vA * vB;                             // sub0: i*g
    float recv = __shfl_xor(send, 1);
    if (act && sub){
      cr = vA*cr + recv;
      float hn = vB * tanhf_(cr);
      hnK = hn;
      ((unsigned short*)hp[(t+1) & 1])[e] = f2h(hn);
      if (houtm) houtm[((size_t)seg*32 + t)*128 + e] = f2bf(hn);
    }
    __syncthreads();
  }

  if (act && sub){
    if (hfin) hfin[seg*100 + e] = hnK;
    if (cfin) cfin[seg*100 + e] = cr;
    if (xout) xout[e] = hnK;
  }
}

// recA: stack-S layer 0 (zero init) -> h0out matrix + layer-0 carry
__global__ __launch_bounds__(256,1) void recA_k(
    const float* __restrict__ X0s, const unsigned int* __restrict__ wpk,
    const float* __restrict__ bias0S,
    unsigned short* __restrict__ h0outS,
    float* __restrict__ h0finS, float* __restrict__ c0finS)
{
  __shared__ unsigned int hp[2][56];
  __shared__ float Xl[12800];
  rec_body(blockIdx.x, threadIdx.x, X0s, Xl, wpk, bias0S, nullptr, nullptr,
           h0outS, h0finS, c0finS, hp, nullptr);
}

// recB: blocks 0-31 = stack-S layer 1; blocks 32-63 = stack-R layer 0.
__global__ __launch_bounds__(256,1) void recB_k(
    const float* __restrict__ X1s, const float* __restrict__ X0r,
    const unsigned int* __restrict__ wpk, const float* __restrict__ bias0R,
    const float* __restrict__ h0finS, const float* __restrict__ c0finS,
    unsigned short* __restrict__ h0outR,
    float* __restrict__ h1finS, float* __restrict__ c1finS)
{
  __shared__ unsigned int hp[2][56];
  __shared__ float Xl[12800];
  int bx = blockIdx.x;
  if (bx < 32){
    rec_body(bx, threadIdx.x, X1s, Xl, wpk + 20000, nullptr, nullptr, nullptr,
             nullptr, h1finS, c1finS, hp, nullptr);
  } else {
    rec_body(bx - 32, threadIdx.x, X0r, Xl, wpk + 40000, bias0R, h0finS, c0finS,
             h0outR, nullptr, nullptr, hp, nullptr);
  }
}

// recC: stack-R layer 1 + fused coalesced head (k-major f16-pair weights).
__global__ __launch_bounds__(256,1) void recC_k(
    const float* __restrict__ X1r, const unsigned int* __restrict__ wpk,
    const float* __restrict__ h1finS, const float* __restrict__ c1finS,
    const unsigned int* __restrict__ f1wTp, const float* __restrict__ f1b,
    const unsigned int* __restrict__ f2wTp, const float* __restrict__ f2b,
    float* __restrict__ out)
{
  __shared__ unsigned int hp[2][56];
  __shared__ float Xl[12800];
  __shared__ float xin[208];
  __shared__ unsigned int xinp[104];
  __shared__ float mid[512];
  __shared__ unsigned int midp[256];
  const int tid = threadIdx.x, b = blockIdx.x;
  rec_body(b, tid, X1r, Xl, wpk + 60000, nullptr, h1finS, c1finS,
           nullptr, nullptr, nullptr, hp, xin);          // xin[0..99] = outR
  if (tid < 100) xin[100 + tid] = h1finS[b*100 + tid];   // outS
  __syncthreads();
  if (tid < 100) xinp[tid] = (unsigned int)f2h(xin[2*tid]) |
                             ((unsigned int)f2h(xin[2*tid + 1]) << 16);
  __syncthreads();
  for (int r = tid; r < 512; r += 256){
    float acc = f1b[r];
    #pragma unroll 4
    for (int k = 0; k < 100; ++k) acc = dot2h(xinp[k], f1wTp[(size_t)k*512 + r], acc);
    mid[r] = fmaxf(acc, 0.f);
  }
  __syncthreads();
  midp[tid] = (unsigned int)f2h(mid[2*tid]) |
              ((unsigned int)f2h(mid[2*tid + 1]) << 16);
  __syncthreads();
  if (tid < 130){
    float acc = f2b[tid];
    #pragma unroll 4
    for (int k = 0; k < 256; ++k) acc = dot2h(midp[k], f2wTp[(size_t)k*130 + tid], acc);
    out[b*130 + tid] = acc;
  }
}

extern "C" void kernel_launch(void* const* d_in, const int* in_sizes, int n_in,
                              void* d_out, int out_size, void* d_ws, size_t ws_size,
                              hipStream_t stream)
{
  const float* obs  = (const float*)d_in[0];
  const float* data = (const float*)d_in[1];
  const float* c1w = (const float*)d_in[2];  const float* c1b = (const float*)d_in[3];
  const float* c2w = (const float*)d_in[4];  const float* c2b = (const float*)d_in[5];
  const float* c3w = (const float*)d_in[6];  const float* c3b = (const float*)d_in[7];
  const float* l1w = (const float*)d_in[8];  const float* l1b = (const float*)d_in[9];
  const float* l2w = (const float*)d_in[10]; const float* l2b = (const float*)d_in[11];
  const float* s_wih0=(const float*)d_in[12]; const float* s_whh0=(const float*)d_in[13];
  const float* s_bih0=(const float*)d_in[14]; const float* s_bhh0=(const float*)d_in[15];
  const float* s_wih1=(const float*)d_in[16]; const float* s_whh1=(const float*)d_in[17];
  const float* s_bih1=(const float*)d_in[18]; const float* s_bhh1=(const float*)d_in[19];
  const float* r_wih0=(const float*)d_in[20]; const float* r_whh0=(const float*)d_in[21];
  const float* r_bih0=(const float*)d_in[22]; const float* r_bhh0=(const float*)d_in[23];
  const float* r_wih1=(const float*)d_in[24]; const float* r_whh1=(const float*)d_in[25];
  const float* r_bih1=(const float*)d_in[26]; const float* r_bhh1=(const float*)d_in[27];
  const float* f1w=(const float*)d_in[28]; const float* f1b=(const float*)d_in[29];
  const float* f2w=(const float*)d_in[30]; const float* f2b=(const float*)d_in[31];
  float* out = (float*)d_out;
  (void)in_sizes; (void)n_in; (void)out_size;

  // ---- workspace layout (bytes, 256-aligned) ----
  char* p = (char*)d_ws;
  auto alloc = [&](size_t bytes){ void* r = (void*)p; p += (bytes + 255) & ~(size_t)255; return r; };
  unsigned short* data_bf = (unsigned short*)alloc((size_t)2048*1536*2);
  unsigned short* c1w_bf  = (unsigned short*)alloc((size_t)32*192*2);
  unsigned short* c2w_bf  = (unsigned short*)alloc((size_t)64*512*2);
  unsigned short* c3w_bf  = (unsigned short*)alloc((size_t)64*576*2);
  unsigned short* l1w_bf  = (unsigned short*)alloc((size_t)1024*1536*2);
  unsigned short* l2w_bf  = (unsigned short*)alloc((size_t)512*1024*2);
  unsigned short* wihS_bf = (unsigned short*)alloc((size_t)400*1536*2);
  unsigned short* wihR_bf = (unsigned short*)alloc((size_t)400*1536*2);
  unsigned short* conv1o  = (unsigned short*)alloc((size_t)2048*225*32*2);  // NHWC
  unsigned short* conv2o  = (unsigned short*)alloc((size_t)2048*36*64*2);   // NHWC
  unsigned short* feat    = (unsigned short*)alloc((size_t)2048*1536*2);
  unsigned short* lin1o   = (unsigned short*)alloc((size_t)2048*1024*2);
  float* X0s  = (float*)alloc((size_t)1024*400*4);
  float* X0r  = (float*)alloc((size_t)1024*400*4);
  unsigned int* wpk = (unsigned int*)alloc((size_t)4*20000*4);
  unsigned short* w1xS_bf = (unsigned short*)alloc((size_t)400*128*2);
  unsigned short* w1xR_bf = (unsigned short*)alloc((size_t)400*128*2);
  unsigned short* h0outS  = (unsigned short*)alloc((size_t)1024*128*2);
  unsigned short* h0outR  = (unsigned short*)alloc((size_t)1024*128*2);
  float* X1s = (float*)alloc((size_t)1024*400*4);
  float* X1r = (float*)alloc((size_t)1024*400*4);
  float* bias0S = (float*)alloc(400*4);
  float* bias0R = (float*)alloc(400*4);
  float* bias1S = (float*)alloc(400*4);
  float* bias1R = (float*)alloc(400*4);
  float* h0finS = (float*)alloc(3200*4);
  float* c0finS = (float*)alloc(3200*4);
  float* h1finS = (float*)alloc(3200*4);
  float* c1finS = (float*)alloc(3200*4);
  unsigned int* f1wTp = (unsigned int*)alloc((size_t)100*512*4);
  unsigned int* f2wTp = (unsigned int*)alloc((size_t)256*130*4);
  (void)ws_size;

  // ---- merged prep (1 launch) ----
  prep_k<<<dim3(512,13),256,0,stream>>>(
      data, data_bf, l1w, l1w_bf, l2w, l2w_bf, c1w, c1w_bf,
      c2w, c2w_bf, c3w, c3w_bf, s_wih0, wihS_bf, r_wih0, wihR_bf,
      s_whh0, s_whh1, r_whh0, r_whh1, wpk,
      s_wih1, r_wih1, w1xS_bf, w1xR_bf,
      s_bih0, s_bhh0, s_bih1, s_bhh1, r_bih0, r_bhh0, r_bih1, r_bhh1,
      bias0S, bias0R, bias1S, bias1R, h0outS, h0outR,
      f1w, f2w, f1wTp, f2wTp);

  // ---- GEMM chain (bf16 MFMA, fp32 accumulate) ----
  mgemm<128,32,4,1, 1,0,1,0, 3,64,64,8,8,4,15,15><<<dim3(3600,1),256,0,stream>>>(
      obs, c1w_bf, conv1o, c1b, 460800, 32, 192, 0, 32, 0);
  mgemm<128,64,2,2, 2,0,1,0, 32,15,15,4,4,2,6,6><<<dim3(576,1),256,0,stream>>>(
      conv1o, c2w_bf, conv2o, c2b, 73728, 64, 512, 0, 64, 0);
  mgemm<128,64,2,2, 0,0,1,0, 1,1,1,1,1,1,1,1><<<dim3(16,16),256,0,stream>>>(
      data_bf, l1w_bf, lin1o, l1b, 2048, 1024, 1536, 1536, 1024, 0);
  mgemm<128,64,2,2, 2,2,1,0, 64,6,6,3,3,1,4,4><<<dim3(256,1),256,0,stream>>>(
      conv2o, c3w_bf, feat, c3b, 32768, 64, 576, 0, 0, 1536);
  mgemm<128,64,2,2, 0,0,0,0, 1,1,1,1,1,1,1,1><<<dim3(16,8),256,0,stream>>>(
      lin1o, l2w_bf, feat + 1024, l2b, 2048, 512, 1024, 1024, 1536, 0);
  mgemm<128,64,2,2, 0,3,0,1, 1,1,1,1,1,1,1,1><<<dim3(8,7),256,0,stream>>>(
      feat, wihS_bf, X0s, (const float*)nullptr, 1024, 400, 1536, 1536, 400, 0);
  mgemm<128,64,2,2, 0,3,0,1, 1,1,1,1,1,1,1,1><<<dim3(8,7),256,0,stream>>>(
      feat + (size_t)1024*1536, wihR_bf, X0r, (const float*)nullptr, 1024, 400, 1536, 1536, 400, 0);

  // ---- pipelined LSTM: recA -> G1 -> recB (L1_S || L0_R) -> G2 -> recC+head ----
  recA_k<<<32,256,0,stream>>>(X0s, wpk, bias0S, h0outS, h0finS, c0finS);
  mgemm<128,64,2,2, 0,3,0,1, 1,1,1,1,1,1,1,1><<<dim3(8,7),256,0,stream>>>(
      h0outS, w1xS_bf, X1s, bias1S, 1024, 400, 128, 128, 400, 0);
  recB_k<<<64,256,0,stream>>>(X1s, X0r, wpk, bias0R, h0finS, c0finS,
                              h0outR, h1finS, c1finS);
  mgemm<128,64,2,2, 0,3,0,1, 1,1,1,1,1,1,1,1><<<dim3(8,7),256,0,stream>>>(
      h0outR, w1xR_bf, X1r, bias1R, 1024, 400, 128, 128, 400, 0);
  recC_k<<<32,256,0,stream>>>(X1r, wpk, h1finS, c1finS,
                              f1wTp, f1b, f2wTp, f2b, out);
}

// Round 20
// 291.403 us; speedup vs baseline: 3.7302x; 1.0149x over previous
//
#include <hip/hip_runtime.h>
#include <hip/hip_fp16.h>
#include <math.h>

// ---------------------------------------------------------------------------
// NatureCNN. Round 20: thread-major recurrent-weight layout. Counters show
// the allocator caps live regs at ~88 < 100 declared weights -> per-step L2
// re-loads (FETCH=2.5MB=once-per-block from HBM; reloads hit L2, invisible).
// Re-pack wpk as [g][56] (224B rows, 16B-aligned) so each thread's 50
// weights are contiguous: loads AND compiler reloads become dwordx4
// (13 instr vs 100). Pipeline unchanged (r17-19): recA -> G1 ->
// recB(L1_S || L0_R) -> G2 -> recC(+coalesced f16 head); X staged in LDS.
// ---------------------------------------------------------------------------

typedef __attribute__((ext_vector_type(4))) float f32x4;
typedef __attribute__((ext_vector_type(8))) short s16x8;
typedef __attribute__((ext_vector_type(8))) unsigned short u16x8;
typedef __attribute__((ext_vector_type(4))) unsigned int u32x4;

__device__ __forceinline__ unsigned short f2bf(float f){
  union { float f; unsigned int u; } v; v.f = f;
  unsigned int r = (v.u + 0x7fffu + ((v.u >> 16) & 1u)) >> 16;
  return (unsigned short)r;
}
__device__ __forceinline__ unsigned short f2h(float f){
  return __half_as_ushort(__float2half(f));
}
__device__ __forceinline__ float sigmoidf_(float x){ return 1.0f/(1.0f+__expf(-x)); }
__device__ __forceinline__ float tanhf_(float x){
  float e = __expf(-2.0f*fabsf(x));
  float t = (1.0f - e)/(1.0f + e);
  return copysignf(t, x);
}

#if __has_builtin(__builtin_amdgcn_fdot2)
typedef _Float16 f16x2 __attribute__((ext_vector_type(2)));
__device__ __forceinline__ float dot2h(unsigned int a, unsigned int b, float c){
  union { unsigned int u; f16x2 h; } ua, ub;
  ua.u = a; ub.u = b;
  return __builtin_amdgcn_fdot2(ua.h, ub.h, c, false);
}
#else
__device__ __forceinline__ float dot2h(unsigned int a, unsigned int b, float c){
  __half2 ha = *(__half2*)&a, hb = *(__half2*)&b;
  float2 fa = __half22float2(ha), fb = __half22float2(hb);
  return c + fa.x*fb.x + fa.y*fb.y;
}
#endif

// ---------------------------------------------------------------------------
// ONE merged prep kernel (jobs as r18/19; job 8 now thread-major [g][56]).
// ---------------------------------------------------------------------------
__global__ void prep_k(
    const float* __restrict__ data, unsigned short* __restrict__ data_bf,
    const float* __restrict__ l1w,  unsigned short* __restrict__ l1w_bf,
    const float* __restrict__ l2w,  unsigned short* __restrict__ l2w_bf,
    const float* __restrict__ c1w,  unsigned short* __restrict__ c1w_bf,
    const float* __restrict__ c2w,  unsigned short* __restrict__ c2w_bf,
    const float* __restrict__ c3w,  unsigned short* __restrict__ c3w_bf,
    const float* __restrict__ wihS, unsigned short* __restrict__ wihS_bf,
    const float* __restrict__ wihR, unsigned short* __restrict__ wihR_bf,
    const float* __restrict__ m0, const float* __restrict__ m1,
    const float* __restrict__ m2, const float* __restrict__ m3,
    unsigned int* __restrict__ wpk,
    const float* __restrict__ wih1S, const float* __restrict__ wih1R,
    unsigned short* __restrict__ w1xS_bf, unsigned short* __restrict__ w1xR_bf,
    const float* __restrict__ s_bih0, const float* __restrict__ s_bhh0,
    const float* __restrict__ s_bih1, const float* __restrict__ s_bhh1,
    const float* __restrict__ r_bih0, const float* __restrict__ r_bhh0,
    const float* __restrict__ r_bih1, const float* __restrict__ r_bhh1,
    float* __restrict__ bias0S, float* __restrict__ bias0R,
    float* __restrict__ bias1S, float* __restrict__ bias1R,
    unsigned short* __restrict__ h0outS, unsigned short* __restrict__ h0outR,
    const float* __restrict__ f1w, const float* __restrict__ f2w,
    unsigned int* __restrict__ f1wTp, unsigned int* __restrict__ f2wTp)
{
  const int job = blockIdx.y;
  const int stride = gridDim.x * blockDim.x;
  int e0 = blockIdx.x * blockDim.x + threadIdx.x;
  if (job == 0){
    for (int e = e0; e < 2048*1536; e += stride){
      int r = e / 1536, k = e - r*1536;
      data_bf[e] = (k < 1500) ? f2bf(data[(size_t)r*1500 + k]) : (unsigned short)0;
    }
  } else if (job == 1){
    for (int e = e0; e < 1024*1536; e += stride){
      int r = e / 1536, k = e - r*1536;
      l1w_bf[e] = (k < 1500) ? f2bf(l1w[(size_t)r*1500 + k]) : (unsigned short)0;
    }
  } else if (job == 2){
    for (int e = e0; e < 512*1024; e += stride) l2w_bf[e] = f2bf(l2w[e]);
  } else if (job == 3){
    for (int e = e0; e < 32*192; e += stride) c1w_bf[e] = f2bf(c1w[e]);
  } else if (job == 4){
    for (int e = e0; e < 64*512; e += stride){
      int oc = e >> 9, r = e & 511;
      int tap = r >> 5, ic = r & 31;
      c2w_bf[e] = f2bf(c2w[(size_t)oc*512 + ic*16 + tap]);
    }
  } else if (job == 5){
    for (int e = e0; e < 64*576; e += stride){
      int oc = e / 576, r = e - oc*576;
      int tap = r >> 6, ic = r & 63;
      c3w_bf[e] = f2bf(c3w[(size_t)oc*576 + ic*9 + tap]);
    }
  } else if (job == 6 || job == 7){
    const float* src = (job == 6) ? wihS : wihR;
    unsigned short* dst = (job == 6) ? wihS_bf : wihR_bf;
    for (int e = e0; e < 400*1536; e += stride){
      int g = e / 1536, k = e - g*1536;
      int ksrc = (k < 1024) ? ((k & 63)*16 + (k >> 6)) : k;
      dst[e] = f2bf(src[(size_t)g*1536 + ksrc]);
    }
  } else if (job == 8){
    // thread-major: wpk[mat*22400 + g*56 + p] = pack(W[g][2p], W[g][2p+1]), p<50
    const float* srcs[4] = {m0,m1,m2,m3};
    for (int e = e0; e < 4*22400; e += stride){
      int mat = e / 22400, r = e - mat*22400;
      int g = r / 56, p = r - g*56;
      unsigned int v = 0u;
      if (p < 50){
        const float* src = srcs[mat];
        unsigned int lo = f2h(src[g*100 + 2*p]);
        unsigned int hi = f2h(src[g*100 + 2*p + 1]);
        v = lo | (hi << 16);
      }
      wpk[e] = v;
    }
  } else if (job == 9){
    for (int e = e0; e < 2*400*128; e += stride){
      int half = e / 51200, r = e - half*51200;
      int g = r >> 7, k = r & 127;
      const float* src = half ? wih1R : wih1S;
      unsigned short* dst = half ? w1xR_bf : w1xS_bf;
      dst[r] = (k < 100) ? f2bf(src[g*100 + k]) : (unsigned short)0;
    }
  } else if (job == 10){
    for (int e = e0; e < 1600 + 131072; e += stride){
      if (e < 400)        bias0S[e]       = s_bih0[e]       + s_bhh0[e];
      else if (e < 800)   bias0R[e-400]   = r_bih0[e-400]   + r_bhh0[e-400];
      else if (e < 1200)  bias1S[e-800]   = s_bih1[e-800]   + s_bhh1[e-800];
      else if (e < 1600)  bias1R[e-1200]  = r_bih1[e-1200]  + r_bhh1[e-1200];
      else {
        int idx = e - 1600;
        if (idx < 65536) ((unsigned int*)h0outS)[idx] = 0u;
        else             ((unsigned int*)h0outR)[idx - 65536] = 0u;
      }
    }
  } else if (job == 11){
    for (int e = e0; e < 100*512; e += stride){
      int k = e >> 9, r = e & 511;
      unsigned int lo = f2h(f1w[(size_t)r*200 + 2*k]);
      unsigned int hi = f2h(f1w[(size_t)r*200 + 2*k + 1]);
      f1wTp[e] = lo | (hi << 16);
    }
  } else {
    for (int e = e0; e < 256*130; e += stride){
      int k = e / 130, j = e - k*130;
      unsigned int lo = f2h(f2w[(size_t)j*512 + 2*k]);
      unsigned int hi = f2h(f2w[(size_t)j*512 + 2*k + 1]);
      f2wTp[e] = lo | (hi << 16);
    }
  }
}

// ---------------------------------------------------------------------------
// bf16 MFMA GEMM (unchanged, passing since round 2)
// ---------------------------------------------------------------------------
template<int BM,int BN,int WAVES_M,int WAVES_N,int AMODE,int CMODE,int RELU,int NGUARD,
         int CIN,int HI,int WI,int KH,int KW,int ST,int HO,int WO>
__global__ __launch_bounds__(256) void mgemm(
    const void* __restrict__ Av, const unsigned short* __restrict__ B,
    void* __restrict__ Cv, const float* __restrict__ bias,
    int M, int N, int K, int lda, int ldc, int cstride)
{
  constexpr int BK = 64;
  constexpr int WROWS = BM / WAVES_M;
  constexpr int WCOLS = BN / WAVES_N;
  constexpr int MF = WROWS / 16;
  constexpr int NF = WCOLS / 16;
  constexpr int HOWO = HO*WO;
  __shared__ unsigned short As[BM*BK];
  __shared__ unsigned short Bs[BN*BK];
  const int tid = threadIdx.x;
  const int bm = blockIdx.x * BM;
  const int bn = blockIdx.y * BN;
  const int lane = tid & 63, w = tid >> 6;
  const int wm = w / WAVES_N, wn = w % WAVES_N;
  const int m0 = wm * WROWS, n0 = wn * WCOLS;

  f32x4 acc[MF][NF] = {};

  const int ar = tid >> 1;
  const int as0 = 4 * (tid & 1);
  const int row_g = bm + ar;
  int a_n = 0, a_oy = 0, a_ox = 0;
  if (AMODE != 0){ a_n = row_g / HOWO; int p = row_g - a_n*HOWO; a_oy = p / WO; a_ox = p - a_oy*WO; }

  for (int kt = 0; kt < K; kt += BK){
    #pragma unroll
    for (int si = 0; si < 4; ++si){
      int s = as0 + si;
      int k0 = kt + s*8;
      u16x8 val;
      if constexpr (AMODE == 0){
        val = *(const u16x8*)((const unsigned short*)Av + (size_t)row_g*lda + k0);
      } else if constexpr (AMODE == 1){
        int ic = k0 >> 6, r = k0 & 63, ky = r >> 3;
        const float* src = (const float*)Av +
            (((size_t)(a_n*CIN + ic)*HI + a_oy*ST + ky)*WI + a_ox*ST);
        f32x4 f0 = *(const f32x4*)src;
        f32x4 f1 = *(const f32x4*)(src + 4);
        val[0]=f2bf(f0[0]); val[1]=f2bf(f0[1]); val[2]=f2bf(f0[2]); val[3]=f2bf(f0[3]);
        val[4]=f2bf(f1[0]); val[5]=f2bf(f1[1]); val[6]=f2bf(f1[2]); val[7]=f2bf(f1[3]);
      } else {
        int tap = k0 / CIN, ic0 = k0 - tap*CIN;
        int ky = tap / KW, kx = tap - ky*KW;
        const unsigned short* src = (const unsigned short*)Av +
            (((size_t)(a_n*HI + a_oy*ST + ky)*WI + a_ox*ST + kx)*CIN + ic0);
        val = *(const u16x8*)src;
      }
      int phys = s ^ ((ar >> 1) & 7);
      *(u16x8*)&As[ar*BK + phys*8] = val;
    }
    if constexpr (BN == 64){
      int br = tid >> 2, bs0 = 2*(tid & 3);
      #pragma unroll
      for (int si = 0; si < 2; ++si){
        int s = bs0 + si, k0 = kt + s*8;
        int n_g = bn + br;
        u16x8 val = {};
        if (!NGUARD || n_g < N) val = *(const u16x8*)(B + (size_t)n_g*K + k0);
        int phys = s ^ ((br >> 1) & 7);
        *(u16x8*)&Bs[br*BK + phys*8] = val;
      }
    } else {
      int br = tid >> 3, s = tid & 7, k0 = kt + s*8;
      int n_g = bn + br;
      u16x8 val = {};
      if (!NGUARD || n_g < N) val = *(const u16x8*)(B + (size_t)n_g*K + k0);
      int phys = s ^ ((br >> 1) & 7);
      *(u16x8*)&Bs[br*BK + phys*8] = val;
    }
    __syncthreads();
    #pragma unroll
    for (int ks = 0; ks < 2; ++ks){
      s16x8 a[MF], b[NF];
      #pragma unroll
      for (int i = 0; i < MF; ++i){
        int row = m0 + i*16 + (lane & 15);
        int phys = (ks*4 + (lane >> 4)) ^ ((row >> 1) & 7);
        a[i] = *(const s16x8*)&As[row*BK + phys*8];
      }
      #pragma unroll
      for (int j = 0; j < NF; ++j){
        int row = n0 + j*16 + (lane & 15);
        int phys = (ks*4 + (lane >> 4)) ^ ((row >> 1) & 7);
        b[j] = *(const s16x8*)&Bs[row*BK + phys*8];
      }
      #pragma unroll
      for (int i = 0; i < MF; ++i)
        #pragma unroll
        for (int j = 0; j < NF; ++j)
          acc[i][j] = __builtin_amdgcn_mfma_f32_16x16x32_bf16(a[i], b[j], acc[i][j], 0, 0, 0);
    }
    __syncthreads();
  }

  if constexpr (CMODE == 3){
    float* Cf = (float*)Cv;
    #pragma unroll
    for (int i = 0; i < MF; ++i)
      #pragma unroll
      for (int j = 0; j < NF; ++j){
        int col = bn + n0 + j*16 + (lane & 15);
        float bv = (bias && (!NGUARD || col < N)) ? bias[col] : 0.f;
        #pragma unroll
        for (int q = 0; q < 4; ++q){
          int row = bm + m0 + i*16 + (lane >> 4)*4 + q;
          float v = acc[i][j][q] + bv;
          if (RELU) v = fmaxf(v, 0.f);
          if (!NGUARD || col < N) Cf[(size_t)row*ldc + col] = v;
        }
      }
  } else {
    unsigned short* tile = As;
    #pragma unroll
    for (int i = 0; i < MF; ++i)
      #pragma unroll
      for (int j = 0; j < NF; ++j){
        int col = n0 + j*16 + (lane & 15);
        float bv = bias ? bias[bn + col] : 0.f;
        #pragma unroll
        for (int q = 0; q < 4; ++q){
          int row = m0 + i*16 + (lane >> 4)*4 + q;
          float v = acc[i][j][q] + bv;
          if (RELU) v = fmaxf(v, 0.f);
          tile[row*BN + col] = f2bf(v);
        }
      }
    __syncthreads();
    unsigned short* Cu = (unsigned short*)Cv;
    constexpr int CHUNKS = (BM*BN)/(256*8);
    #pragma unroll
    for (int c = 0; c < CHUNKS; ++c){
      int flat = tid*8 + c*2048;
      int row = flat / BN, col = flat - (flat/BN)*BN;
      u16x8 v = *(const u16x8*)&tile[flat];
      int rg = bm + row;
      size_t addr;
      if constexpr (CMODE == 0) addr = (size_t)rg*ldc + bn + col;
      else { int n = rg >> 4, p = rg & 15; addr = (size_t)n*cstride + p*64 + col; }
      *(u16x8*)&Cu[addr] = v;
    }
  }
}

// ---------------------------------------------------------------------------
// Unified single-layer recurrent body; X staged in LDS; weights loaded
// (and compiler-reloaded) as contiguous per-thread dwordx4 runs.
// ---------------------------------------------------------------------------
__device__ __forceinline__ void rec_body(
    int seg, int tid,
    const float* __restrict__ X,            // global [(seg*32+t)*400 + g]
    float* __restrict__ Xl,                 // LDS [12800]
    const unsigned int* __restrict__ wP,    // thread-major [400][56]
    const float* __restrict__ bsum,
    const float* __restrict__ hinit,
    const float* __restrict__ cinit,
    unsigned short* __restrict__ houtm,
    float* __restrict__ hfin,
    float* __restrict__ cfin,
    unsigned int (*hp)[56],
    float* __restrict__ xout)
{
  const int e = tid >> 1, sub = tid & 1;
  const bool act = (e < 100);
  const int eS = act ? e : 0;
  const int gA = sub*100 + eS;
  const int gB = gA + 200;

  // stage X (51.2 KB) into LDS, coalesced
  const f32x4* Xg4 = (const f32x4*)(X + (size_t)seg*32*400);
  f32x4* Xl4 = (f32x4*)Xl;
  #pragma unroll
  for (int q = 0; q < 12; ++q) Xl4[tid + q*256] = Xg4[tid + q*256];
  if (tid < 128) Xl4[tid + 3072] = Xg4[tid + 3072];

  if (tid < 56){
    unsigned int v = 0u;
    if (hinit && tid < 50){
      unsigned int lo = f2h(hinit[seg*100 + 2*tid]);
      unsigned int hi = f2h(hinit[seg*100 + 2*tid + 1]);
      v = lo | (hi << 16);
    }
    hp[0][tid] = v;
    hp[1][tid] = 0u;
  }
  float cr = 0.f;
  if (cinit && act && sub) cr = cinit[seg*100 + e];

  unsigned int wA[50], wB[50];
  const u32x4* wa4 = (const u32x4*)(wP + (size_t)gA*56);
  const u32x4* wb4 = (const u32x4*)(wP + (size_t)gB*56);
  #pragma unroll
  for (int q = 0; q < 12; ++q){
    u32x4 va = wa4[q], vb = wb4[q];
    wA[4*q+0]=va[0]; wA[4*q+1]=va[1]; wA[4*q+2]=va[2]; wA[4*q+3]=va[3];
    wB[4*q+0]=vb[0]; wB[4*q+1]=vb[1]; wB[4*q+2]=vb[2]; wB[4*q+3]=vb[3];
  }
  { u32x4 va = wa4[12], vb = wb4[12];
    wA[48]=va[0]; wA[49]=va[1];
    wB[48]=vb[0]; wB[49]=vb[1];
  }
  float bsA = bsum ? bsum[gA] : 0.f;
  float bsB = bsum ? bsum[gB] : 0.f;
  float hnK = 0.f;
  __syncthreads();

  #pragma unroll 1
  for (int t = 0; t < 32; ++t){
    float xcA = Xl[t*400 + gA];
    float xcB = Xl[t*400 + gB];
    const u32x4* h4 = (const u32x4*)hp[t & 1];
    float a0=0.f, a1=0.f, b0=0.f, b1=0.f;
    #pragma unroll
    for (int i = 0; i < 12; ++i){
      u32x4 hv = h4[i];
      a0 = dot2h(wA[4*i+0], hv[0], a0);
      a1 = dot2h(wA[4*i+1], hv[1], a1);
      a0 = dot2h(wA[4*i+2], hv[2], a0);
      a1 = dot2h(wA[4*i+3], hv[3], a1);
      b0 = dot2h(wB[4*i+0], hv[0], b0);
      b1 = dot2h(wB[4*i+1], hv[1], b1);
      b0 = dot2h(wB[4*i+2], hv[2], b0);
      b1 = dot2h(wB[4*i+3], hv[3], b1);
    }
    { u32x4 hv = h4[12];
      a0 = dot2h(wA[48], hv[0], a0);
      a1 = dot2h(wA[49], hv[1], a1);
      b0 = dot2h(wB[48], hv[0], b0);
      b1 = dot2h(wB[49], hv[1], b1);
    }
    float preA = (a0 + a1) + xcA + bsA;
    float preB = (b0 + b1) + xcB + bsB;
    float vA = sigmoidf_(preA);                       // i (sub0) / f (sub1)
    float vB = sub ? sigmoidf_(preB) : tanhf_(preB);  // o (sub1) / g (sub0)
    float send = vA * vB;                             // sub0: i*g
    float recv = __shfl_xor(send, 1);
    if (act && sub){
      cr = vA*cr + recv;
      float hn = vB * tanhf_(cr);
      hnK = hn;
      ((unsigned short*)hp[(t+1) & 1])[e] = f2h(hn);
      if (houtm) houtm[((size_t)seg*32 + t)*128 + e] = f2bf(hn);
    }
    __syncthreads();
  }

  if (act && sub){
    if (hfin) hfin[seg*100 + e] = hnK;
    if (cfin) cfin[seg*100 + e] = cr;
    if (xout) xout[e] = hnK;
  }
}

// recA: stack-S layer 0 (zero init) -> h0out matrix + layer-0 carry
__global__ __launch_bounds__(256,1) void recA_k(
    const float* __restrict__ X0s, const unsigned int* __restrict__ wpk,
    const float* __restrict__ bias0S,
    unsigned short* __restrict__ h0outS,
    float* __restrict__ h0finS, float* __restrict__ c0finS)
{
  __shared__ unsigned int hp[2][56];
  __shared__ float Xl[12800];
  rec_body(blockIdx.x, threadIdx.x, X0s, Xl, wpk, bias0S, nullptr, nullptr,
           h0outS, h0finS, c0finS, hp, nullptr);
}

// recB: blocks 0-31 = stack-S layer 1; blocks 32-63 = stack-R layer 0.
__global__ __launch_bounds__(256,1) void recB_k(
    const float* __restrict__ X1s, const float* __restrict__ X0r,
    const unsigned int* __restrict__ wpk, const float* __restrict__ bias0R,
    const float* __restrict__ h0finS, const float* __restrict__ c0finS,
    unsigned short* __restrict__ h0outR,
    float* __restrict__ h1finS, float* __restrict__ c1finS)
{
  __shared__ unsigned int hp[2][56];
  __shared__ float Xl[12800];
  int bx = blockIdx.x;
  if (bx < 32){
    rec_body(bx, threadIdx.x, X1s, Xl, wpk + 22400, nullptr, nullptr, nullptr,
             nullptr, h1finS, c1finS, hp, nullptr);
  } else {
    rec_body(bx - 32, threadIdx.x, X0r, Xl, wpk + 44800, bias0R, h0finS, c0finS,
             h0outR, nullptr, nullptr, hp, nullptr);
  }
}

// recC: stack-R layer 1 + fused coalesced head (k-major f16-pair weights).
__global__ __launch_bounds__(256,1) void recC_k(
    const float* __restrict__ X1r, const unsigned int* __restrict__ wpk,
    const float* __restrict__ h1finS, const float* __restrict__ c1finS,
    const unsigned int* __restrict__ f1wTp, const float* __restrict__ f1b,
    const unsigned int* __restrict__ f2wTp, const float* __restrict__ f2b,
    float* __restrict__ out)
{
  __shared__ unsigned int hp[2][56];
  __shared__ float Xl[12800];
  __shared__ float xin[208];
  __shared__ unsigned int xinp[104];
  __shared__ float mid[512];
  __shared__ unsigned int midp[256];
  const int tid = threadIdx.x, b = blockIdx.x;
  rec_body(b, tid, X1r, Xl, wpk + 67200, nullptr, h1finS, c1finS,
           nullptr, nullptr, nullptr, hp, xin);          // xin[0..99] = outR
  if (tid < 100) xin[100 + tid] = h1finS[b*100 + tid];   // outS
  __syncthreads();
  if (tid < 100) xinp[tid] = (unsigned int)f2h(xin[2*tid]) |
                             ((unsigned int)f2h(xin[2*tid + 1]) << 16);
  __syncthreads();
  for (int r = tid; r < 512; r += 256){
    float acc = f1b[r];
    #pragma unroll 4
    for (int k = 0; k < 100; ++k) acc = dot2h(xinp[k], f1wTp[(size_t)k*512 + r], acc);
    mid[r] = fmaxf(acc, 0.f);
  }
  __syncthreads();
  midp[tid] = (unsigned int)f2h(mid[2*tid]) |
              ((unsigned int)f2h(mid[2*tid + 1]) << 16);
  __syncthreads();
  if (tid < 130){
    float acc = f2b[tid];
    #pragma unroll 4
    for (int k = 0; k < 256; ++k) acc = dot2h(midp[k], f2wTp[(size_t)k*130 + tid], acc);
    out[b*130 + tid] = acc;
  }
}

extern "C" void kernel_launch(void* const* d_in, const int* in_sizes, int n_in,
                              void* d_out, int out_size, void* d_ws, size_t ws_size,
                              hipStream_t stream)
{
  const float* obs  = (const float*)d_in[0];
  const float* data = (const float*)d_in[1];
  const float* c1w = (const float*)d_in[2];  const float* c1b = (const float*)d_in[3];
  const float* c2w = (const float*)d_in[4];  const float* c2b = (const float*)d_in[5];
  const float* c3w = (const float*)d_in[6];  const float* c3b = (const float*)d_in[7];
  const float* l1w = (const float*)d_in[8];  const float* l1b = (const float*)d_in[9];
  const float* l2w = (const float*)d_in[10]; const float* l2b = (const float*)d_in[11];
  const float* s_wih0=(const float*)d_in[12]; const float* s_whh0=(const float*)d_in[13];
  const float* s_bih0=(const float*)d_in[14]; const float* s_bhh0=(const float*)d_in[15];
  const float* s_wih1=(const float*)d_in[16]; const float* s_whh1=(const float*)d_in[17];
  const float* s_bih1=(const float*)d_in[18]; const float* s_bhh1=(const float*)d_in[19];
  const float* r_wih0=(const float*)d_in[20]; const float* r_whh0=(const float*)d_in[21];
  const float* r_bih0=(const float*)d_in[22]; const float* r_bhh0=(const float*)d_in[23];
  const float* r_wih1=(const float*)d_in[24]; const float* r_whh1=(const float*)d_in[25];
  const float* r_bih1=(const float*)d_in[26]; const float* r_bhh1=(const float*)d_in[27];
  const float* f1w=(const float*)d_in[28]; const float* f1b=(const float*)d_in[29];
  const float* f2w=(const float*)d_in[30]; const float* f2b=(const float*)d_in[31];
  float* out = (float*)d_out;
  (void)in_sizes; (void)n_in; (void)out_size;

  // ---- workspace layout (bytes, 256-aligned) ----
  char* p = (char*)d_ws;
  auto alloc = [&](size_t bytes){ void* r = (void*)p; p += (bytes + 255) & ~(size_t)255; return r; };
  unsigned short* data_bf = (unsigned short*)alloc((size_t)2048*1536*2);
  unsigned short* c1w_bf  = (unsigned short*)alloc((size_t)32*192*2);
  unsigned short* c2w_bf  = (unsigned short*)alloc((size_t)64*512*2);
  unsigned short* c3w_bf  = (unsigned short*)alloc((size_t)64*576*2);
  unsigned short* l1w_bf  = (unsigned short*)alloc((size_t)1024*1536*2);
  unsigned short* l2w_bf  = (unsigned short*)alloc((size_t)512*1024*2);
  unsigned short* wihS_bf = (unsigned short*)alloc((size_t)400*1536*2);
  unsigned short* wihR_bf = (unsigned short*)alloc((size_t)400*1536*2);
  unsigned short* conv1o  = (unsigned short*)alloc((size_t)2048*225*32*2);  // NHWC
  unsigned short* conv2o  = (unsigned short*)alloc((size_t)2048*36*64*2);   // NHWC
  unsigned short* feat    = (unsigned short*)alloc((size_t)2048*1536*2);
  unsigned short* lin1o   = (unsigned short*)alloc((size_t)2048*1024*2);
  float* X0s  = (float*)alloc((size_t)1024*400*4);
  float* X0r  = (float*)alloc((size_t)1024*400*4);
  unsigned int* wpk = (unsigned int*)alloc((size_t)4*22400*4);
  unsigned short* w1xS_bf = (unsigned short*)alloc((size_t)400*128*2);
  unsigned short* w1xR_bf = (unsigned short*)alloc((size_t)400*128*2);
  unsigned short* h0outS  = (unsigned short*)alloc((size_t)1024*128*2);
  unsigned short* h0outR  = (unsigned short*)alloc((size_t)1024*128*2);
  float* X1s = (float*)alloc((size_t)1024*400*4);
  float* X1r = (float*)alloc((size_t)1024*400*4);
  float* bias0S = (float*)alloc(400*4);
  float* bias0R = (float*)alloc(400*4);
  float* bias1S = (float*)alloc(400*4);
  float* bias1R = (float*)alloc(400*4);
  float* h0finS = (float*)alloc(3200*4);
  float* c0finS = (float*)alloc(3200*4);
  float* h1finS = (float*)alloc(3200*4);
  float* c1finS = (float*)alloc(3200*4);
  unsigned int* f1wTp = (unsigned int*)alloc((size_t)100*512*4);
  unsigned int* f2wTp = (unsigned int*)alloc((size_t)256*130*4);
  (void)ws_size;

  // ---- merged prep (1 launch) ----
  prep_k<<<dim3(512,13),256,0,stream>>>(
      data, data_bf, l1w, l1w_bf, l2w, l2w_bf, c1w, c1w_bf,
      c2w, c2w_bf, c3w, c3w_bf, s_wih0, wihS_bf, r_wih0, wihR_bf,
      s_whh0, s_whh1, r_whh0, r_whh1, wpk,
      s_wih1, r_wih1, w1xS_bf, w1xR_bf,
      s_bih0, s_bhh0, s_bih1, s_bhh1, r_bih0, r_bhh0, r_bih1, r_bhh1,
      bias0S, bias0R, bias1S, bias1R, h0outS, h0outR,
      f1w, f2w, f1wTp, f2wTp);

  // ---- GEMM chain (bf16 MFMA, fp32 accumulate) ----
  mgemm<128,32,4,1, 1,0,1,0, 3,64,64,8,8,4,15,15><<<dim3(3600,1),256,0,stream>>>(
      obs, c1w_bf, conv1o, c1b, 460800, 32, 192, 0, 32, 0);
  mgemm<128,64,2,2, 2,0,1,0, 32,15,15,4,4,2,6,6><<<dim3(576,1),256,0,stream>>>(
      conv1o, c2w_bf, conv2o, c2b, 73728, 64, 512, 0, 64, 0);
  mgemm<128,64,2,2, 0,0,1,0, 1,1,1,1,1,1,1,1><<<dim3(16,16),256,0,stream>>>(
      data_bf, l1w_bf, lin1o, l1b, 2048, 1024, 1536, 1536, 1024, 0);
  mgemm<128,64,2,2, 2,2,1,0, 64,6,6,3,3,1,4,4><<<dim3(256,1),256,0,stream>>>(
      conv2o, c3w_bf, feat, c3b, 32768, 64, 576, 0, 0, 1536);
  mgemm<128,64,2,2, 0,0,0,0, 1,1,1,1,1,1,1,1><<<dim3(16,8),256,0,stream>>>(
      lin1o, l2w_bf, feat + 1024, l2b, 2048, 512, 1024, 1024, 1536, 0);
  mgemm<128,64,2,2, 0,3,0,1, 1,1,1,1,1,1,1,1><<<dim3(8,7),256,0,stream>>>(
      feat, wihS_bf, X0s, (const float*)nullptr, 1024, 400, 1536, 1536, 400, 0);
  mgemm<128,64,2,2, 0,3,0,1, 1,1,1,1,1,1,1,1><<<dim3(8,7),256,0,stream>>>(
      feat + (size_t)1024*1536, wihR_bf, X0r, (const float*)nullptr, 1024, 400, 1536, 1536, 400, 0);

  // ---- pipelined LSTM: recA -> G1 -> recB (L1_S || L0_R) -> G2 -> recC+head ----
  recA_k<<<32,256,0,stream>>>(X0s, wpk, bias0S, h0outS, h0finS, c0finS);
  mgemm<128,64,2,2, 0,3,0,1, 1,1,1,1,1,1,1,1><<<dim3(8,7),256,0,stream>>>(
      h0outS, w1xS_bf, X1s, bias1S, 1024, 400, 128, 128, 400, 0);
  recB_k<<<64,256,0,stream>>>(X1s, X0r, wpk, bias0R, h0finS, c0finS,
                              h0outR, h1finS, c1finS);
  mgemm<128,64,2,2, 0,3,0,1, 1,1,1,1,1,1,1,1><<<dim3(8,7),256,0,stream>>>(
      h0outR, w1xR_bf, X1r, bias1R, 1024, 400, 128, 128, 400, 0);
  recC_k<<<32,256,0,stream>>>(X1r, wpk, h1finS, c1finS,
                              f1wTp, f1b, f2wTp, f2b, out);
}